// Round 2
// baseline (11246.271 us; speedup 1.0000x reference)
//
#include <hip/hip_runtime.h>
#include <cstddef>
#include <cstdint>
#include <cmath>

// ---------------------------------------------------------------------------
// HiGLDP forward: 2x {GCN(1024->512->256)} + 2x {GAT 4h + GAT 1h} +
// 2x {GCN(256->128->256)} + attention fusion + MLP + log_softmax.
// fp32 throughout (correctness round). Self-loops handled as virtual edges.
// ---------------------------------------------------------------------------

static inline int cdiv(int a, int b) { return (a + b - 1) / b; }

__device__ __forceinline__ void atomAddF(float* p, float v) {
  unsafeAtomicAdd(p, v);  // hw global_atomic_add_f32
}

__device__ __forceinline__ void atomMaxF(float* addr, float v) {
  v += 0.0f;  // canonicalize -0.0 -> +0.0 so the int trick is a true max
  if (v >= 0.f) atomicMax((int*)addr, __float_as_int(v));
  else          atomicMin((unsigned int*)addr, __float_as_uint(v));
}

// ---------------- fill ----------------
__global__ void fill_k(float* __restrict__ p, float v, int n) {
  int i = blockIdx.x * 256 + threadIdx.x;
  if (i < n) p[i] = v;
}

// ---------------- degree / norms ----------------
__global__ void count_deg_k(const int* __restrict__ dst, float* __restrict__ deg, int E) {
  int e = blockIdx.x * 256 + threadIdx.x;
  if (e < E) atomAddF(&deg[dst[e]], 1.f);
}
__global__ void edge_norm_k(const int* __restrict__ src, const int* __restrict__ dst,
                            const float* __restrict__ deg, float* __restrict__ enorm, int E) {
  int e = blockIdx.x * 256 + threadIdx.x;
  if (e < E) enorm[e] = rsqrtf(deg[src[e]]) * rsqrtf(deg[dst[e]]);
}
__global__ void self_norm_k(const float* __restrict__ deg, float* __restrict__ sn, int N) {
  int i = blockIdx.x * 256 + threadIdx.x;
  if (i < N) sn[i] = 1.f / deg[i];
}

// ---------------- GEMM: C[M,N] = A[M,K] @ B[K,N] (row-major) ----------------
#define GT 64
#define GK 16
__global__ __launch_bounds__(256) void gemm_k(const float* __restrict__ A,
                                              const float* __restrict__ B,
                                              float* __restrict__ C,
                                              int M, int K, int N) {
  __shared__ float As[GK][GT + 1];
  __shared__ float Bs[GK][GT + 1];
  const int bm = blockIdx.y * GT;
  const int bn = blockIdx.x * GT;
  const int tid = threadIdx.x;
  const int tr = (tid >> 4) << 2;   // 0..60
  const int tc = (tid & 15) << 2;   // 0..60
  float acc[4][4] = {{0.f, 0.f, 0.f, 0.f}, {0.f, 0.f, 0.f, 0.f},
                     {0.f, 0.f, 0.f, 0.f}, {0.f, 0.f, 0.f, 0.f}};
  for (int k0 = 0; k0 < K; k0 += GK) {
#pragma unroll
    for (int i = 0; i < 4; ++i) {
      int idx = tid + i * 256;
      int r = idx >> 4, c = idx & 15;     // A tile: 64 rows x 16 k
      int gr = bm + r;
      As[c][r] = (gr < M) ? A[(size_t)gr * K + k0 + c] : 0.f;
      int r2 = idx >> 6, c2 = idx & 63;   // B tile: 16 k x 64 cols
      Bs[r2][c2] = B[(size_t)(k0 + r2) * N + bn + c2];  // K%16==0, N%64==0
    }
    __syncthreads();
#pragma unroll
    for (int kk = 0; kk < GK; ++kk) {
      float a[4], b[4];
#pragma unroll
      for (int i = 0; i < 4; ++i) a[i] = As[kk][tr + i];
#pragma unroll
      for (int j = 0; j < 4; ++j) b[j] = Bs[kk][tc + j];
#pragma unroll
      for (int i = 0; i < 4; ++i)
#pragma unroll
        for (int j = 0; j < 4; ++j) acc[i][j] += a[i] * b[j];
    }
    __syncthreads();
  }
#pragma unroll
  for (int i = 0; i < 4; ++i) {
    int gr = bm + tr + i;
    if (gr < M) {
#pragma unroll
      for (int j = 0; j < 4; ++j) C[(size_t)gr * N + bn + tc + j] = acc[i][j];
    }
  }
}

// ---------------- GCN pieces ----------------
// out[n,f] = h[n,f]*selfnorm[n] + bias[f]   (self-loop term + bias init)
__global__ void gcn_self_bias_k(const float* __restrict__ h, const float* __restrict__ sn,
                                const float* __restrict__ b, float* __restrict__ out,
                                int N, int F) {
  int i = blockIdx.x * 256 + threadIdx.x;
  if (i >= N * F) return;
  int n = i / F, f = i - n * F;
  out[i] = h[i] * sn[n] + b[f];
}

// out[dst] += h[src] * enorm[e]  (4 feats / thread)
__global__ void gcn_scatter_k(const float* __restrict__ h, const float* __restrict__ enorm,
                              const int* __restrict__ src, const int* __restrict__ dst,
                              float* __restrict__ out, int E, int F) {
  int t = blockIdx.x * 256 + threadIdx.x;
  int per = F >> 2;
  int e = t / per;
  if (e >= E) return;
  int f = (t - e * per) << 2;
  int s = src[e], d = dst[e];
  float nrm = enorm[e];
  const float4 hv = *reinterpret_cast<const float4*>(h + (size_t)s * F + f);
  float* o = out + (size_t)d * F + f;
  atomAddF(o + 0, hv.x * nrm);
  atomAddF(o + 1, hv.y * nrm);
  atomAddF(o + 2, hv.z * nrm);
  atomAddF(o + 3, hv.w * nrm);
}

__global__ void relu_k(float* __restrict__ x, int n) {
  int i = blockIdx.x * 256 + threadIdx.x;
  if (i < n) x[i] = fmaxf(x[i], 0.f);
}

// ---------------- GAT pieces ----------------
// asrc[n,h] = sum_c h[n,h,c]*a_src[h,c]; adst likewise
__global__ void gat_attn_k(const float* __restrict__ h, const float* __restrict__ a_s,
                           const float* __restrict__ a_d, float* __restrict__ asrc,
                           float* __restrict__ adst, int N, int H, int C) {
  int i = blockIdx.x * 256 + threadIdx.x;
  if (i >= N * H) return;
  int n = i / H, hh = i - n * H;
  const float* hp = h + (size_t)n * H * C + hh * C;
  const float* as = a_s + hh * C;
  const float* ad = a_d + hh * C;
  float s1 = 0.f, s2 = 0.f;
  for (int c = 0; c < C; ++c) { float v = hp[c]; s1 += v * as[c]; s2 += v * ad[c]; }
  asrc[i] = s1; adst[i] = s2;
}

// virtual edges: e<E real, e>=E self-loop (e-E, e-E)
__global__ void gat_max_k(const int* __restrict__ src, const int* __restrict__ dst,
                          const float* __restrict__ asrc, const float* __restrict__ adst,
                          float* __restrict__ emax, int E, int N, int H) {
  int t = blockIdx.x * 256 + threadIdx.x;
  if (t >= (E + N) * H) return;
  int e = t / H, hh = t - e * H;
  int s, d;
  if (e < E) { s = src[e]; d = dst[e]; } else { s = d = e - E; }
  float v = asrc[s * H + hh] + adst[d * H + hh];
  v = v > 0.f ? v : 0.2f * v;
  atomMaxF(&emax[d * H + hh], v);
}

__global__ void gat_exp_k(const int* __restrict__ src, const int* __restrict__ dst,
                          const float* __restrict__ asrc, const float* __restrict__ adst,
                          const float* __restrict__ emax, float* __restrict__ p,
                          float* __restrict__ denom, int E, int N, int H) {
  int t = blockIdx.x * 256 + threadIdx.x;
  if (t >= (E + N) * H) return;
  int e = t / H, hh = t - e * H;
  int s, d;
  if (e < E) { s = src[e]; d = dst[e]; } else { s = d = e - E; }
  float v = asrc[s * H + hh] + adst[d * H + hh];
  v = v > 0.f ? v : 0.2f * v;
  float pe = __expf(v - emax[d * H + hh]);
  p[t] = pe;
  atomAddF(&denom[d * H + hh], pe);
}

__global__ void gat_agg_k(const int* __restrict__ src, const int* __restrict__ dst,
                          const float* __restrict__ h, const float* __restrict__ p,
                          const float* __restrict__ denom, float* __restrict__ out,
                          int E, int N, int H, int C) {
  int F = H * C;
  int per = F >> 2;
  int t = blockIdx.x * 256 + threadIdx.x;
  int e = t / per;
  if (e >= E + N) return;
  int rem = (t - e * per) << 2;   // feature offset in [0,F)
  int hh = rem / C;
  int s, d;
  if (e < E) { s = src[e]; d = dst[e]; } else { s = d = e - E; }
  float alpha = p[e * H + hh] / (denom[d * H + hh] + 1e-16f);
  const float4 hv = *reinterpret_cast<const float4*>(h + (size_t)s * F + rem);
  float* o = out + (size_t)d * F + rem;
  atomAddF(o + 0, hv.x * alpha);
  atomAddF(o + 1, hv.y * alpha);
  atomAddF(o + 2, hv.z * alpha);
  atomAddF(o + 3, hv.w * alpha);
}

__global__ void bias_elu_k(float* __restrict__ x, const float* __restrict__ b,
                           int total, int F) {
  int i = blockIdx.x * 256 + threadIdx.x;
  if (i >= total) return;
  int f = i % F;
  float v = x[i] + b[f];
  x[i] = v > 0.f ? v : (expf(v) - 1.f);
}

// in-place: x = relu(log_softmax(x + b)) over rows of F==blockDim(256)
__global__ __launch_bounds__(256) void logsm_bias_relu_k(float* __restrict__ x,
                                                         const float* __restrict__ b, int F) {
  int n = blockIdx.x;
  int t = threadIdx.x;
  __shared__ float red[256];
  float v = x[(size_t)n * F + t] + b[t];
  red[t] = v;
  __syncthreads();
  for (int s = 128; s > 0; s >>= 1) {
    if (t < s) red[t] = fmaxf(red[t], red[t + s]);
    __syncthreads();
  }
  float m = red[0];
  __syncthreads();
  red[t] = expf(v - m);
  __syncthreads();
  for (int s = 128; s > 0; s >>= 1) {
    if (t < s) red[t] += red[t + s];
    __syncthreads();
  }
  float ls = logf(red[0]);
  float y = v - m - ls;
  x[(size_t)n * F + t] = fmaxf(y, 0.f);
}

// ---------------- final attention-fusion + MLP + log_softmax ----------------
__global__ __launch_bounds__(64) void final_k(const float* __restrict__ E1,
                                              const float* __restrict__ E3,
                                              const float* __restrict__ E4,
                                              const float* __restrict__ E6,
                                              const float* __restrict__ aw1,
                                              const float* __restrict__ ab1,
                                              const float* __restrict__ aw2,
                                              const float* __restrict__ mw1,
                                              const float* __restrict__ mb1,
                                              const float* __restrict__ mw2,
                                              const float* __restrict__ mb2,
                                              float* __restrict__ out, int N) {
  int n = blockIdx.x;
  int l = threadIdx.x;  // 0..63
  __shared__ float z[2][512];
  __shared__ float hsh[64];
  __shared__ float o7[8];
  for (int c = l; c < 256; c += 64) {
    z[0][c]       = E1[(size_t)n * 256 + c];
    z[0][256 + c] = E3[(size_t)n * 256 + c];
    z[1][c]       = E4[(size_t)n * 256 + c];
    z[1][256 + c] = E6[(size_t)n * 256 + c];
  }
  __syncthreads();
  // w_r = tanh(z_r @ aw1 + ab1) @ aw2
  float wv[2];
  for (int r = 0; r < 2; ++r) {
    float t = 0.f;
    if (l < 16) {
      float acc = ab1[l];
      for (int c = 0; c < 512; ++c) acc += z[r][c] * aw1[c * 16 + l];
      t = tanhf(acc) * aw2[l];
    }
    for (int off = 8; off >= 1; off >>= 1) t += __shfl_xor(t, off);
    wv[r] = __shfl(t, 0);
  }
  float mx = fmaxf(wv[0], wv[1]);
  float e0 = expf(wv[0] - mx), e1 = expf(wv[1] - mx);
  float inv = 1.f / (e0 + e1);
  float b0 = e0 * inv, b1 = e1 * inv;
  // hvec[l] = tanh(emb @ mw1[:,l] + mb1[l]);  emb[c] = b0*z0[c]+b1*z1[c]
  float acc = mb1[l];
  for (int c = 0; c < 512; ++c) acc += (b0 * z[0][c] + b1 * z[1][c]) * mw1[c * 64 + l];
  hsh[l] = tanhf(acc);
  __syncthreads();
  if (l < 7) {
    float o = mb2[l];
    for (int j = 0; j < 64; ++j) o += hsh[j] * mw2[j * 7 + l];
    o7[l] = o;
  }
  __syncthreads();
  if (l == 0) {
    float m = o7[0];
    for (int k = 1; k < 7; ++k) m = fmaxf(m, o7[k]);
    float s = 0.f;
    for (int k = 0; k < 7; ++k) s += expf(o7[k] - m);
    float ls = logf(s);
    for (int k = 0; k < 7; ++k) out[(size_t)n * 7 + k] = o7[k] - m - ls;
  }
}

// ---------------------------------------------------------------------------
extern "C" void kernel_launch(void* const* d_in, const int* in_sizes, int n_in,
                              void* d_out, int out_size, void* d_ws, size_t ws_size,
                              hipStream_t stream) {
  (void)n_in; (void)out_size; (void)ws_size;
  const float* x     = (const float*)d_in[0];
  const int*   sadj  = (const int*)d_in[1];
  const int*   fadj  = (const int*)d_in[2];
  const int*   asadj = (const int*)d_in[3];
  const int*   afadj = (const int*)d_in[4];
  const float* W1a = (const float*)d_in[5];  const float* b1a = (const float*)d_in[6];
  const float* W1b = (const float*)d_in[7];  const float* b1b = (const float*)d_in[8];
  const float* W2a = (const float*)d_in[9];  const float* b2a = (const float*)d_in[10];
  const float* W2b = (const float*)d_in[11]; const float* b2b = (const float*)d_in[12];
  const float* W3a = (const float*)d_in[13]; const float* b3a = (const float*)d_in[14];
  const float* W3b = (const float*)d_in[15]; const float* b3b = (const float*)d_in[16];
  const float* W4a = (const float*)d_in[17]; const float* b4a = (const float*)d_in[18];
  const float* W4b = (const float*)d_in[19]; const float* b4b = (const float*)d_in[20];
  const float* Wg1a = (const float*)d_in[21]; const float* as1a = (const float*)d_in[22];
  const float* ad1a = (const float*)d_in[23]; const float* bg1a = (const float*)d_in[24];
  const float* Wg1b = (const float*)d_in[25]; const float* as1b = (const float*)d_in[26];
  const float* ad1b = (const float*)d_in[27]; const float* bg1b = (const float*)d_in[28];
  const float* Wg2a = (const float*)d_in[29]; const float* as2a = (const float*)d_in[30];
  const float* ad2a = (const float*)d_in[31]; const float* bg2a = (const float*)d_in[32];
  const float* Wg2b = (const float*)d_in[33]; const float* as2b = (const float*)d_in[34];
  const float* ad2b = (const float*)d_in[35]; const float* bg2b = (const float*)d_in[36];
  const float* aw1 = (const float*)d_in[37]; const float* ab1 = (const float*)d_in[38];
  const float* aw2 = (const float*)d_in[39];
  const float* mw1 = (const float*)d_in[40]; const float* mb1 = (const float*)d_in[41];
  const float* mw2 = (const float*)d_in[42]; const float* mb2 = (const float*)d_in[43];

  const int N = in_sizes[0] / 1024;   // 20000
  const int E = in_sizes[1] / 2;      // 160000

  // ---- workspace layout (floats), ~190 MB total ----
  float* ws = (float*)d_ws;
  float* bufA   = ws;                           // N*512  (gemm output h)
  float* bufB   = bufA + (size_t)N * 512;       // N*512  (aggregation)
  float* E1buf  = bufB + (size_t)N * 512;       // N*256
  float* Etmp   = E1buf + (size_t)N * 256;      // N*256  (emb2 / emb5)
  float* E3buf  = Etmp + (size_t)N * 256;       // N*256
  float* E4buf  = E3buf + (size_t)N * 256;      // N*256
  float* E6buf  = E4buf + (size_t)N * 256;      // N*256
  float* degS   = E6buf + (size_t)N * 256;      // N
  float* degF   = degS + N;                     // N
  float* snormS = degF + N;                     // N
  float* snormF = snormS + N;                   // N
  float* enormS = snormF + N;                   // E
  float* enormF = enormS + E;                   // E
  float* asrc   = enormF + E;                   // N*4
  float* adst   = asrc + (size_t)N * 4;         // N*4
  float* emax   = adst + (size_t)N * 4;         // N*4
  float* denom  = emax + (size_t)N * 4;         // N*4
  float* pbuf   = denom + (size_t)N * 4;        // (E+N)*4

  auto gemm = [&](const float* A, const float* W, float* C, int K, int F) {
    gemm_k<<<dim3(F / 64, cdiv(N, 64)), 256, 0, stream>>>(A, W, C, N, K, F);
  };
  auto gcn = [&](const float* in, const float* W, const float* b, const int* ei,
                 const float* enorm, const float* snorm, float* h, float* out,
                 int K, int F) {
    gemm(in, W, h, K, F);
    gcn_self_bias_k<<<cdiv(N * F, 256), 256, 0, stream>>>(h, snorm, b, out, N, F);
    gcn_scatter_k<<<cdiv(E * (F / 4), 256), 256, 0, stream>>>(h, enorm, ei, ei + E, out, E, F);
    relu_k<<<cdiv(N * F, 256), 256, 0, stream>>>(out, N * F);
  };
  auto gat = [&](const float* in, const float* W, const float* a_s, const float* a_d,
                 const int* ei, float* h, float* out, int K, int H, int C) {
    int F = H * C;
    gemm(in, W, h, K, F);
    gat_attn_k<<<cdiv(N * H, 256), 256, 0, stream>>>(h, a_s, a_d, asrc, adst, N, H, C);
    fill_k<<<cdiv(N * H, 256), 256, 0, stream>>>(emax, -INFINITY, N * H);
    fill_k<<<cdiv(N * H, 256), 256, 0, stream>>>(denom, 0.f, N * H);
    gat_max_k<<<cdiv((E + N) * H, 256), 256, 0, stream>>>(ei, ei + E, asrc, adst, emax, E, N, H);
    gat_exp_k<<<cdiv((E + N) * H, 256), 256, 0, stream>>>(ei, ei + E, asrc, adst, emax, pbuf, denom, E, N, H);
    fill_k<<<cdiv(N * F, 256), 256, 0, stream>>>(out, 0.f, N * F);
    gat_agg_k<<<cdiv((E + N) * (F / 4), 256), 256, 0, stream>>>(ei, ei + E, h, pbuf, denom, out, E, N, H, C);
  };

  // ---- degrees / norms (shared: sadj by GCN1&3, fadj by GCN2&4) ----
  fill_k<<<cdiv(N, 256), 256, 0, stream>>>(degS, 1.f, N);  // +1 self loop
  count_deg_k<<<cdiv(E, 256), 256, 0, stream>>>(sadj + E, degS, E);
  edge_norm_k<<<cdiv(E, 256), 256, 0, stream>>>(sadj, sadj + E, degS, enormS, E);
  self_norm_k<<<cdiv(N, 256), 256, 0, stream>>>(degS, snormS, N);
  fill_k<<<cdiv(N, 256), 256, 0, stream>>>(degF, 1.f, N);
  count_deg_k<<<cdiv(E, 256), 256, 0, stream>>>(fadj + E, degF, E);
  edge_norm_k<<<cdiv(E, 256), 256, 0, stream>>>(fadj, fadj + E, degF, enormF, E);
  self_norm_k<<<cdiv(N, 256), 256, 0, stream>>>(degF, snormF, N);

  // ---- path 1: x --GCN1--> E1 --GAT1--> emb2 --GCN3--> E3 ----
  gcn(x, W1a, b1a, sadj, enormS, snormS, bufA, bufB, 1024, 512);
  gcn(bufB, W1b, b1b, sadj, enormS, snormS, bufA, E1buf, 512, 256);
  gat(E1buf, Wg1a, as1a, ad1a, asadj, bufA, bufB, 256, 4, 128);
  bias_elu_k<<<cdiv(N * 512, 256), 256, 0, stream>>>(bufB, bg1a, N * 512, 512);
  gat(bufB, Wg1b, as1b, ad1b, asadj, bufA, Etmp, 512, 1, 256);
  logsm_bias_relu_k<<<N, 256, 0, stream>>>(Etmp, bg1b, 256);  // emb2
  gcn(Etmp, W3a, b3a, sadj, enormS, snormS, bufA, bufB, 256, 128);
  gcn(bufB, W3b, b3b, sadj, enormS, snormS, bufA, E3buf, 128, 256);

  // ---- path 2: x --GCN2--> E4 --GAT2--> emb5 --GCN4--> E6 ----
  gcn(x, W2a, b2a, fadj, enormF, snormF, bufA, bufB, 1024, 512);
  gcn(bufB, W2b, b2b, fadj, enormF, snormF, bufA, E4buf, 512, 256);
  gat(E4buf, Wg2a, as2a, ad2a, afadj, bufA, bufB, 256, 4, 128);
  bias_elu_k<<<cdiv(N * 512, 256), 256, 0, stream>>>(bufB, bg2a, N * 512, 512);
  gat(bufB, Wg2b, as2b, ad2b, afadj, bufA, Etmp, 512, 1, 256);
  logsm_bias_relu_k<<<N, 256, 0, stream>>>(Etmp, bg2b, 256);  // emb5
  gcn(Etmp, W4a, b4a, fadj, enormF, snormF, bufA, bufB, 256, 128);
  gcn(bufB, W4b, b4b, fadj, enormF, snormF, bufA, E6buf, 128, 256);

  // ---- fusion + MLP + log_softmax ----
  final_k<<<N, 64, 0, stream>>>(E1buf, E3buf, E4buf, E6buf, aw1, ab1, aw2,
                                mw1, mb1, mw2, mb2, (float*)d_out, N);
}

// Round 4
// 3342.710 us; speedup vs baseline: 3.3644x; 3.3644x over previous
//
#include <hip/hip_runtime.h>
#include <cstddef>
#include <cstdint>
#include <cmath>

// ---------------------------------------------------------------------------
// HiGLDP forward, round 3 (resubmit): CSR-gather aggregation (no scatter
// atomics). Per adjacency: build CSR (hist -> scan -> place), then per-dst
// gather kernels fuse norm/self-loop/bias/activation (GCN) and the whole
// softmax-attention aggregation (GAT).
// ---------------------------------------------------------------------------

static inline int cdiv(int a, int b) { return (a + b - 1) / b; }

// ---------------- CSR build ----------------
__global__ void zero_int_k(int* __restrict__ p, int n) {
  int i = blockIdx.x * 256 + threadIdx.x;
  if (i < n) p[i] = 0;
}
__global__ void hist_k(const int* __restrict__ dst, int* __restrict__ deg, int E) {
  int e = blockIdx.x * 256 + threadIdx.x;
  if (e < E) atomicAdd(&deg[dst[e]], 1);
}
// single-block exclusive scan of deg[0..N) -> rowptr[0..N], cursor copy
__global__ __launch_bounds__(1024) void scan_k(const int* __restrict__ deg,
                                               int* __restrict__ rowptr,
                                               int* __restrict__ cursor, int N) {
  __shared__ int part[1024];
  const int t = threadIdx.x;
  const int CH = (N + 1023) / 1024;
  const int base = t * CH;
  int loc = 0;
  for (int i = 0; i < CH; ++i)
    if (base + i < N) loc += deg[base + i];
  part[t] = loc;
  __syncthreads();
  for (int off = 1; off < 1024; off <<= 1) {
    int v = (t >= off) ? part[t - off] : 0;
    __syncthreads();
    part[t] += v;
    __syncthreads();
  }
  int run = (t > 0) ? part[t - 1] : 0;
  for (int i = 0; i < CH; ++i)
    if (base + i < N) {
      rowptr[base + i] = run;
      cursor[base + i] = run;
      run += deg[base + i];
    }
  if (t == 1023) rowptr[N] = part[1023];
}
__global__ void place_k(const int* __restrict__ src, const int* __restrict__ dst,
                        int* __restrict__ cursor, int* __restrict__ col, int E) {
  int e = blockIdx.x * 256 + threadIdx.x;
  if (e < E) {
    int p = atomicAdd(&cursor[dst[e]], 1);
    col[p] = src[e];
  }
}
__global__ void dinv_k(const int* __restrict__ deg, float* __restrict__ dinv, int N) {
  int i = blockIdx.x * 256 + threadIdx.x;
  if (i < N) dinv[i] = rsqrtf((float)deg[i] + 1.f);  // +1 self loop
}

// ---------------- GEMM: C[M,N] = A[M,K] @ B[K,N] (row-major) ----------------
#define GT 64
#define GK 16
__global__ __launch_bounds__(256) void gemm_k(const float* __restrict__ A,
                                              const float* __restrict__ B,
                                              float* __restrict__ C,
                                              int M, int K, int N) {
  __shared__ float As[GK][GT + 1];
  __shared__ float Bs[GK][GT + 1];
  const int bm = blockIdx.y * GT;
  const int bn = blockIdx.x * GT;
  const int tid = threadIdx.x;
  const int tr = (tid >> 4) << 2;
  const int tc = (tid & 15) << 2;
  float acc[4][4] = {{0.f, 0.f, 0.f, 0.f}, {0.f, 0.f, 0.f, 0.f},
                     {0.f, 0.f, 0.f, 0.f}, {0.f, 0.f, 0.f, 0.f}};
  for (int k0 = 0; k0 < K; k0 += GK) {
#pragma unroll
    for (int i = 0; i < 4; ++i) {
      int idx = tid + i * 256;
      int r = idx >> 4, c = idx & 15;
      int gr = bm + r;
      As[c][r] = (gr < M) ? A[(size_t)gr * K + k0 + c] : 0.f;
      int r2 = idx >> 6, c2 = idx & 63;
      Bs[r2][c2] = B[(size_t)(k0 + r2) * N + bn + c2];
    }
    __syncthreads();
#pragma unroll
    for (int kk = 0; kk < GK; ++kk) {
      float a[4], b[4];
#pragma unroll
      for (int i = 0; i < 4; ++i) a[i] = As[kk][tr + i];
#pragma unroll
      for (int j = 0; j < 4; ++j) b[j] = Bs[kk][tc + j];
#pragma unroll
      for (int i = 0; i < 4; ++i)
#pragma unroll
        for (int j = 0; j < 4; ++j) acc[i][j] += a[i] * b[j];
    }
    __syncthreads();
  }
#pragma unroll
  for (int i = 0; i < 4; ++i) {
    int gr = bm + tr + i;
    if (gr < M) {
#pragma unroll
      for (int j = 0; j < 4; ++j) C[(size_t)gr * N + bn + tc + j] = acc[i][j];
    }
  }
}

// ---------------- GCN: per-dst gather + self + bias + relu ----------------
__global__ __launch_bounds__(256) void gcn_gather_k(
    const float* __restrict__ h, const int* __restrict__ rowptr,
    const int* __restrict__ col, const float* __restrict__ dinv,
    const float* __restrict__ bias, float* __restrict__ out, int F) {
  const int d = blockIdx.x;
  const int tid = threadIdx.x;
  const int beg = rowptr[d], end = rowptr[d + 1];
  const float di = dinv[d];
  const int f0 = tid, f1 = tid + 256;
  float a0 = 0.f, a1 = 0.f;
  if (f0 < F) a0 = h[(size_t)d * F + f0] * (di * di);
  if (f1 < F) a1 = h[(size_t)d * F + f1] * (di * di);
  for (int p = beg; p < end; ++p) {
    int s = col[p];
    float w = dinv[s] * di;
    if (f0 < F) a0 += h[(size_t)s * F + f0] * w;
    if (f1 < F) a1 += h[(size_t)s * F + f1] * w;
  }
  if (f0 < F) out[(size_t)d * F + f0] = fmaxf(a0 + bias[f0], 0.f);
  if (f1 < F) out[(size_t)d * F + f1] = fmaxf(a1 + bias[f1], 0.f);
}

// ---------------- GAT pieces ----------------
__global__ void gat_attn_k(const float* __restrict__ h, const float* __restrict__ a_s,
                           const float* __restrict__ a_d, float* __restrict__ asrc,
                           float* __restrict__ adst, int N, int H, int C) {
  int i = blockIdx.x * 256 + threadIdx.x;
  if (i >= N * H) return;
  int n = i / H, hh = i - n * H;
  const float* hp = h + (size_t)n * H * C + hh * C;
  const float* as = a_s + hh * C;
  const float* ad = a_d + hh * C;
  float s1 = 0.f, s2 = 0.f;
  for (int c = 0; c < C; ++c) { float v = hp[c]; s1 += v * as[c]; s2 += v * ad[c]; }
  asrc[i] = s1; adst[i] = s2;
}

// Fused GAT softmax + aggregation per dst node.
// EPI 0: out = elu(agg + bias)            (layer-1, concat heads)
// EPI 1: out = relu(log_softmax(agg + bias))   (layer-2, H==1)
template <int H, int C, int EPI>
__global__ __launch_bounds__(256) void gat_fused_k(
    const float* __restrict__ h, const float* __restrict__ asrc,
    const float* __restrict__ adst, const int* __restrict__ rowptr,
    const int* __restrict__ col, const float* __restrict__ bias,
    float* __restrict__ out) {
  constexpr int F = H * C;
  constexpr int FPT = F / 256;
  const int d = blockIdx.x;
  const int tid = threadIdx.x;
  const int lane = tid & 63, wv = tid >> 6;
  const int beg = rowptr[d], end = rowptr[d + 1];
  __shared__ float sred[2][4][H > 4 ? H : 4];

  float ad[H], vself[H];
#pragma unroll
  for (int k = 0; k < H; ++k) {
    ad[k] = adst[d * H + k];
    float v = asrc[d * H + k] + ad[k];
    vself[k] = v > 0.f ? v : 0.2f * v;
  }
  // ---- pass 1: segment max (self included) ----
  float mx[H];
#pragma unroll
  for (int k = 0; k < H; ++k) mx[k] = vself[k];
  for (int p = beg + tid; p < end; p += 256) {
    int s = col[p];
#pragma unroll
    for (int k = 0; k < H; ++k) {
      float v = asrc[s * H + k] + ad[k];
      v = v > 0.f ? v : 0.2f * v;
      mx[k] = fmaxf(mx[k], v);
    }
  }
#pragma unroll
  for (int off = 32; off >= 1; off >>= 1)
#pragma unroll
    for (int k = 0; k < H; ++k) mx[k] = fmaxf(mx[k], __shfl_xor(mx[k], off));
  if (lane == 0)
#pragma unroll
    for (int k = 0; k < H; ++k) sred[0][wv][k] = mx[k];
  __syncthreads();
  float m[H];
#pragma unroll
  for (int k = 0; k < H; ++k)
    m[k] = fmaxf(fmaxf(sred[0][0][k], sred[0][1][k]),
                 fmaxf(sred[0][2][k], sred[0][3][k]));
  // ---- pass 2: denom ----
  float dn[H];
#pragma unroll
  for (int k = 0; k < H; ++k) dn[k] = 0.f;
  for (int p = beg + tid; p < end; p += 256) {
    int s = col[p];
#pragma unroll
    for (int k = 0; k < H; ++k) {
      float v = asrc[s * H + k] + ad[k];
      v = v > 0.f ? v : 0.2f * v;
      dn[k] += __expf(v - m[k]);
    }
  }
#pragma unroll
  for (int off = 32; off >= 1; off >>= 1)
#pragma unroll
    for (int k = 0; k < H; ++k) dn[k] += __shfl_xor(dn[k], off);
  if (lane == 0)
#pragma unroll
    for (int k = 0; k < H; ++k) sred[1][wv][k] = dn[k];
  __syncthreads();
  float invD[H];
#pragma unroll
  for (int k = 0; k < H; ++k) {
    float t = sred[1][0][k] + sred[1][1][k] + sred[1][2][k] + sred[1][3][k];
    invD[k] = 1.f / (t + __expf(vself[k] - m[k]) + 1e-16f);
  }
  // ---- pass 3: weighted feature gather ----
  float acc[FPT];
  int f[FPT], hh[FPT];
#pragma unroll
  for (int i = 0; i < FPT; ++i) {
    f[i] = tid + i * 256;
    hh[i] = f[i] / C;
    float aself = __expf(vself[hh[i]] - m[hh[i]]) * invD[hh[i]];
    acc[i] = aself * h[(size_t)d * F + f[i]];
  }
  for (int p = beg; p < end; ++p) {
    int s = col[p];
#pragma unroll
    for (int i = 0; i < FPT; ++i) {
      int k = hh[i];
      float v = asrc[s * H + k] + ad[k];
      v = v > 0.f ? v : 0.2f * v;
      float a = __expf(v - m[k]) * invD[k];
      acc[i] += a * h[(size_t)s * F + f[i]];
    }
  }
  // ---- epilogue ----
  if (EPI == 0) {
#pragma unroll
    for (int i = 0; i < FPT; ++i) {
      float v = acc[i] + bias[f[i]];
      out[(size_t)d * F + f[i]] = v > 0.f ? v : (__expf(v) - 1.f);
    }
  } else {
    // H==1, F==256, FPT==1: log_softmax over the row then relu
    float v = acc[0] + bias[tid];
    float r = v;
#pragma unroll
    for (int off = 32; off >= 1; off >>= 1) r = fmaxf(r, __shfl_xor(r, off));
    __syncthreads();
    if (lane == 0) sred[0][wv][0] = r;
    __syncthreads();
    float m2 = fmaxf(fmaxf(sred[0][0][0], sred[0][1][0]),
                     fmaxf(sred[0][2][0], sred[0][3][0]));
    float e = __expf(v - m2);
    float se = e;
#pragma unroll
    for (int off = 32; off >= 1; off >>= 1) se += __shfl_xor(se, off);
    if (lane == 0) sred[1][wv][0] = se;
    __syncthreads();
    float tot = sred[1][0][0] + sred[1][1][0] + sred[1][2][0] + sred[1][3][0];
    float y = v - m2 - logf(tot);
    out[(size_t)d * F + tid] = fmaxf(y, 0.f);
  }
}

// ---------------- final attention-fusion + MLP + log_softmax ----------------
__global__ __launch_bounds__(64) void final_k(const float* __restrict__ E1,
                                              const float* __restrict__ E3,
                                              const float* __restrict__ E4,
                                              const float* __restrict__ E6,
                                              const float* __restrict__ aw1,
                                              const float* __restrict__ ab1,
                                              const float* __restrict__ aw2,
                                              const float* __restrict__ mw1,
                                              const float* __restrict__ mb1,
                                              const float* __restrict__ mw2,
                                              const float* __restrict__ mb2,
                                              float* __restrict__ out, int N) {
  int n = blockIdx.x;
  int l = threadIdx.x;
  __shared__ float z[2][512];
  __shared__ float hsh[64];
  __shared__ float o7[8];
  for (int c = l; c < 256; c += 64) {
    z[0][c]       = E1[(size_t)n * 256 + c];
    z[0][256 + c] = E3[(size_t)n * 256 + c];
    z[1][c]       = E4[(size_t)n * 256 + c];
    z[1][256 + c] = E6[(size_t)n * 256 + c];
  }
  __syncthreads();
  float wv[2];
  for (int r = 0; r < 2; ++r) {
    float t = 0.f;
    if (l < 16) {
      float acc = ab1[l];
      for (int c = 0; c < 512; ++c) acc += z[r][c] * aw1[c * 16 + l];
      t = tanhf(acc) * aw2[l];
    }
    for (int off = 8; off >= 1; off >>= 1) t += __shfl_xor(t, off);
    wv[r] = __shfl(t, 0);
  }
  float mx = fmaxf(wv[0], wv[1]);
  float e0 = expf(wv[0] - mx), e1 = expf(wv[1] - mx);
  float inv = 1.f / (e0 + e1);
  float b0 = e0 * inv, b1 = e1 * inv;
  float acc = mb1[l];
  for (int c = 0; c < 512; ++c) acc += (b0 * z[0][c] + b1 * z[1][c]) * mw1[c * 64 + l];
  hsh[l] = tanhf(acc);
  __syncthreads();
  if (l < 7) {
    float o = mb2[l];
    for (int j = 0; j < 64; ++j) o += hsh[j] * mw2[j * 7 + l];
    o7[l] = o;
  }
  __syncthreads();
  if (l == 0) {
    float m = o7[0];
    for (int k = 1; k < 7; ++k) m = fmaxf(m, o7[k]);
    float s = 0.f;
    for (int k = 0; k < 7; ++k) s += expf(o7[k] - m);
    float ls = logf(s);
    for (int k = 0; k < 7; ++k) out[(size_t)n * 7 + k] = o7[k] - m - ls;
  }
}

// ---------------------------------------------------------------------------
extern "C" void kernel_launch(void* const* d_in, const int* in_sizes, int n_in,
                              void* d_out, int out_size, void* d_ws, size_t ws_size,
                              hipStream_t stream) {
  (void)n_in; (void)out_size; (void)ws_size;
  const float* x     = (const float*)d_in[0];
  const int*   sadj  = (const int*)d_in[1];
  const int*   fadj  = (const int*)d_in[2];
  const int*   asadj = (const int*)d_in[3];
  const int*   afadj = (const int*)d_in[4];
  const float* W1a = (const float*)d_in[5];  const float* b1a = (const float*)d_in[6];
  const float* W1b = (const float*)d_in[7];  const float* b1b = (const float*)d_in[8];
  const float* W2a = (const float*)d_in[9];  const float* b2a = (const float*)d_in[10];
  const float* W2b = (const float*)d_in[11]; const float* b2b = (const float*)d_in[12];
  const float* W3a = (const float*)d_in[13]; const float* b3a = (const float*)d_in[14];
  const float* W3b = (const float*)d_in[15]; const float* b3b = (const float*)d_in[16];
  const float* W4a = (const float*)d_in[17]; const float* b4a = (const float*)d_in[18];
  const float* W4b = (const float*)d_in[19]; const float* b4b = (const float*)d_in[20];
  const float* Wg1a = (const float*)d_in[21]; const float* as1a = (const float*)d_in[22];
  const float* ad1a = (const float*)d_in[23]; const float* bg1a = (const float*)d_in[24];
  const float* Wg1b = (const float*)d_in[25]; const float* as1b = (const float*)d_in[26];
  const float* ad1b = (const float*)d_in[27]; const float* bg1b = (const float*)d_in[28];
  const float* Wg2a = (const float*)d_in[29]; const float* as2a = (const float*)d_in[30];
  const float* ad2a = (const float*)d_in[31]; const float* bg2a = (const float*)d_in[32];
  const float* Wg2b = (const float*)d_in[33]; const float* as2b = (const float*)d_in[34];
  const float* ad2b = (const float*)d_in[35]; const float* bg2b = (const float*)d_in[36];
  const float* aw1 = (const float*)d_in[37]; const float* ab1 = (const float*)d_in[38];
  const float* aw2 = (const float*)d_in[39];
  const float* mw1 = (const float*)d_in[40]; const float* mb1 = (const float*)d_in[41];
  const float* mw2 = (const float*)d_in[42]; const float* mb2 = (const float*)d_in[43];

  const int N = in_sizes[0] / 1024;   // 20000
  const int E = in_sizes[1] / 2;      // 160000

  // ---- workspace layout ----
  float* ws = (float*)d_ws;
  float* bufA  = ws;                          // N*512
  float* bufB  = bufA + (size_t)N * 512;      // N*512
  float* E1buf = bufB + (size_t)N * 512;      // N*256
  float* Etmp  = E1buf + (size_t)N * 256;     // N*256
  float* E3buf = Etmp + (size_t)N * 256;      // N*256
  float* E4buf = E3buf + (size_t)N * 256;     // N*256
  float* E6buf = E4buf + (size_t)N * 256;     // N*256
  float* dinvS = E6buf + (size_t)N * 256;     // N
  float* dinvF = dinvS + N;                   // N
  float* asrcB = dinvF + N;                   // N*4
  float* adstB = asrcB + (size_t)N * 4;       // N*4
  int* ib = (int*)(adstB + (size_t)N * 4);
  int* rowptrS = ib;            ib += N + 1;
  int* rowptrF = ib;            ib += N + 1;
  int* rowptrA1 = ib;           ib += N + 1;
  int* rowptrA2 = ib;           ib += N + 1;
  int* colS = ib;               ib += E;
  int* colF = ib;               ib += E;
  int* colA1 = ib;              ib += E;
  int* colA2 = ib;              ib += E;
  int* degI = ib;               ib += N;
  int* cursor = ib;             ib += N;

  // ---- CSR builds ----
  auto build = [&](const int* ei, int* rowptr, int* col, float* dinv) {
    zero_int_k<<<cdiv(N, 256), 256, 0, stream>>>(degI, N);
    hist_k<<<cdiv(E, 256), 256, 0, stream>>>(ei + E, degI, E);
    scan_k<<<1, 1024, 0, stream>>>(degI, rowptr, cursor, N);
    if (dinv) dinv_k<<<cdiv(N, 256), 256, 0, stream>>>(degI, dinv, N);
    place_k<<<cdiv(E, 256), 256, 0, stream>>>(ei, ei + E, cursor, col, E);
  };
  build(sadj, rowptrS, colS, dinvS);
  build(fadj, rowptrF, colF, dinvF);
  build(asadj, rowptrA1, colA1, nullptr);
  build(afadj, rowptrA2, colA2, nullptr);

  auto gemm = [&](const float* A, const float* W, float* C, int K, int F) {
    gemm_k<<<dim3(F / 64, cdiv(N, 64)), 256, 0, stream>>>(A, W, C, N, K, F);
  };
  auto gcn = [&](const float* in, const float* W, const float* b, const int* rowptr,
                 const int* col, const float* dinv, float* h, float* out, int K, int F) {
    gemm(in, W, h, K, F);
    gcn_gather_k<<<N, 256, 0, stream>>>(h, rowptr, col, dinv, b, out, F);
  };
  auto gat1 = [&](const float* in, const float* W, const float* a_s, const float* a_d,
                  const float* b, const int* rowptr, const int* col, float* h, float* out) {
    gemm(in, W, h, 256, 512);
    gat_attn_k<<<cdiv(N * 4, 256), 256, 0, stream>>>(h, a_s, a_d, asrcB, adstB, N, 4, 128);
    gat_fused_k<4, 128, 0><<<N, 256, 0, stream>>>(h, asrcB, adstB, rowptr, col, b, out);
  };
  auto gat2 = [&](const float* in, const float* W, const float* a_s, const float* a_d,
                  const float* b, const int* rowptr, const int* col, float* h, float* out) {
    gemm(in, W, h, 512, 256);
    gat_attn_k<<<cdiv(N, 256), 256, 0, stream>>>(h, a_s, a_d, asrcB, adstB, N, 1, 256);
    gat_fused_k<1, 256, 1><<<N, 256, 0, stream>>>(h, asrcB, adstB, rowptr, col, b, out);
  };

  // ---- path 1: x --GCN1--> E1 --GAT1--> emb2 --GCN3--> E3 ----
  gcn(x, W1a, b1a, rowptrS, colS, dinvS, bufA, bufB, 1024, 512);
  gcn(bufB, W1b, b1b, rowptrS, colS, dinvS, bufA, E1buf, 512, 256);
  gat1(E1buf, Wg1a, as1a, ad1a, bg1a, rowptrA1, colA1, bufA, bufB);
  gat2(bufB, Wg1b, as1b, ad1b, bg1b, rowptrA1, colA1, bufA, Etmp);
  gcn(Etmp, W3a, b3a, rowptrS, colS, dinvS, bufA, bufB, 256, 128);
  gcn(bufB, W3b, b3b, rowptrS, colS, dinvS, bufA, E3buf, 128, 256);

  // ---- path 2: x --GCN2--> E4 --GAT2--> emb5 --GCN4--> E6 ----
  gcn(x, W2a, b2a, rowptrF, colF, dinvF, bufA, bufB, 1024, 512);
  gcn(bufB, W2b, b2b, rowptrF, colF, dinvF, bufA, E4buf, 512, 256);
  gat1(E4buf, Wg2a, as2a, ad2a, bg2a, rowptrA2, colA2, bufA, bufB);
  gat2(bufB, Wg2b, as2b, ad2b, bg2b, rowptrA2, colA2, bufA, Etmp);
  gcn(Etmp, W4a, b4a, rowptrF, colF, dinvF, bufA, bufB, 256, 128);
  gcn(bufB, W4b, b4b, rowptrF, colF, dinvF, bufA, E6buf, 128, 256);

  // ---- fusion + MLP + log_softmax ----
  final_k<<<N, 64, 0, stream>>>(E1buf, E3buf, E4buf, E6buf, aw1, ab1, aw2,
                                mw1, mb1, mw2, mb2, (float*)d_out, N);
}

// Round 5
// 2029.669 us; speedup vs baseline: 5.5409x; 1.6469x over previous
//
#include <hip/hip_runtime.h>
#include <cstddef>
#include <cstdint>
#include <cmath>

// ---------------------------------------------------------------------------
// HiGLDP forward, round 5: bf16 MFMA GEMMs (16x16x32), CSR-gather aggregation.
// Weights pre-transposed+cast to bf16 [F][K]; activations cast per GEMM.
// All aggregation / softmax / epilogues remain fp32.
// ---------------------------------------------------------------------------

static inline int cdiv(int a, int b) { return (a + b - 1) / b; }

typedef __attribute__((ext_vector_type(8))) unsigned short ush8;
typedef __attribute__((ext_vector_type(4))) unsigned short ush4;
typedef __attribute__((ext_vector_type(8))) short bf16x8;
typedef __attribute__((ext_vector_type(4))) float f32x4;

__device__ __forceinline__ unsigned short f2bf(float f) {
  unsigned u = __float_as_uint(f);
  unsigned r = 0x7fffu + ((u >> 16) & 1u);
  return (unsigned short)((u + r) >> 16);
}

// ---------------- CSR build ----------------
__global__ void zero_int_k(int* __restrict__ p, int n) {
  int i = blockIdx.x * 256 + threadIdx.x;
  if (i < n) p[i] = 0;
}
__global__ void hist_k(const int* __restrict__ dst, int* __restrict__ deg, int E) {
  int e = blockIdx.x * 256 + threadIdx.x;
  if (e < E) atomicAdd(&deg[dst[e]], 1);
}
__global__ __launch_bounds__(1024) void scan_k(const int* __restrict__ deg,
                                               int* __restrict__ rowptr,
                                               int* __restrict__ cursor, int N) {
  __shared__ int part[1024];
  const int t = threadIdx.x;
  const int CH = (N + 1023) / 1024;
  const int base = t * CH;
  int loc = 0;
  for (int i = 0; i < CH; ++i)
    if (base + i < N) loc += deg[base + i];
  part[t] = loc;
  __syncthreads();
  for (int off = 1; off < 1024; off <<= 1) {
    int v = (t >= off) ? part[t - off] : 0;
    __syncthreads();
    part[t] += v;
    __syncthreads();
  }
  int run = (t > 0) ? part[t - 1] : 0;
  for (int i = 0; i < CH; ++i)
    if (base + i < N) {
      rowptr[base + i] = run;
      cursor[base + i] = run;
      run += deg[base + i];
    }
  if (t == 1023) rowptr[N] = part[1023];
}
__global__ void place_k(const int* __restrict__ src, const int* __restrict__ dst,
                        int* __restrict__ cursor, int* __restrict__ col, int E) {
  int e = blockIdx.x * 256 + threadIdx.x;
  if (e < E) {
    int p = atomicAdd(&cursor[dst[e]], 1);
    col[p] = src[e];
  }
}
__global__ void dinv_k(const int* __restrict__ deg, float* __restrict__ dinv, int N) {
  int i = blockIdx.x * 256 + threadIdx.x;
  if (i < N) dinv[i] = rsqrtf((float)deg[i] + 1.f);
}

// ---------------- casts ----------------
__global__ void cast_bf16_k(const float* __restrict__ in, unsigned short* __restrict__ out,
                            int n4) {
  int i = blockIdx.x * 256 + threadIdx.x;
  if (i >= n4) return;
  float4 v = reinterpret_cast<const float4*>(in)[i];
  ush4 o;
  o.x = f2bf(v.x); o.y = f2bf(v.y); o.z = f2bf(v.z); o.w = f2bf(v.w);
  reinterpret_cast<ush4*>(out)[i] = o;
}

// Wt[f][k] = bf16(W[k][f]); K,F multiples of 32
__global__ __launch_bounds__(256) void transpose_cast_k(const float* __restrict__ W,
                                                        unsigned short* __restrict__ Wt,
                                                        int K, int F) {
  __shared__ float t[32][33];
  int bk = blockIdx.x * 32, bf = blockIdx.y * 32;
  int tx = threadIdx.x & 31, ty = threadIdx.x >> 5;  // 32 x 8
  for (int i = ty; i < 32; i += 8) t[i][tx] = W[(size_t)(bk + i) * F + bf + tx];
  __syncthreads();
  for (int i = ty; i < 32; i += 8)
    Wt[(size_t)(bf + i) * K + bk + tx] = f2bf(t[tx][i]);
}

// ---------------- bf16 MFMA GEMM: C[M,F] = A[M,K] @ Wt[F,K]^T ----------------
// 128x128 tile, BK=32, 4 waves (2x2), each wave 64x64 = 4x4 frags of 16x16x32.
#define LDT 40  // padded LDS row (bf16 elems): 80B -> 16-row frag reads 2-way free
__global__ __launch_bounds__(256) void gemm_bf16_k(
    const unsigned short* __restrict__ A,   // [M][K] bf16
    const unsigned short* __restrict__ Bt,  // [F][K] bf16
    float* __restrict__ C, int M, int K, int F) {
  __shared__ unsigned short Asl[128 * LDT];
  __shared__ unsigned short Bsl[128 * LDT];
  const int tid = threadIdx.x;
  const int wid = tid >> 6, lane = tid & 63;
  const int wr = (wid >> 1) * 64, wc = (wid & 1) * 64;
  const int bm = blockIdx.y * 128, bn = blockIdx.x * 128;
  const int l15 = lane & 15, lk = lane >> 4;
  f32x4 acc[4][4] = {};
  for (int k0 = 0; k0 < K; k0 += 32) {
    __syncthreads();
#pragma unroll
    for (int i = 0; i < 2; ++i) {
      int c = tid + i * 256;          // 0..511 chunk id
      int r = c >> 2;                 // 0..127
      int off = (c & 3) << 3;         // 0,8,16,24 (bf16 elems)
      int gr = bm + r;
      ush8 av = {};
      if (gr < M) av = *reinterpret_cast<const ush8*>(A + (size_t)gr * K + k0 + off);
      *reinterpret_cast<ush8*>(&Asl[r * LDT + off]) = av;
      ush8 bv = *reinterpret_cast<const ush8*>(Bt + (size_t)(bn + r) * K + k0 + off);
      *reinterpret_cast<ush8*>(&Bsl[r * LDT + off]) = bv;
    }
    __syncthreads();
    bf16x8 af[4], bfv[4];
#pragma unroll
    for (int mi = 0; mi < 4; ++mi)
      af[mi] = *reinterpret_cast<const bf16x8*>(&Asl[(wr + mi * 16 + l15) * LDT + (lk << 3)]);
#pragma unroll
    for (int ni = 0; ni < 4; ++ni)
      bfv[ni] = *reinterpret_cast<const bf16x8*>(&Bsl[(wc + ni * 16 + l15) * LDT + (lk << 3)]);
#pragma unroll
    for (int mi = 0; mi < 4; ++mi)
#pragma unroll
      for (int ni = 0; ni < 4; ++ni)
        acc[mi][ni] = __builtin_amdgcn_mfma_f32_16x16x32_bf16(af[mi], bfv[ni], acc[mi][ni], 0, 0, 0);
  }
  // C/D layout (m89/m91): col = lane&15, row = (lane>>4)*4 + reg
#pragma unroll
  for (int mi = 0; mi < 4; ++mi) {
    int gr0 = bm + wr + mi * 16 + (lk << 2);
#pragma unroll
    for (int ni = 0; ni < 4; ++ni) {
      int gc = bn + wc + ni * 16 + l15;
#pragma unroll
      for (int r4 = 0; r4 < 4; ++r4) {
        int gr = gr0 + r4;
        if (gr < M) C[(size_t)gr * F + gc] = acc[mi][ni][r4];
      }
    }
  }
}

// ---------------- GCN: per-dst gather + self + bias + relu ----------------
__global__ __launch_bounds__(256) void gcn_gather_k(
    const float* __restrict__ h, const int* __restrict__ rowptr,
    const int* __restrict__ col, const float* __restrict__ dinv,
    const float* __restrict__ bias, float* __restrict__ out, int F) {
  const int d = blockIdx.x;
  const int tid = threadIdx.x;
  const int beg = rowptr[d], end = rowptr[d + 1];
  const float di = dinv[d];
  const int f0 = tid, f1 = tid + 256;
  float a0 = 0.f, a1 = 0.f;
  if (f0 < F) a0 = h[(size_t)d * F + f0] * (di * di);
  if (f1 < F) a1 = h[(size_t)d * F + f1] * (di * di);
  for (int p = beg; p < end; ++p) {
    int s = col[p];
    float w = dinv[s] * di;
    if (f0 < F) a0 += h[(size_t)s * F + f0] * w;
    if (f1 < F) a1 += h[(size_t)s * F + f1] * w;
  }
  if (f0 < F) out[(size_t)d * F + f0] = fmaxf(a0 + bias[f0], 0.f);
  if (f1 < F) out[(size_t)d * F + f1] = fmaxf(a1 + bias[f1], 0.f);
}

// ---------------- GAT pieces ----------------
__global__ void gat_attn_k(const float* __restrict__ h, const float* __restrict__ a_s,
                           const float* __restrict__ a_d, float* __restrict__ asrc,
                           float* __restrict__ adst, int N, int H, int C) {
  int i = blockIdx.x * 256 + threadIdx.x;
  if (i >= N * H) return;
  int n = i / H, hh = i - n * H;
  const float* hp = h + (size_t)n * H * C + hh * C;
  const float* as = a_s + hh * C;
  const float* ad = a_d + hh * C;
  float s1 = 0.f, s2 = 0.f;
  for (int c = 0; c < C; ++c) { float v = hp[c]; s1 += v * as[c]; s2 += v * ad[c]; }
  asrc[i] = s1; adst[i] = s2;
}

template <int H, int C, int EPI>
__global__ __launch_bounds__(256) void gat_fused_k(
    const float* __restrict__ h, const float* __restrict__ asrc,
    const float* __restrict__ adst, const int* __restrict__ rowptr,
    const int* __restrict__ col, const float* __restrict__ bias,
    float* __restrict__ out) {
  constexpr int F = H * C;
  constexpr int FPT = F / 256;
  const int d = blockIdx.x;
  const int tid = threadIdx.x;
  const int lane = tid & 63, wv = tid >> 6;
  const int beg = rowptr[d], end = rowptr[d + 1];
  __shared__ float sred[2][4][H > 4 ? H : 4];

  float ad[H], vself[H];
#pragma unroll
  for (int k = 0; k < H; ++k) {
    ad[k] = adst[d * H + k];
    float v = asrc[d * H + k] + ad[k];
    vself[k] = v > 0.f ? v : 0.2f * v;
  }
  float mx[H];
#pragma unroll
  for (int k = 0; k < H; ++k) mx[k] = vself[k];
  for (int p = beg + tid; p < end; p += 256) {
    int s = col[p];
#pragma unroll
    for (int k = 0; k < H; ++k) {
      float v = asrc[s * H + k] + ad[k];
      v = v > 0.f ? v : 0.2f * v;
      mx[k] = fmaxf(mx[k], v);
    }
  }
#pragma unroll
  for (int off = 32; off >= 1; off >>= 1)
#pragma unroll
    for (int k = 0; k < H; ++k) mx[k] = fmaxf(mx[k], __shfl_xor(mx[k], off));
  if (lane == 0)
#pragma unroll
    for (int k = 0; k < H; ++k) sred[0][wv][k] = mx[k];
  __syncthreads();
  float m[H];
#pragma unroll
  for (int k = 0; k < H; ++k)
    m[k] = fmaxf(fmaxf(sred[0][0][k], sred[0][1][k]),
                 fmaxf(sred[0][2][k], sred[0][3][k]));
  float dn[H];
#pragma unroll
  for (int k = 0; k < H; ++k) dn[k] = 0.f;
  for (int p = beg + tid; p < end; p += 256) {
    int s = col[p];
#pragma unroll
    for (int k = 0; k < H; ++k) {
      float v = asrc[s * H + k] + ad[k];
      v = v > 0.f ? v : 0.2f * v;
      dn[k] += __expf(v - m[k]);
    }
  }
#pragma unroll
  for (int off = 32; off >= 1; off >>= 1)
#pragma unroll
    for (int k = 0; k < H; ++k) dn[k] += __shfl_xor(dn[k], off);
  if (lane == 0)
#pragma unroll
    for (int k = 0; k < H; ++k) sred[1][wv][k] = dn[k];
  __syncthreads();
  float invD[H];
#pragma unroll
  for (int k = 0; k < H; ++k) {
    float t = sred[1][0][k] + sred[1][1][k] + sred[1][2][k] + sred[1][3][k];
    invD[k] = 1.f / (t + __expf(vself[k] - m[k]) + 1e-16f);
  }
  float acc[FPT];
  int f[FPT], hh[FPT];
#pragma unroll
  for (int i = 0; i < FPT; ++i) {
    f[i] = tid + i * 256;
    hh[i] = f[i] / C;
    float aself = __expf(vself[hh[i]] - m[hh[i]]) * invD[hh[i]];
    acc[i] = aself * h[(size_t)d * F + f[i]];
  }
  for (int p = beg; p < end; ++p) {
    int s = col[p];
#pragma unroll
    for (int i = 0; i < FPT; ++i) {
      int k = hh[i];
      float v = asrc[s * H + k] + ad[k];
      v = v > 0.f ? v : 0.2f * v;
      float a = __expf(v - m[k]) * invD[k];
      acc[i] += a * h[(size_t)s * F + f[i]];
    }
  }
  if (EPI == 0) {
#pragma unroll
    for (int i = 0; i < FPT; ++i) {
      float v = acc[i] + bias[f[i]];
      out[(size_t)d * F + f[i]] = v > 0.f ? v : (__expf(v) - 1.f);
    }
  } else {
    float v = acc[0] + bias[tid];
    float r = v;
#pragma unroll
    for (int off = 32; off >= 1; off >>= 1) r = fmaxf(r, __shfl_xor(r, off));
    __syncthreads();
    if (lane == 0) sred[0][wv][0] = r;
    __syncthreads();
    float m2 = fmaxf(fmaxf(sred[0][0][0], sred[0][1][0]),
                     fmaxf(sred[0][2][0], sred[0][3][0]));
    float e = __expf(v - m2);
    float se = e;
#pragma unroll
    for (int off = 32; off >= 1; off >>= 1) se += __shfl_xor(se, off);
    if (lane == 0) sred[1][wv][0] = se;
    __syncthreads();
    float tot = sred[1][0][0] + sred[1][1][0] + sred[1][2][0] + sred[1][3][0];
    float y = v - m2 - logf(tot);
    out[(size_t)d * F + tid] = fmaxf(y, 0.f);
  }
}

// ---------------- final attention-fusion + MLP + log_softmax ----------------
__global__ __launch_bounds__(64) void final_k(const float* __restrict__ E1,
                                              const float* __restrict__ E3,
                                              const float* __restrict__ E4,
                                              const float* __restrict__ E6,
                                              const float* __restrict__ aw1,
                                              const float* __restrict__ ab1,
                                              const float* __restrict__ aw2,
                                              const float* __restrict__ mw1,
                                              const float* __restrict__ mb1,
                                              const float* __restrict__ mw2,
                                              const float* __restrict__ mb2,
                                              float* __restrict__ out, int N) {
  int n = blockIdx.x;
  int l = threadIdx.x;
  __shared__ float z[2][512];
  __shared__ float hsh[64];
  __shared__ float o7[8];
  for (int c = l; c < 256; c += 64) {
    z[0][c]       = E1[(size_t)n * 256 + c];
    z[0][256 + c] = E3[(size_t)n * 256 + c];
    z[1][c]       = E4[(size_t)n * 256 + c];
    z[1][256 + c] = E6[(size_t)n * 256 + c];
  }
  __syncthreads();
  float wv[2];
  for (int r = 0; r < 2; ++r) {
    float t = 0.f;
    if (l < 16) {
      float acc = ab1[l];
      for (int c = 0; c < 512; ++c) acc += z[r][c] * aw1[c * 16 + l];
      t = tanhf(acc) * aw2[l];
    }
    for (int off = 8; off >= 1; off >>= 1) t += __shfl_xor(t, off);
    wv[r] = __shfl(t, 0);
  }
  float mx = fmaxf(wv[0], wv[1]);
  float e0 = expf(wv[0] - mx), e1 = expf(wv[1] - mx);
  float inv = 1.f / (e0 + e1);
  float b0 = e0 * inv, b1 = e1 * inv;
  float acc = mb1[l];
  for (int c = 0; c < 512; ++c) acc += (b0 * z[0][c] + b1 * z[1][c]) * mw1[c * 64 + l];
  hsh[l] = tanhf(acc);
  __syncthreads();
  if (l < 7) {
    float o = mb2[l];
    for (int j = 0; j < 64; ++j) o += hsh[j] * mw2[j * 7 + l];
    o7[l] = o;
  }
  __syncthreads();
  if (l == 0) {
    float m = o7[0];
    for (int k = 1; k < 7; ++k) m = fmaxf(m, o7[k]);
    float s = 0.f;
    for (int k = 0; k < 7; ++k) s += expf(o7[k] - m);
    float ls = logf(s);
    for (int k = 0; k < 7; ++k) out[(size_t)n * 7 + k] = o7[k] - m - ls;
  }
}

// ---------------------------------------------------------------------------
extern "C" void kernel_launch(void* const* d_in, const int* in_sizes, int n_in,
                              void* d_out, int out_size, void* d_ws, size_t ws_size,
                              hipStream_t stream) {
  (void)n_in; (void)out_size; (void)ws_size;
  const float* x     = (const float*)d_in[0];
  const int*   sadj  = (const int*)d_in[1];
  const int*   fadj  = (const int*)d_in[2];
  const int*   asadj = (const int*)d_in[3];
  const int*   afadj = (const int*)d_in[4];
  const float* W1a = (const float*)d_in[5];  const float* b1a = (const float*)d_in[6];
  const float* W1b = (const float*)d_in[7];  const float* b1b = (const float*)d_in[8];
  const float* W2a = (const float*)d_in[9];  const float* b2a = (const float*)d_in[10];
  const float* W2b = (const float*)d_in[11]; const float* b2b = (const float*)d_in[12];
  const float* W3a = (const float*)d_in[13]; const float* b3a = (const float*)d_in[14];
  const float* W3b = (const float*)d_in[15]; const float* b3b = (const float*)d_in[16];
  const float* W4a = (const float*)d_in[17]; const float* b4a = (const float*)d_in[18];
  const float* W4b = (const float*)d_in[19]; const float* b4b = (const float*)d_in[20];
  const float* Wg1a = (const float*)d_in[21]; const float* as1a = (const float*)d_in[22];
  const float* ad1a = (const float*)d_in[23]; const float* bg1a = (const float*)d_in[24];
  const float* Wg1b = (const float*)d_in[25]; const float* as1b = (const float*)d_in[26];
  const float* ad1b = (const float*)d_in[27]; const float* bg1b = (const float*)d_in[28];
  const float* Wg2a = (const float*)d_in[29]; const float* as2a = (const float*)d_in[30];
  const float* ad2a = (const float*)d_in[31]; const float* bg2a = (const float*)d_in[32];
  const float* Wg2b = (const float*)d_in[33]; const float* as2b = (const float*)d_in[34];
  const float* ad2b = (const float*)d_in[35]; const float* bg2b = (const float*)d_in[36];
  const float* aw1 = (const float*)d_in[37]; const float* ab1 = (const float*)d_in[38];
  const float* aw2 = (const float*)d_in[39];
  const float* mw1 = (const float*)d_in[40]; const float* mb1 = (const float*)d_in[41];
  const float* mw2 = (const float*)d_in[42]; const float* mb2 = (const float*)d_in[43];

  const int N = in_sizes[0] / 1024;   // 20000
  const int E = in_sizes[1] / 2;      // 160000

  // ---- workspace layout ----
  float* ws = (float*)d_ws;
  float* bufA  = ws;                          // N*512 (gemm out h)
  float* bufB  = bufA + (size_t)N * 512;      // N*512 (agg out / Etmp alias)
  float* E1buf = bufB + (size_t)N * 512;      // N*256
  float* E3buf = E1buf + (size_t)N * 256;     // N*256
  float* E4buf = E3buf + (size_t)N * 256;     // N*256
  float* E6buf = E4buf + (size_t)N * 256;     // N*256
  float* dinvS = E6buf + (size_t)N * 256;     // N
  float* dinvF = dinvS + N;                   // N
  float* asrcB = dinvF + N;                   // N*4
  float* adstB = asrcB + (size_t)N * 4;       // N*4
  int* ib = (int*)(adstB + (size_t)N * 4);
  int* rowptrS = ib;            ib += N + 1;
  int* rowptrF = ib;            ib += N + 1;
  int* rowptrA1 = ib;           ib += N + 1;
  int* rowptrA2 = ib;           ib += N + 1;
  int* colS = ib;               ib += E;
  int* colF = ib;               ib += E;
  int* colA1 = ib;              ib += E;
  int* colA2 = ib;              ib += E;
  int* degI = ib;               ib += N;
  int* cursor = ib;             ib += N;
  unsigned short* ub = (unsigned short*)(ib + ((size_t)(-(intptr_t)ib) & 3));
  unsigned short* xb = ub;            ub += (size_t)N * 1024;  // bf16(x)
  unsigned short* ab = ub;            ub += (size_t)N * 512;   // bf16 activations
  unsigned short* Wt1a = ub;  ub += 1024 * 512;
  unsigned short* Wt1b = ub;  ub += 512 * 256;
  unsigned short* Wt2a = ub;  ub += 1024 * 512;
  unsigned short* Wt2b = ub;  ub += 512 * 256;
  unsigned short* Wt3a = ub;  ub += 256 * 128;
  unsigned short* Wt3b = ub;  ub += 128 * 256;
  unsigned short* Wt4a = ub;  ub += 256 * 128;
  unsigned short* Wt4b = ub;  ub += 128 * 256;
  unsigned short* Wtg1a = ub; ub += 256 * 512;
  unsigned short* Wtg1b = ub; ub += 512 * 256;
  unsigned short* Wtg2a = ub; ub += 256 * 512;
  unsigned short* Wtg2b = ub; ub += 512 * 256;
  float* Etmp = bufB;  // alias: safe (bufB consumed via cast before reuse)

  // ---- weight transpose+cast (12) ----
  auto tc = [&](const float* W, unsigned short* Wt, int K, int F) {
    transpose_cast_k<<<dim3(K / 32, F / 32), 256, 0, stream>>>(W, Wt, K, F);
  };
  tc(W1a, Wt1a, 1024, 512); tc(W1b, Wt1b, 512, 256);
  tc(W2a, Wt2a, 1024, 512); tc(W2b, Wt2b, 512, 256);
  tc(W3a, Wt3a, 256, 128);  tc(W3b, Wt3b, 128, 256);
  tc(W4a, Wt4a, 256, 128);  tc(W4b, Wt4b, 128, 256);
  tc(Wg1a, Wtg1a, 256, 512); tc(Wg1b, Wtg1b, 512, 256);
  tc(Wg2a, Wtg2a, 256, 512); tc(Wg2b, Wtg2b, 512, 256);
  cast_bf16_k<<<cdiv(N * 1024 / 4, 256), 256, 0, stream>>>(x, xb, N * 1024 / 4);

  // ---- CSR builds ----
  auto build = [&](const int* ei, int* rowptr, int* col, float* dinv) {
    zero_int_k<<<cdiv(N, 256), 256, 0, stream>>>(degI, N);
    hist_k<<<cdiv(E, 256), 256, 0, stream>>>(ei + E, degI, E);
    scan_k<<<1, 1024, 0, stream>>>(degI, rowptr, cursor, N);
    if (dinv) dinv_k<<<cdiv(N, 256), 256, 0, stream>>>(degI, dinv, N);
    place_k<<<cdiv(E, 256), 256, 0, stream>>>(ei, ei + E, cursor, col, E);
  };
  build(sadj, rowptrS, colS, dinvS);
  build(fadj, rowptrF, colF, dinvF);
  build(asadj, rowptrA1, colA1, nullptr);
  build(afadj, rowptrA2, colA2, nullptr);

  auto gemmB = [&](const unsigned short* Ab, const unsigned short* Wt, float* Cm,
                   int K, int F) {
    gemm_bf16_k<<<dim3(F / 128, cdiv(N, 128)), 256, 0, stream>>>(Ab, Wt, Cm, N, K, F);
  };
  auto cast = [&](const float* src, int total) {
    cast_bf16_k<<<cdiv(total / 4, 256), 256, 0, stream>>>(src, ab, total / 4);
  };
  auto gcnB = [&](const unsigned short* inb, const unsigned short* Wt, const float* b,
                  const int* rowptr, const int* col, const float* dinv, float* out,
                  int K, int F) {
    gemmB(inb, Wt, bufA, K, F);
    gcn_gather_k<<<N, 256, 0, stream>>>(bufA, rowptr, col, dinv, b, out, F);
  };
  auto gat1B = [&](const unsigned short* inb, const unsigned short* Wt, const float* a_s,
                   const float* a_d, const float* b, const int* rowptr, const int* col,
                   float* out) {
    gemmB(inb, Wt, bufA, 256, 512);
    gat_attn_k<<<cdiv(N * 4, 256), 256, 0, stream>>>(bufA, a_s, a_d, asrcB, adstB, N, 4, 128);
    gat_fused_k<4, 128, 0><<<N, 256, 0, stream>>>(bufA, asrcB, adstB, rowptr, col, b, out);
  };
  auto gat2B = [&](const unsigned short* inb, const unsigned short* Wt, const float* a_s,
                   const float* a_d, const float* b, const int* rowptr, const int* col,
                   float* out) {
    gemmB(inb, Wt, bufA, 512, 256);
    gat_attn_k<<<cdiv(N, 256), 256, 0, stream>>>(bufA, a_s, a_d, asrcB, adstB, N, 1, 256);
    gat_fused_k<1, 256, 1><<<N, 256, 0, stream>>>(bufA, asrcB, adstB, rowptr, col, b, out);
  };

  // ---- path 1: x --GCN1--> E1 --GAT1--> emb2 --GCN3--> E3 ----
  gcnB(xb, Wt1a, b1a, rowptrS, colS, dinvS, bufB, 1024, 512);
  cast(bufB, N * 512);
  gcnB(ab, Wt1b, b1b, rowptrS, colS, dinvS, E1buf, 512, 256);
  cast(E1buf, N * 256);
  gat1B(ab, Wtg1a, as1a, ad1a, bg1a, rowptrA1, colA1, bufB);
  cast(bufB, N * 512);
  gat2B(ab, Wtg1b, as1b, ad1b, bg1b, rowptrA1, colA1, Etmp);
  cast(Etmp, N * 256);
  gcnB(ab, Wt3a, b3a, rowptrS, colS, dinvS, bufB, 256, 128);
  cast(bufB, N * 128);
  gcnB(ab, Wt3b, b3b, rowptrS, colS, dinvS, E3buf, 128, 256);

  // ---- path 2: x --GCN2--> E4 --GAT2--> emb5 --GCN4--> E6 ----
  gcnB(xb, Wt2a, b2a, rowptrF, colF, dinvF, bufB, 1024, 512);
  cast(bufB, N * 512);
  gcnB(ab, Wt2b, b2b, rowptrF, colF, dinvF, E4buf, 512, 256);
  cast(E4buf, N * 256);
  gat1B(ab, Wtg2a, as2a, ad2a, bg2a, rowptrA2, colA2, bufB);
  cast(bufB, N * 512);
  gat2B(ab, Wtg2b, as2b, ad2b, bg2b, rowptrA2, colA2, Etmp);
  cast(Etmp, N * 256);
  gcnB(ab, Wt4a, b4a, rowptrF, colF, dinvF, bufB, 256, 128);
  cast(bufB, N * 128);
  gcnB(ab, Wt4b, b4b, rowptrF, colF, dinvF, E6buf, 128, 256);

  // ---- fusion + MLP + log_softmax ----
  final_k<<<N, 64, 0, stream>>>(E1buf, E3buf, E4buf, E6buf, aw1, ab1, aw2,
                                mw1, mb1, mw2, mb2, (float*)d_out, N);
}

// Round 6
// 1716.423 us; speedup vs baseline: 6.5522x; 1.1825x over previous
//
#include <hip/hip_runtime.h>
#include <cstddef>
#include <cstdint>
#include <cmath>

// ---------------------------------------------------------------------------
// HiGLDP forward, round 6: bf16 MFMA GEMMs + CSR gather; casts fused into
// epilogues; final fusion-MLP rewritten (8 nodes/block, full-lane phases).
// ---------------------------------------------------------------------------

static inline int cdiv(int a, int b) { return (a + b - 1) / b; }

typedef __attribute__((ext_vector_type(8))) unsigned short ush8;
typedef __attribute__((ext_vector_type(4))) unsigned short ush4;
typedef __attribute__((ext_vector_type(8))) short bf16x8;
typedef __attribute__((ext_vector_type(4))) float f32x4;

__device__ __forceinline__ unsigned short f2bf(float f) {
  unsigned u = __float_as_uint(f);
  unsigned r = 0x7fffu + ((u >> 16) & 1u);
  return (unsigned short)((u + r) >> 16);
}

// ---------------- CSR build ----------------
__global__ void zero_int_k(int* __restrict__ p, int n) {
  int i = blockIdx.x * 256 + threadIdx.x;
  if (i < n) p[i] = 0;
}
__global__ void hist_k(const int* __restrict__ dst, int* __restrict__ deg, int E) {
  int e = blockIdx.x * 256 + threadIdx.x;
  if (e < E) atomicAdd(&deg[dst[e]], 1);
}
__global__ __launch_bounds__(1024) void scan_k(const int* __restrict__ deg,
                                               int* __restrict__ rowptr,
                                               int* __restrict__ cursor, int N) {
  __shared__ int part[1024];
  const int t = threadIdx.x;
  const int CH = (N + 1023) / 1024;
  const int base = t * CH;
  int loc = 0;
  for (int i = 0; i < CH; ++i)
    if (base + i < N) loc += deg[base + i];
  part[t] = loc;
  __syncthreads();
  for (int off = 1; off < 1024; off <<= 1) {
    int v = (t >= off) ? part[t - off] : 0;
    __syncthreads();
    part[t] += v;
    __syncthreads();
  }
  int run = (t > 0) ? part[t - 1] : 0;
  for (int i = 0; i < CH; ++i)
    if (base + i < N) {
      rowptr[base + i] = run;
      cursor[base + i] = run;
      run += deg[base + i];
    }
  if (t == 1023) rowptr[N] = part[1023];
}
__global__ void place_k(const int* __restrict__ src, const int* __restrict__ dst,
                        int* __restrict__ cursor, int* __restrict__ col, int E) {
  int e = blockIdx.x * 256 + threadIdx.x;
  if (e < E) {
    int p = atomicAdd(&cursor[dst[e]], 1);
    col[p] = src[e];
  }
}
__global__ void dinv_k(const int* __restrict__ deg, float* __restrict__ dinv, int N) {
  int i = blockIdx.x * 256 + threadIdx.x;
  if (i < N) dinv[i] = rsqrtf((float)deg[i] + 1.f);
}

// ---------------- casts ----------------
__global__ void cast_bf16_k(const float* __restrict__ in, unsigned short* __restrict__ out,
                            int n4) {
  int i = blockIdx.x * 256 + threadIdx.x;
  if (i >= n4) return;
  float4 v = reinterpret_cast<const float4*>(in)[i];
  ush4 o;
  o.x = f2bf(v.x); o.y = f2bf(v.y); o.z = f2bf(v.z); o.w = f2bf(v.w);
  reinterpret_cast<ush4*>(out)[i] = o;
}

// Wt[f][k] = bf16(W[k][f]); K,F multiples of 32
__global__ __launch_bounds__(256) void transpose_cast_k(const float* __restrict__ W,
                                                        unsigned short* __restrict__ Wt,
                                                        int K, int F) {
  __shared__ float t[32][33];
  int bk = blockIdx.x * 32, bf = blockIdx.y * 32;
  int tx = threadIdx.x & 31, ty = threadIdx.x >> 5;
  for (int i = ty; i < 32; i += 8) t[i][tx] = W[(size_t)(bk + i) * F + bf + tx];
  __syncthreads();
  for (int i = ty; i < 32; i += 8)
    Wt[(size_t)(bf + i) * K + bk + tx] = f2bf(t[tx][i]);
}

// ---------------- bf16 MFMA GEMM: C[M,F] = A[M,K] @ Wt[F,K]^T ----------------
#define LDT 40
__global__ __launch_bounds__(256) void gemm_bf16_k(
    const unsigned short* __restrict__ A,
    const unsigned short* __restrict__ Bt,
    float* __restrict__ C, int M, int K, int F) {
  __shared__ unsigned short Asl[128 * LDT];
  __shared__ unsigned short Bsl[128 * LDT];
  const int tid = threadIdx.x;
  const int wid = tid >> 6, lane = tid & 63;
  const int wr = (wid >> 1) * 64, wc = (wid & 1) * 64;
  const int bm = blockIdx.y * 128, bn = blockIdx.x * 128;
  const int l15 = lane & 15, lk = lane >> 4;
  f32x4 acc[4][4] = {};
  for (int k0 = 0; k0 < K; k0 += 32) {
    __syncthreads();
#pragma unroll
    for (int i = 0; i < 2; ++i) {
      int c = tid + i * 256;
      int r = c >> 2;
      int off = (c & 3) << 3;
      int gr = bm + r;
      ush8 av = {};
      if (gr < M) av = *reinterpret_cast<const ush8*>(A + (size_t)gr * K + k0 + off);
      *reinterpret_cast<ush8*>(&Asl[r * LDT + off]) = av;
      ush8 bv = *reinterpret_cast<const ush8*>(Bt + (size_t)(bn + r) * K + k0 + off);
      *reinterpret_cast<ush8*>(&Bsl[r * LDT + off]) = bv;
    }
    __syncthreads();
    bf16x8 af[4], bfv[4];
#pragma unroll
    for (int mi = 0; mi < 4; ++mi)
      af[mi] = *reinterpret_cast<const bf16x8*>(&Asl[(wr + mi * 16 + l15) * LDT + (lk << 3)]);
#pragma unroll
    for (int ni = 0; ni < 4; ++ni)
      bfv[ni] = *reinterpret_cast<const bf16x8*>(&Bsl[(wc + ni * 16 + l15) * LDT + (lk << 3)]);
#pragma unroll
    for (int mi = 0; mi < 4; ++mi)
#pragma unroll
      for (int ni = 0; ni < 4; ++ni)
        acc[mi][ni] = __builtin_amdgcn_mfma_f32_16x16x32_bf16(af[mi], bfv[ni], acc[mi][ni], 0, 0, 0);
  }
#pragma unroll
  for (int mi = 0; mi < 4; ++mi) {
    int gr0 = bm + wr + mi * 16 + (lk << 2);
#pragma unroll
    for (int ni = 0; ni < 4; ++ni) {
      int gc = bn + wc + ni * 16 + l15;
#pragma unroll
      for (int r4 = 0; r4 < 4; ++r4) {
        int gr = gr0 + r4;
        if (gr < M) C[(size_t)gr * F + gc] = acc[mi][ni][r4];
      }
    }
  }
}

// ---------------- GCN: per-dst gather + self + bias + relu + cast ----------
// MODE: 0 = fp32 only, 1 = bf16 only, 2 = both
template <int MODE>
__global__ __launch_bounds__(256) void gcn_gather_k(
    const float* __restrict__ h, const int* __restrict__ rowptr,
    const int* __restrict__ col, const float* __restrict__ dinv,
    const float* __restrict__ bias, float* __restrict__ outf,
    unsigned short* __restrict__ outb, int F) {
  const int d = blockIdx.x;
  const int tid = threadIdx.x;
  const int beg = rowptr[d], end = rowptr[d + 1];
  const float di = dinv[d];
  const int f0 = tid, f1 = tid + 256;
  float a0 = 0.f, a1 = 0.f;
  if (f0 < F) a0 = h[(size_t)d * F + f0] * (di * di);
  if (f1 < F) a1 = h[(size_t)d * F + f1] * (di * di);
  for (int p = beg; p < end; ++p) {
    int s = col[p];
    float w = dinv[s] * di;
    if (f0 < F) a0 += h[(size_t)s * F + f0] * w;
    if (f1 < F) a1 += h[(size_t)s * F + f1] * w;
  }
  if (f0 < F) {
    float v = fmaxf(a0 + bias[f0], 0.f);
    if (MODE != 1) outf[(size_t)d * F + f0] = v;
    if (MODE != 0) outb[(size_t)d * F + f0] = f2bf(v);
  }
  if (f1 < F) {
    float v = fmaxf(a1 + bias[f1], 0.f);
    if (MODE != 1) outf[(size_t)d * F + f1] = v;
    if (MODE != 0) outb[(size_t)d * F + f1] = f2bf(v);
  }
}

// ---------------- GAT: attention logits (coalesced, block-per-node) --------
template <int H, int C>
__global__ __launch_bounds__(256) void gat_attn2_k(
    const float* __restrict__ h, const float* __restrict__ a_s,
    const float* __restrict__ a_d, float* __restrict__ asrc,
    float* __restrict__ adst) {
  constexpr int TPH = 256 / H;  // threads per head
  const int n = blockIdx.x;
  const int t = threadIdx.x;
  const int head = t / TPH;
  const int lt = t % TPH;
  float s1 = 0.f, s2 = 0.f;
  for (int c = lt; c < C; c += TPH) {
    float v = h[(size_t)n * H * C + head * C + c];
    s1 += v * a_s[head * C + c];
    s2 += v * a_d[head * C + c];
  }
#pragma unroll
  for (int off = 32; off >= 1; off >>= 1) {
    s1 += __shfl_xor(s1, off);
    s2 += __shfl_xor(s2, off);
  }
  if (H == 1) {
    __shared__ float p1[4], p2[4];
    if ((t & 63) == 0) { p1[t >> 6] = s1; p2[t >> 6] = s2; }
    __syncthreads();
    if (t == 0) {
      asrc[n] = p1[0] + p1[1] + p1[2] + p1[3];
      adst[n] = p2[0] + p2[1] + p2[2] + p2[3];
    }
  } else {
    if ((t & 63) == 0) { asrc[n * H + head] = s1; adst[n * H + head] = s2; }
  }
}

// ---------------- GAT fused softmax + aggregation (bf16 out) ----------------
template <int H, int C, int EPI>
__global__ __launch_bounds__(256) void gat_fused_k(
    const float* __restrict__ h, const float* __restrict__ asrc,
    const float* __restrict__ adst, const int* __restrict__ rowptr,
    const int* __restrict__ col, const float* __restrict__ bias,
    unsigned short* __restrict__ out) {
  constexpr int F = H * C;
  constexpr int FPT = F / 256;
  const int d = blockIdx.x;
  const int tid = threadIdx.x;
  const int lane = tid & 63, wv = tid >> 6;
  const int beg = rowptr[d], end = rowptr[d + 1];
  __shared__ float sred[2][4][H > 4 ? H : 4];

  float ad[H], vself[H];
#pragma unroll
  for (int k = 0; k < H; ++k) {
    ad[k] = adst[d * H + k];
    float v = asrc[d * H + k] + ad[k];
    vself[k] = v > 0.f ? v : 0.2f * v;
  }
  float mx[H];
#pragma unroll
  for (int k = 0; k < H; ++k) mx[k] = vself[k];
  for (int p = beg + tid; p < end; p += 256) {
    int s = col[p];
#pragma unroll
    for (int k = 0; k < H; ++k) {
      float v = asrc[s * H + k] + ad[k];
      v = v > 0.f ? v : 0.2f * v;
      mx[k] = fmaxf(mx[k], v);
    }
  }
#pragma unroll
  for (int off = 32; off >= 1; off >>= 1)
#pragma unroll
    for (int k = 0; k < H; ++k) mx[k] = fmaxf(mx[k], __shfl_xor(mx[k], off));
  if (lane == 0)
#pragma unroll
    for (int k = 0; k < H; ++k) sred[0][wv][k] = mx[k];
  __syncthreads();
  float m[H];
#pragma unroll
  for (int k = 0; k < H; ++k)
    m[k] = fmaxf(fmaxf(sred[0][0][k], sred[0][1][k]),
                 fmaxf(sred[0][2][k], sred[0][3][k]));
  float dn[H];
#pragma unroll
  for (int k = 0; k < H; ++k) dn[k] = 0.f;
  for (int p = beg + tid; p < end; p += 256) {
    int s = col[p];
#pragma unroll
    for (int k = 0; k < H; ++k) {
      float v = asrc[s * H + k] + ad[k];
      v = v > 0.f ? v : 0.2f * v;
      dn[k] += __expf(v - m[k]);
    }
  }
#pragma unroll
  for (int off = 32; off >= 1; off >>= 1)
#pragma unroll
    for (int k = 0; k < H; ++k) dn[k] += __shfl_xor(dn[k], off);
  if (lane == 0)
#pragma unroll
    for (int k = 0; k < H; ++k) sred[1][wv][k] = dn[k];
  __syncthreads();
  float invD[H];
#pragma unroll
  for (int k = 0; k < H; ++k) {
    float t = sred[1][0][k] + sred[1][1][k] + sred[1][2][k] + sred[1][3][k];
    invD[k] = 1.f / (t + __expf(vself[k] - m[k]) + 1e-16f);
  }
  float acc[FPT];
  int f[FPT], hh[FPT];
#pragma unroll
  for (int i = 0; i < FPT; ++i) {
    f[i] = tid + i * 256;
    hh[i] = f[i] / C;
    float aself = __expf(vself[hh[i]] - m[hh[i]]) * invD[hh[i]];
    acc[i] = aself * h[(size_t)d * F + f[i]];
  }
  for (int p = beg; p < end; ++p) {
    int s = col[p];
#pragma unroll
    for (int i = 0; i < FPT; ++i) {
      int k = hh[i];
      float v = asrc[s * H + k] + ad[k];
      v = v > 0.f ? v : 0.2f * v;
      float a = __expf(v - m[k]) * invD[k];
      acc[i] += a * h[(size_t)s * F + f[i]];
    }
  }
  if (EPI == 0) {
#pragma unroll
    for (int i = 0; i < FPT; ++i) {
      float v = acc[i] + bias[f[i]];
      v = v > 0.f ? v : (__expf(v) - 1.f);
      out[(size_t)d * F + f[i]] = f2bf(v);
    }
  } else {
    float v = acc[0] + bias[tid];
    float r = v;
#pragma unroll
    for (int off = 32; off >= 1; off >>= 1) r = fmaxf(r, __shfl_xor(r, off));
    __syncthreads();
    if (lane == 0) sred[0][wv][0] = r;
    __syncthreads();
    float m2 = fmaxf(fmaxf(sred[0][0][0], sred[0][1][0]),
                     fmaxf(sred[0][2][0], sred[0][3][0]));
    float e = __expf(v - m2);
    float se = e;
#pragma unroll
    for (int off = 32; off >= 1; off >>= 1) se += __shfl_xor(se, off);
    if (lane == 0) sred[1][wv][0] = se;
    __syncthreads();
    float tot = sred[1][0][0] + sred[1][1][0] + sred[1][2][0] + sred[1][3][0];
    float y = v - m2 - logf(tot);
    out[(size_t)d * F + tid] = f2bf(fmaxf(y, 0.f));
  }
}

// ---------------- final fusion + MLP + log_softmax (8 nodes/block) ----------
#define NPB 8
__global__ __launch_bounds__(256) void final2_k(
    const float* __restrict__ E1, const float* __restrict__ E3,
    const float* __restrict__ E4, const float* __restrict__ E6,
    const float* __restrict__ aw1, const float* __restrict__ ab1,
    const float* __restrict__ aw2, const float* __restrict__ mw1,
    const float* __restrict__ mb1, const float* __restrict__ mw2,
    const float* __restrict__ mb2, float* __restrict__ out, int N) {
  __shared__ float zsh[NPB][2][512];   // 32 KB; zsh[nd][0] later becomes emb
  __shared__ float wsh[NPB * 2][17];
  __shared__ float warr[NPB][2];
  __shared__ float bsh[NPB][2];
  __shared__ float hsh[NPB][64];
  __shared__ float o7sh[NPB][8];
  const int t = threadIdx.x;
  const int n0 = blockIdx.x * NPB;
  // ---- load z (each wave = one segment, float4 coalesced) ----
  {
    int seg = t >> 6, idx = t & 63;
    const float* sp = (seg == 0) ? E1 : (seg == 1) ? E3 : (seg == 2) ? E4 : E6;
    int r = seg >> 1, half = seg & 1;
    for (int nd = 0; nd < NPB; ++nd) {
      if (n0 + nd < N) {
        float4 v = reinterpret_cast<const float4*>(sp)[(size_t)(n0 + nd) * 64 + idx];
        reinterpret_cast<float4*>(&zsh[nd][r][half * 256])[idx] = v;
      }
    }
  }
  __syncthreads();
  // ---- aw1: 16 rows (8 nd x 2 r) x 16 cols, all 256 threads ----
  {
    int row = t >> 4, j = t & 15;
    int nd = row >> 1, r = row & 1;
    const float* zp = zsh[nd][r];
    float a0 = ab1[j], a1 = 0.f;
    for (int c = 0; c < 512; c += 2) {
      a0 += zp[c] * aw1[c * 16 + j];
      a1 += zp[c + 1] * aw1[(c + 1) * 16 + j];
    }
    wsh[row][j] = tanhf(a0 + a1) * aw2[j];
  }
  __syncthreads();
  if (t < 16) {
    float s = 0.f;
    for (int j = 0; j < 16; ++j) s += wsh[t][j];
    warr[t >> 1][t & 1] = s;
  }
  __syncthreads();
  if (t < NPB) {
    float w0 = warr[t][0], w1 = warr[t][1];
    float mxv = fmaxf(w0, w1);
    float e0 = __expf(w0 - mxv), e1 = __expf(w1 - mxv);
    float inv = 1.f / (e0 + e1);
    bsh[t][0] = e0 * inv; bsh[t][1] = e1 * inv;
  }
  __syncthreads();
  // ---- emb = b0*z0 + b1*z1 (overwrite zsh[nd][0]), conflict-free ----
  {
    int nd = t >> 5, l = t & 31;
    float b0 = bsh[nd][0], b1 = bsh[nd][1];
    for (int i = 0; i < 16; ++i) {
      int c = l + 32 * i;
      zsh[nd][0][c] = b0 * zsh[nd][0][c] + b1 * zsh[nd][1][c];
    }
  }
  __syncthreads();
  // ---- mw1: out o (64) x node pair (np, np+4) ----
  {
    int o = t & 63, np = t >> 6;
    float a0 = mb1[o], a1 = a0;
    for (int c = 0; c < 512; ++c) {
      float w = mw1[c * 64 + o];
      a0 += zsh[np][0][c] * w;
      a1 += zsh[np + 4][0][c] * w;
    }
    hsh[np][o] = tanhf(a0);
    hsh[np + 4][o] = tanhf(a1);
  }
  __syncthreads();
  if (t < NPB * 7) {
    int nd = t / 7, jo = t - nd * 7;
    float a = mb2[jo];
    for (int j = 0; j < 64; ++j) a += hsh[nd][j] * mw2[j * 7 + jo];
    o7sh[nd][jo] = a;
  }
  __syncthreads();
  if (t < NPB && n0 + t < N) {
    float m = o7sh[t][0];
    for (int k = 1; k < 7; ++k) m = fmaxf(m, o7sh[t][k]);
    float s = 0.f;
    for (int k = 0; k < 7; ++k) s += expf(o7sh[t][k] - m);
    float ls = logf(s);
    for (int k = 0; k < 7; ++k) out[(size_t)(n0 + t) * 7 + k] = o7sh[t][k] - m - ls;
  }
}

// ---------------------------------------------------------------------------
extern "C" void kernel_launch(void* const* d_in, const int* in_sizes, int n_in,
                              void* d_out, int out_size, void* d_ws, size_t ws_size,
                              hipStream_t stream) {
  (void)n_in; (void)out_size; (void)ws_size;
  const float* x     = (const float*)d_in[0];
  const int*   sadj  = (const int*)d_in[1];
  const int*   fadj  = (const int*)d_in[2];
  const int*   asadj = (const int*)d_in[3];
  const int*   afadj = (const int*)d_in[4];
  const float* W1a = (const float*)d_in[5];  const float* b1a = (const float*)d_in[6];
  const float* W1b = (const float*)d_in[7];  const float* b1b = (const float*)d_in[8];
  const float* W2a = (const float*)d_in[9];  const float* b2a = (const float*)d_in[10];
  const float* W2b = (const float*)d_in[11]; const float* b2b = (const float*)d_in[12];
  const float* W3a = (const float*)d_in[13]; const float* b3a = (const float*)d_in[14];
  const float* W3b = (const float*)d_in[15]; const float* b3b = (const float*)d_in[16];
  const float* W4a = (const float*)d_in[17]; const float* b4a = (const float*)d_in[18];
  const float* W4b = (const float*)d_in[19]; const float* b4b = (const float*)d_in[20];
  const float* Wg1a = (const float*)d_in[21]; const float* as1a = (const float*)d_in[22];
  const float* ad1a = (const float*)d_in[23]; const float* bg1a = (const float*)d_in[24];
  const float* Wg1b = (const float*)d_in[25]; const float* as1b = (const float*)d_in[26];
  const float* ad1b = (const float*)d_in[27]; const float* bg1b = (const float*)d_in[28];
  const float* Wg2a = (const float*)d_in[29]; const float* as2a = (const float*)d_in[30];
  const float* ad2a = (const float*)d_in[31]; const float* bg2a = (const float*)d_in[32];
  const float* Wg2b = (const float*)d_in[33]; const float* as2b = (const float*)d_in[34];
  const float* ad2b = (const float*)d_in[35]; const float* bg2b = (const float*)d_in[36];
  const float* aw1 = (const float*)d_in[37]; const float* ab1 = (const float*)d_in[38];
  const float* aw2 = (const float*)d_in[39];
  const float* mw1 = (const float*)d_in[40]; const float* mb1 = (const float*)d_in[41];
  const float* mw2 = (const float*)d_in[42]; const float* mb2 = (const float*)d_in[43];

  const int N = in_sizes[0] / 1024;   // 20000
  const int E = in_sizes[1] / 2;      // 160000

  // ---- workspace layout ----
  float* ws = (float*)d_ws;
  float* bufA  = ws;                          // N*512 (gemm out h, fp32)
  float* bufB  = bufA + (size_t)N * 512;      // N*512 (spare)
  float* E1buf = bufB + (size_t)N * 512;      // N*256
  float* E3buf = E1buf + (size_t)N * 256;     // N*256
  float* E4buf = E3buf + (size_t)N * 256;     // N*256
  float* E6buf = E4buf + (size_t)N * 256;     // N*256
  float* dinvS = E6buf + (size_t)N * 256;     // N
  float* dinvF = dinvS + N;                   // N
  float* asrcB = dinvF + N;                   // N*4
  float* adstB = asrcB + (size_t)N * 4;       // N*4
  int* ib = (int*)(adstB + (size_t)N * 4);
  int* rowptrS = ib;            ib += N + 1;
  int* rowptrF = ib;            ib += N + 1;
  int* rowptrA1 = ib;           ib += N + 1;
  int* rowptrA2 = ib;           ib += N + 1;
  int* colS = ib;               ib += E;
  int* colF = ib;               ib += E;
  int* colA1 = ib;              ib += E;
  int* colA2 = ib;              ib += E;
  int* degI = ib;               ib += N;
  int* cursor = ib;             ib += N;
  unsigned short* ub = (unsigned short*)(ib + ((size_t)(-(intptr_t)ib) & 3));
  unsigned short* xb = ub;            ub += (size_t)N * 1024;  // bf16(x)
  unsigned short* ab = ub;            ub += (size_t)N * 512;   // bf16 activations
  unsigned short* Wt1a = ub;  ub += 1024 * 512;
  unsigned short* Wt1b = ub;  ub += 512 * 256;
  unsigned short* Wt2a = ub;  ub += 1024 * 512;
  unsigned short* Wt2b = ub;  ub += 512 * 256;
  unsigned short* Wt3a = ub;  ub += 256 * 128;
  unsigned short* Wt3b = ub;  ub += 128 * 256;
  unsigned short* Wt4a = ub;  ub += 256 * 128;
  unsigned short* Wt4b = ub;  ub += 128 * 256;
  unsigned short* Wtg1a = ub; ub += 256 * 512;
  unsigned short* Wtg1b = ub; ub += 512 * 256;
  unsigned short* Wtg2a = ub; ub += 256 * 512;
  unsigned short* Wtg2b = ub; ub += 512 * 256;

  // ---- weight transpose+cast ----
  auto tc = [&](const float* W, unsigned short* Wt, int K, int F) {
    transpose_cast_k<<<dim3(K / 32, F / 32), 256, 0, stream>>>(W, Wt, K, F);
  };
  tc(W1a, Wt1a, 1024, 512); tc(W1b, Wt1b, 512, 256);
  tc(W2a, Wt2a, 1024, 512); tc(W2b, Wt2b, 512, 256);
  tc(W3a, Wt3a, 256, 128);  tc(W3b, Wt3b, 128, 256);
  tc(W4a, Wt4a, 256, 128);  tc(W4b, Wt4b, 128, 256);
  tc(Wg1a, Wtg1a, 256, 512); tc(Wg1b, Wtg1b, 512, 256);
  tc(Wg2a, Wtg2a, 256, 512); tc(Wg2b, Wtg2b, 512, 256);
  cast_bf16_k<<<cdiv(N * 1024 / 4, 256), 256, 0, stream>>>(x, xb, N * 1024 / 4);

  // ---- CSR builds ----
  auto build = [&](const int* ei, int* rowptr, int* col, float* dinv) {
    zero_int_k<<<cdiv(N, 256), 256, 0, stream>>>(degI, N);
    hist_k<<<cdiv(E, 256), 256, 0, stream>>>(ei + E, degI, E);
    scan_k<<<1, 1024, 0, stream>>>(degI, rowptr, cursor, N);
    if (dinv) dinv_k<<<cdiv(N, 256), 256, 0, stream>>>(degI, dinv, N);
    place_k<<<cdiv(E, 256), 256, 0, stream>>>(ei, ei + E, cursor, col, E);
  };
  build(sadj, rowptrS, colS, dinvS);
  build(fadj, rowptrF, colF, dinvF);
  build(asadj, rowptrA1, colA1, nullptr);
  build(afadj, rowptrA2, colA2, nullptr);

  auto gemmB = [&](const unsigned short* Ab, const unsigned short* Wt, int K, int F) {
    gemm_bf16_k<<<dim3(F / 128, cdiv(N, 128)), 256, 0, stream>>>(Ab, Wt, bufA, N, K, F);
  };
  // gcn: MODE 0 fp32-only, 1 bf16-only, 2 both
  auto gcn0 = [&](const unsigned short* inb, const unsigned short* Wt, const float* b,
                  const int* rowptr, const int* col, const float* dinv, float* outf,
                  int K, int F) {
    gemmB(inb, Wt, K, F);
    gcn_gather_k<0><<<N, 256, 0, stream>>>(bufA, rowptr, col, dinv, b, outf, nullptr, F);
  };
  auto gcn1 = [&](const unsigned short* inb, const unsigned short* Wt, const float* b,
                  const int* rowptr, const int* col, const float* dinv, int K, int F) {
    gemmB(inb, Wt, K, F);
    gcn_gather_k<1><<<N, 256, 0, stream>>>(bufA, rowptr, col, dinv, b, nullptr, ab, F);
  };
  auto gcn2 = [&](const unsigned short* inb, const unsigned short* Wt, const float* b,
                  const int* rowptr, const int* col, const float* dinv, float* outf,
                  int K, int F) {
    gemmB(inb, Wt, K, F);
    gcn_gather_k<2><<<N, 256, 0, stream>>>(bufA, rowptr, col, dinv, b, outf, ab, F);
  };
  auto gatA = [&](const unsigned short* Wt, const float* a_s, const float* a_d,
                  const float* b, const int* rowptr, const int* col) {
    gemmB(ab, Wt, 256, 512);
    gat_attn2_k<4, 128><<<N, 256, 0, stream>>>(bufA, a_s, a_d, asrcB, adstB);
    gat_fused_k<4, 128, 0><<<N, 256, 0, stream>>>(bufA, asrcB, adstB, rowptr, col, b, ab);
  };
  auto gatB = [&](const unsigned short* Wt, const float* a_s, const float* a_d,
                  const float* b, const int* rowptr, const int* col) {
    gemmB(ab, Wt, 512, 256);
    gat_attn2_k<1, 256><<<N, 256, 0, stream>>>(bufA, a_s, a_d, asrcB, adstB);
    gat_fused_k<1, 256, 1><<<N, 256, 0, stream>>>(bufA, asrcB, adstB, rowptr, col, b, ab);
  };

  // ---- path 1: x --GCN1--> E1 --GAT1--> emb2 --GCN3--> E3 ----
  gcn1(xb, Wt1a, b1a, rowptrS, colS, dinvS, 1024, 512);
  gcn2(ab, Wt1b, b1b, rowptrS, colS, dinvS, E1buf, 512, 256);
  gatA(Wtg1a, as1a, ad1a, bg1a, rowptrA1, colA1);
  gatB(Wtg1b, as1b, ad1b, bg1b, rowptrA1, colA1);
  gcn1(ab, Wt3a, b3a, rowptrS, colS, dinvS, 256, 128);
  gcn0(ab, Wt3b, b3b, rowptrS, colS, dinvS, E3buf, 128, 256);

  // ---- path 2: x --GCN2--> E4 --GAT2--> emb5 --GCN4--> E6 ----
  gcn1(xb, Wt2a, b2a, rowptrF, colF, dinvF, 1024, 512);
  gcn2(ab, Wt2b, b2b, rowptrF, colF, dinvF, E4buf, 512, 256);
  gatA(Wtg2a, as2a, ad2a, bg2a, rowptrA2, colA2);
  gatB(Wtg2b, as2b, ad2b, bg2b, rowptrA2, colA2);
  gcn1(ab, Wt4a, b4a, rowptrF, colF, dinvF, 256, 128);
  gcn0(ab, Wt4b, b4b, rowptrF, colF, dinvF, E6buf, 128, 256);

  // ---- fusion + MLP + log_softmax ----
  final2_k<<<cdiv(N, NPB), 256, 0, stream>>>(E1buf, E3buf, E4buf, E6buf,
                                             aw1, ab1, aw2, mw1, mb1, mw2, mb2,
                                             (float*)d_out, N);
}

// Round 7
// 1524.671 us; speedup vs baseline: 7.3762x; 1.1258x over previous
//
#include <hip/hip_runtime.h>
#include <cstddef>
#include <cstdint>
#include <cmath>

// ---------------------------------------------------------------------------
// HiGLDP forward, round 7: bf16 h everywhere (GEMM writes bf16, gathers read
// bf16), GAT logits via projected-a (in @ (W a)), final2 mw1 chunked.
// ---------------------------------------------------------------------------

static inline int cdiv(int a, int b) { return (a + b - 1) / b; }

typedef __attribute__((ext_vector_type(8))) unsigned short ush8;
typedef __attribute__((ext_vector_type(4))) unsigned short ush4;
typedef __attribute__((ext_vector_type(2))) unsigned short ush2;
typedef __attribute__((ext_vector_type(8))) short bf16x8;
typedef __attribute__((ext_vector_type(4))) float f32x4;

__device__ __forceinline__ unsigned short f2bf(float f) {
  unsigned u = __float_as_uint(f);
  unsigned r = 0x7fffu + ((u >> 16) & 1u);
  return (unsigned short)((u + r) >> 16);
}
__device__ __forceinline__ float bf2f(unsigned short u) {
  return __uint_as_float((unsigned)u << 16);
}

// ---------------- CSR build ----------------
__global__ void zero_int_k(int* __restrict__ p, int n) {
  int i = blockIdx.x * 256 + threadIdx.x;
  if (i < n) p[i] = 0;
}
__global__ void hist_k(const int* __restrict__ dst, int* __restrict__ deg, int E) {
  int e = blockIdx.x * 256 + threadIdx.x;
  if (e < E) atomicAdd(&deg[dst[e]], 1);
}
__global__ __launch_bounds__(1024) void scan_k(const int* __restrict__ deg,
                                               int* __restrict__ rowptr,
                                               int* __restrict__ cursor, int N) {
  __shared__ int part[1024];
  const int t = threadIdx.x;
  const int CH = (N + 1023) / 1024;
  const int base = t * CH;
  int loc = 0;
  for (int i = 0; i < CH; ++i)
    if (base + i < N) loc += deg[base + i];
  part[t] = loc;
  __syncthreads();
  for (int off = 1; off < 1024; off <<= 1) {
    int v = (t >= off) ? part[t - off] : 0;
    __syncthreads();
    part[t] += v;
    __syncthreads();
  }
  int run = (t > 0) ? part[t - 1] : 0;
  for (int i = 0; i < CH; ++i)
    if (base + i < N) {
      rowptr[base + i] = run;
      cursor[base + i] = run;
      run += deg[base + i];
    }
  if (t == 1023) rowptr[N] = part[1023];
}
__global__ void place_k(const int* __restrict__ src, const int* __restrict__ dst,
                        int* __restrict__ cursor, int* __restrict__ col, int E) {
  int e = blockIdx.x * 256 + threadIdx.x;
  if (e < E) {
    int p = atomicAdd(&cursor[dst[e]], 1);
    col[p] = src[e];
  }
}
__global__ void dinv_k(const int* __restrict__ deg, float* __restrict__ dinv, int N) {
  int i = blockIdx.x * 256 + threadIdx.x;
  if (i < N) dinv[i] = rsqrtf((float)deg[i] + 1.f);
}

// ---------------- casts ----------------
__global__ void cast_bf16_k(const float* __restrict__ in, unsigned short* __restrict__ out,
                            int n4) {
  int i = blockIdx.x * 256 + threadIdx.x;
  if (i >= n4) return;
  float4 v = reinterpret_cast<const float4*>(in)[i];
  ush4 o;
  o.x = f2bf(v.x); o.y = f2bf(v.y); o.z = f2bf(v.z); o.w = f2bf(v.w);
  reinterpret_cast<ush4*>(out)[i] = o;
}

// Wt[f][k] = bf16(W[k][f]); K,F multiples of 32
__global__ __launch_bounds__(256) void transpose_cast_k(const float* __restrict__ W,
                                                        unsigned short* __restrict__ Wt,
                                                        int K, int F) {
  __shared__ float t[32][33];
  int bk = blockIdx.x * 32, bf = blockIdx.y * 32;
  int tx = threadIdx.x & 31, ty = threadIdx.x >> 5;
  for (int i = ty; i < 32; i += 8) t[i][tx] = W[(size_t)(bk + i) * F + bf + tx];
  __syncthreads();
  for (int i = ty; i < 32; i += 8)
    Wt[(size_t)(bf + i) * K + bk + tx] = f2bf(t[tx][i]);
}

// va[k][o] = sum_c W[k, h*C+c] * a[h][c], o in [0,2H): o<H -> a_src, else a_dst
template <int H, int C>
__global__ void va_proj_k(const float* __restrict__ W, const float* __restrict__ a_s,
                          const float* __restrict__ a_d, float* __restrict__ va, int K) {
  int i = blockIdx.x * 256 + threadIdx.x;
  if (i >= K * 2 * H) return;
  int k = i / (2 * H), o = i - k * 2 * H;
  int hh = (o >= H) ? (o - H) : o;
  const float* a = (o >= H) ? a_d : a_s;
  float s = 0.f;
  for (int c = 0; c < C; ++c) s += W[(size_t)k * (H * C) + hh * C + c] * a[hh * C + c];
  va[k * 2 * H + o] = s;
}

// ---------------- bf16 MFMA GEMM: Cb[M,F] = bf16(A[M,K] @ Wt[F,K]^T) --------
#define LDT 40
__global__ __launch_bounds__(256) void gemm_bf16_k(
    const unsigned short* __restrict__ A,
    const unsigned short* __restrict__ Bt,
    unsigned short* __restrict__ Cb, int M, int K, int F) {
  __shared__ unsigned short Asl[128 * LDT];
  __shared__ unsigned short Bsl[128 * LDT];
  const int tid = threadIdx.x;
  const int wid = tid >> 6, lane = tid & 63;
  const int wr = (wid >> 1) * 64, wc = (wid & 1) * 64;
  const int bm = blockIdx.y * 128, bn = blockIdx.x * 128;
  const int l15 = lane & 15, lk = lane >> 4;
  f32x4 acc[4][4] = {};
  for (int k0 = 0; k0 < K; k0 += 32) {
    __syncthreads();
#pragma unroll
    for (int i = 0; i < 2; ++i) {
      int c = tid + i * 256;
      int r = c >> 2;
      int off = (c & 3) << 3;
      int gr = bm + r;
      ush8 av = {};
      if (gr < M) av = *reinterpret_cast<const ush8*>(A + (size_t)gr * K + k0 + off);
      *reinterpret_cast<ush8*>(&Asl[r * LDT + off]) = av;
      ush8 bv = *reinterpret_cast<const ush8*>(Bt + (size_t)(bn + r) * K + k0 + off);
      *reinterpret_cast<ush8*>(&Bsl[r * LDT + off]) = bv;
    }
    __syncthreads();
    bf16x8 af[4], bfv[4];
#pragma unroll
    for (int mi = 0; mi < 4; ++mi)
      af[mi] = *reinterpret_cast<const bf16x8*>(&Asl[(wr + mi * 16 + l15) * LDT + (lk << 3)]);
#pragma unroll
    for (int ni = 0; ni < 4; ++ni)
      bfv[ni] = *reinterpret_cast<const bf16x8*>(&Bsl[(wc + ni * 16 + l15) * LDT + (lk << 3)]);
#pragma unroll
    for (int mi = 0; mi < 4; ++mi)
#pragma unroll
      for (int ni = 0; ni < 4; ++ni)
        acc[mi][ni] = __builtin_amdgcn_mfma_f32_16x16x32_bf16(af[mi], bfv[ni], acc[mi][ni], 0, 0, 0);
  }
#pragma unroll
  for (int mi = 0; mi < 4; ++mi) {
    int gr0 = bm + wr + mi * 16 + (lk << 2);
#pragma unroll
    for (int ni = 0; ni < 4; ++ni) {
      int gc = bn + wc + ni * 16 + l15;
#pragma unroll
      for (int r4 = 0; r4 < 4; ++r4) {
        int gr = gr0 + r4;
        if (gr < M) Cb[(size_t)gr * F + gc] = f2bf(acc[mi][ni][r4]);
      }
    }
  }
}

// ---------------- GCN: per-dst gather (bf16 h) + self + bias + relu --------
// MODE: 0 = fp32 only, 1 = bf16 only, 2 = both.  VPT: features/thread (1|2)
template <int MODE, int VPT>
__global__ __launch_bounds__(256) void gcn_gather_k(
    const unsigned short* __restrict__ h, const int* __restrict__ rowptr,
    const int* __restrict__ col, const float* __restrict__ dinv,
    const float* __restrict__ bias, float* __restrict__ outf,
    unsigned short* __restrict__ outb, int F) {
  const int d = blockIdx.x;
  const int tid = threadIdx.x;
  const int f = tid * VPT;
  if (VPT == 1 && f >= F) return;
  const int beg = rowptr[d], end = rowptr[d + 1];
  const float di = dinv[d];
  float a0, a1 = 0.f;
  {
    float w = di * di;
    if (VPT == 2) {
      ush2 v = *reinterpret_cast<const ush2*>(h + (size_t)d * F + f);
      a0 = bf2f(v.x) * w; a1 = bf2f(v.y) * w;
    } else {
      a0 = bf2f(h[(size_t)d * F + f]) * w;
    }
  }
  for (int p = beg; p < end; ++p) {
    int s = col[p];
    float w = dinv[s] * di;
    if (VPT == 2) {
      ush2 v = *reinterpret_cast<const ush2*>(h + (size_t)s * F + f);
      a0 += bf2f(v.x) * w; a1 += bf2f(v.y) * w;
    } else {
      a0 += bf2f(h[(size_t)s * F + f]) * w;
    }
  }
  {
    float v = fmaxf(a0 + bias[f], 0.f);
    if (MODE != 1) outf[(size_t)d * F + f] = v;
    if (MODE != 0) outb[(size_t)d * F + f] = f2bf(v);
  }
  if (VPT == 2) {
    float v = fmaxf(a1 + bias[f + 1], 0.f);
    if (MODE != 1) outf[(size_t)d * F + f + 1] = v;
    if (MODE != 0) outb[(size_t)d * F + f + 1] = f2bf(v);
  }
}

// ---------------- GAT logits: [asrc|adst] = in(bf16) @ va (wave per node) ---
template <int K, int H>
__global__ __launch_bounds__(256) void attn_dot_k(
    const unsigned short* __restrict__ in, const float* __restrict__ va,
    float* __restrict__ asrc, float* __restrict__ adst, int N) {
  constexpr int EPL = K / 64;  // 4 or 8
  const int n = blockIdx.x * 4 + (threadIdx.x >> 6);
  const int lane = threadIdx.x & 63;
  if (n >= N) return;
  float acc[2 * H] = {};
  const unsigned short* row = in + (size_t)n * K + lane * EPL;
  unsigned short vj[EPL];
  if (EPL == 4) {
    ush4 t = *reinterpret_cast<const ush4*>(row);
    vj[0] = t.x; vj[1] = t.y; vj[2] = t.z; vj[3] = t.w;
  } else {
    ush8 t = *reinterpret_cast<const ush8*>(row);
#pragma unroll
    for (int j = 0; j < EPL; ++j) vj[j] = t[j];
  }
#pragma unroll
  for (int j = 0; j < EPL; ++j) {
    float xv = bf2f(vj[j]);
    const float* vp = va + (size_t)(lane * EPL + j) * 2 * H;
#pragma unroll
    for (int o = 0; o < 2 * H; ++o) acc[o] += xv * vp[o];
  }
#pragma unroll
  for (int off = 32; off >= 1; off >>= 1)
#pragma unroll
    for (int o = 0; o < 2 * H; ++o) acc[o] += __shfl_xor(acc[o], off);
  if (lane == 0) {
#pragma unroll
    for (int hh = 0; hh < H; ++hh) {
      asrc[n * H + hh] = acc[hh];
      adst[n * H + hh] = acc[H + hh];
    }
  }
}

// ---------------- GAT fused softmax + aggregation (bf16 h, bf16 out) --------
template <int H, int C, int EPI>
__global__ __launch_bounds__(256) void gat_fused_k(
    const unsigned short* __restrict__ h, const float* __restrict__ asrc,
    const float* __restrict__ adst, const int* __restrict__ rowptr,
    const int* __restrict__ col, const float* __restrict__ bias,
    unsigned short* __restrict__ out) {
  constexpr int F = H * C;
  constexpr int FPT = F / 256;
  const int d = blockIdx.x;
  const int tid = threadIdx.x;
  const int lane = tid & 63, wv = tid >> 6;
  const int beg = rowptr[d], end = rowptr[d + 1];
  __shared__ float sred[2][4][H > 4 ? H : 4];

  float ad[H], vself[H];
#pragma unroll
  for (int k = 0; k < H; ++k) {
    ad[k] = adst[d * H + k];
    float v = asrc[d * H + k] + ad[k];
    vself[k] = v > 0.f ? v : 0.2f * v;
  }
  float mx[H];
#pragma unroll
  for (int k = 0; k < H; ++k) mx[k] = vself[k];
  for (int p = beg + tid; p < end; p += 256) {
    int s = col[p];
#pragma unroll
    for (int k = 0; k < H; ++k) {
      float v = asrc[s * H + k] + ad[k];
      v = v > 0.f ? v : 0.2f * v;
      mx[k] = fmaxf(mx[k], v);
    }
  }
#pragma unroll
  for (int off = 32; off >= 1; off >>= 1)
#pragma unroll
    for (int k = 0; k < H; ++k) mx[k] = fmaxf(mx[k], __shfl_xor(mx[k], off));
  if (lane == 0)
#pragma unroll
    for (int k = 0; k < H; ++k) sred[0][wv][k] = mx[k];
  __syncthreads();
  float m[H];
#pragma unroll
  for (int k = 0; k < H; ++k)
    m[k] = fmaxf(fmaxf(sred[0][0][k], sred[0][1][k]),
                 fmaxf(sred[0][2][k], sred[0][3][k]));
  float dn[H];
#pragma unroll
  for (int k = 0; k < H; ++k) dn[k] = 0.f;
  for (int p = beg + tid; p < end; p += 256) {
    int s = col[p];
#pragma unroll
    for (int k = 0; k < H; ++k) {
      float v = asrc[s * H + k] + ad[k];
      v = v > 0.f ? v : 0.2f * v;
      dn[k] += __expf(v - m[k]);
    }
  }
#pragma unroll
  for (int off = 32; off >= 1; off >>= 1)
#pragma unroll
    for (int k = 0; k < H; ++k) dn[k] += __shfl_xor(dn[k], off);
  if (lane == 0)
#pragma unroll
    for (int k = 0; k < H; ++k) sred[1][wv][k] = dn[k];
  __syncthreads();
  float invD[H];
#pragma unroll
  for (int k = 0; k < H; ++k) {
    float t = sred[1][0][k] + sred[1][1][k] + sred[1][2][k] + sred[1][3][k];
    invD[k] = 1.f / (t + __expf(vself[k] - m[k]) + 1e-16f);
  }
  if (EPI == 0) {
    // FPT==2: contiguous feature pair (2t, 2t+1); same head since C even
    const int f0 = 2 * tid;
    const int k0 = f0 / C;
    float aself = __expf(vself[k0] - m[k0]) * invD[k0];
    ush2 hv = *reinterpret_cast<const ush2*>(h + (size_t)d * F + f0);
    float acc0 = aself * bf2f(hv.x), acc1 = aself * bf2f(hv.y);
    for (int p = beg; p < end; ++p) {
      int s = col[p];
      float v = asrc[s * H + k0] + ad[k0];
      v = v > 0.f ? v : 0.2f * v;
      float a = __expf(v - m[k0]) * invD[k0];
      ush2 sv = *reinterpret_cast<const ush2*>(h + (size_t)s * F + f0);
      acc0 += a * bf2f(sv.x);
      acc1 += a * bf2f(sv.y);
    }
    float v0 = acc0 + bias[f0];
    float v1 = acc1 + bias[f0 + 1];
    v0 = v0 > 0.f ? v0 : (__expf(v0) - 1.f);
    v1 = v1 > 0.f ? v1 : (__expf(v1) - 1.f);
    ush2 o2; o2.x = f2bf(v0); o2.y = f2bf(v1);
    *reinterpret_cast<ush2*>(out + (size_t)d * F + f0) = o2;
  } else {
    // H==1, F==256, one feature per thread
    float aself = __expf(vself[0] - m[0]) * invD[0];
    float acc0 = aself * bf2f(h[(size_t)d * F + tid]);
    for (int p = beg; p < end; ++p) {
      int s = col[p];
      float v = asrc[s] + ad[0];
      v = v > 0.f ? v : 0.2f * v;
      float a = __expf(v - m[0]) * invD[0];
      acc0 += a * bf2f(h[(size_t)s * F + tid]);
    }
    float v = acc0 + bias[tid];
    float r = v;
#pragma unroll
    for (int off = 32; off >= 1; off >>= 1) r = fmaxf(r, __shfl_xor(r, off));
    __syncthreads();
    if (lane == 0) sred[0][wv][0] = r;
    __syncthreads();
    float m2 = fmaxf(fmaxf(sred[0][0][0], sred[0][1][0]),
                     fmaxf(sred[0][2][0], sred[0][3][0]));
    float e = __expf(v - m2);
    float se = e;
#pragma unroll
    for (int off = 32; off >= 1; off >>= 1) se += __shfl_xor(se, off);
    if (lane == 0) sred[1][wv][0] = se;
    __syncthreads();
    float tot = sred[1][0][0] + sred[1][1][0] + sred[1][2][0] + sred[1][3][0];
    float y = v - m2 - logf(tot);
    out[(size_t)d * F + tid] = f2bf(fmaxf(y, 0.f));
  }
}

// ---------------- final fusion + MLP + log_softmax (8 nodes/block) ----------
#define NPB 8
__global__ __launch_bounds__(256) void final2_k(
    const float* __restrict__ E1, const float* __restrict__ E3,
    const float* __restrict__ E4, const float* __restrict__ E6,
    const float* __restrict__ aw1, const float* __restrict__ ab1,
    const float* __restrict__ aw2, const float* __restrict__ mw1,
    const float* __restrict__ mb1, const float* __restrict__ mw2,
    const float* __restrict__ mb2, float* __restrict__ out, int N) {
  __shared__ float zsh[NPB][2][512];   // 32 KB; [nd][1] reused for partials
  __shared__ float wsh[NPB * 2][17];
  __shared__ float warr[NPB][2];
  __shared__ float bsh[NPB][2];
  __shared__ float hsh[NPB][64];
  __shared__ float o7sh[NPB][8];
  const int t = threadIdx.x;
  const int n0 = blockIdx.x * NPB;
  {
    int seg = t >> 6, idx = t & 63;
    const float* sp = (seg == 0) ? E1 : (seg == 1) ? E3 : (seg == 2) ? E4 : E6;
    int r = seg >> 1, half = seg & 1;
    for (int nd = 0; nd < NPB; ++nd) {
      if (n0 + nd < N) {
        float4 v = reinterpret_cast<const float4*>(sp)[(size_t)(n0 + nd) * 64 + idx];
        reinterpret_cast<float4*>(&zsh[nd][r][half * 256])[idx] = v;
      }
    }
  }
  __syncthreads();
  {
    int row = t >> 4, j = t & 15;
    int nd = row >> 1, r = row & 1;
    const float* zp = zsh[nd][r];
    float a0 = ab1[j], a1 = 0.f;
    for (int c = 0; c < 512; c += 2) {
      a0 += zp[c] * aw1[c * 16 + j];
      a1 += zp[c + 1] * aw1[(c + 1) * 16 + j];
    }
    wsh[row][j] = tanhf(a0 + a1) * aw2[j];
  }
  __syncthreads();
  if (t < 16) {
    float s = 0.f;
    for (int j = 0; j < 16; ++j) s += wsh[t][j];
    warr[t >> 1][t & 1] = s;
  }
  __syncthreads();
  if (t < NPB) {
    float w0 = warr[t][0], w1 = warr[t][1];
    float mxv = fmaxf(w0, w1);
    float e0 = __expf(w0 - mxv), e1 = __expf(w1 - mxv);
    float inv = 1.f / (e0 + e1);
    bsh[t][0] = e0 * inv; bsh[t][1] = e1 * inv;
  }
  __syncthreads();
  {
    int nd = t >> 5, l = t & 31;
    float b0 = bsh[nd][0], b1 = bsh[nd][1];
    for (int i = 0; i < 16; ++i) {
      int c = l + 32 * i;
      zsh[nd][0][c] = b0 * zsh[nd][0][c] + b1 * zsh[nd][1][c];
    }
  }
  __syncthreads();
  // ---- mw1: 64 outs x 4 K-chunks, 8-node ILP; partials into zsh[nd][1] ----
  {
    int o = t & 63, ch = t >> 6;   // ch 0..3
    float accv[NPB];
#pragma unroll
    for (int nd = 0; nd < NPB; ++nd) accv[nd] = 0.f;
    for (int c = ch * 128; c < ch * 128 + 128; ++c) {
      float w = mw1[c * 64 + o];
#pragma unroll
      for (int nd = 0; nd < NPB; ++nd) accv[nd] += zsh[nd][0][c] * w;
    }
#pragma unroll
    for (int nd = 0; nd < NPB; ++nd) zsh[nd][1][ch * 64 + o] = accv[nd];
  }
  __syncthreads();
  {
    int nd = t >> 5, oo = t & 31;
#pragma unroll
    for (int i = 0; i < 2; ++i) {
      int o = oo + i * 32;
      float s = mb1[o] + zsh[nd][1][o] + zsh[nd][1][64 + o] +
                zsh[nd][1][128 + o] + zsh[nd][1][192 + o];
      hsh[nd][o] = tanhf(s);
    }
  }
  __syncthreads();
  if (t < NPB * 7) {
    int nd = t / 7, jo = t - nd * 7;
    float a = mb2[jo];
    for (int j = 0; j < 64; ++j) a += hsh[nd][j] * mw2[j * 7 + jo];
    o7sh[nd][jo] = a;
  }
  __syncthreads();
  if (t < NPB && n0 + t < N) {
    float m = o7sh[t][0];
    for (int k = 1; k < 7; ++k) m = fmaxf(m, o7sh[t][k]);
    float s = 0.f;
    for (int k = 0; k < 7; ++k) s += expf(o7sh[t][k] - m);
    float ls = logf(s);
    for (int k = 0; k < 7; ++k) out[(size_t)(n0 + t) * 7 + k] = o7sh[t][k] - m - ls;
  }
}

// ---------------------------------------------------------------------------
extern "C" void kernel_launch(void* const* d_in, const int* in_sizes, int n_in,
                              void* d_out, int out_size, void* d_ws, size_t ws_size,
                              hipStream_t stream) {
  (void)n_in; (void)out_size; (void)ws_size;
  const float* x     = (const float*)d_in[0];
  const int*   sadj  = (const int*)d_in[1];
  const int*   fadj  = (const int*)d_in[2];
  const int*   asadj = (const int*)d_in[3];
  const int*   afadj = (const int*)d_in[4];
  const float* W1a = (const float*)d_in[5];  const float* b1a = (const float*)d_in[6];
  const float* W1b = (const float*)d_in[7];  const float* b1b = (const float*)d_in[8];
  const float* W2a = (const float*)d_in[9];  const float* b2a = (const float*)d_in[10];
  const float* W2b = (const float*)d_in[11]; const float* b2b = (const float*)d_in[12];
  const float* W3a = (const float*)d_in[13]; const float* b3a = (const float*)d_in[14];
  const float* W3b = (const float*)d_in[15]; const float* b3b = (const float*)d_in[16];
  const float* W4a = (const float*)d_in[17]; const float* b4a = (const float*)d_in[18];
  const float* W4b = (const float*)d_in[19]; const float* b4b = (const float*)d_in[20];
  const float* Wg1a = (const float*)d_in[21]; const float* as1a = (const float*)d_in[22];
  const float* ad1a = (const float*)d_in[23]; const float* bg1a = (const float*)d_in[24];
  const float* Wg1b = (const float*)d_in[25]; const float* as1b = (const float*)d_in[26];
  const float* ad1b = (const float*)d_in[27]; const float* bg1b = (const float*)d_in[28];
  const float* Wg2a = (const float*)d_in[29]; const float* as2a = (const float*)d_in[30];
  const float* ad2a = (const float*)d_in[31]; const float* bg2a = (const float*)d_in[32];
  const float* Wg2b = (const float*)d_in[33]; const float* as2b = (const float*)d_in[34];
  const float* ad2b = (const float*)d_in[35]; const float* bg2b = (const float*)d_in[36];
  const float* aw1 = (const float*)d_in[37]; const float* ab1 = (const float*)d_in[38];
  const float* aw2 = (const float*)d_in[39];
  const float* mw1 = (const float*)d_in[40]; const float* mb1 = (const float*)d_in[41];
  const float* mw2 = (const float*)d_in[42]; const float* mb2 = (const float*)d_in[43];

  const int N = in_sizes[0] / 1024;   // 20000
  const int E = in_sizes[1] / 2;      // 160000

  // ---- workspace layout ----
  float* ws = (float*)d_ws;
  float* bufA  = ws;                          // N*512 fp32 region; hb aliases it
  float* bufB  = bufA + (size_t)N * 512;      // N*512 (va tables live here)
  float* E1buf = bufB + (size_t)N * 512;      // N*256
  float* E3buf = E1buf + (size_t)N * 256;     // N*256
  float* E4buf = E3buf + (size_t)N * 256;     // N*256
  float* E6buf = E4buf + (size_t)N * 256;     // N*256
  float* dinvS = E6buf + (size_t)N * 256;     // N
  float* dinvF = dinvS + N;                   // N
  float* asrcB = dinvF + N;                   // N*4
  float* adstB = asrcB + (size_t)N * 4;       // N*4
  int* ib = (int*)(adstB + (size_t)N * 4);
  int* rowptrS = ib;            ib += N + 1;
  int* rowptrF = ib;            ib += N + 1;
  int* rowptrA1 = ib;           ib += N + 1;
  int* rowptrA2 = ib;           ib += N + 1;
  int* colS = ib;               ib += E;
  int* colF = ib;               ib += E;
  int* colA1 = ib;              ib += E;
  int* colA2 = ib;              ib += E;
  int* degI = ib;               ib += N;
  int* cursor = ib;             ib += N;
  unsigned short* ub = (unsigned short*)(ib + ((size_t)(-(intptr_t)ib) & 3));
  unsigned short* xb = ub;            ub += (size_t)N * 1024;  // bf16(x)
  unsigned short* ab = ub;            ub += (size_t)N * 512;   // bf16 activations
  unsigned short* Wt1a = ub;  ub += 1024 * 512;
  unsigned short* Wt1b = ub;  ub += 512 * 256;
  unsigned short* Wt2a = ub;  ub += 1024 * 512;
  unsigned short* Wt2b = ub;  ub += 512 * 256;
  unsigned short* Wt3a = ub;  ub += 256 * 128;
  unsigned short* Wt3b = ub;  ub += 128 * 256;
  unsigned short* Wt4a = ub;  ub += 256 * 128;
  unsigned short* Wt4b = ub;  ub += 128 * 256;
  unsigned short* Wtg1a = ub; ub += 256 * 512;
  unsigned short* Wtg1b = ub; ub += 512 * 256;
  unsigned short* Wtg2a = ub; ub += 256 * 512;
  unsigned short* Wtg2b = ub; ub += 512 * 256;
  unsigned short* hb = (unsigned short*)bufA;   // bf16 h (N*512 max)
  float* vag1a = bufB;               // [256][8]
  float* vag1b = bufB + 2048;        // [512][2]
  float* vag2a = bufB + 3072;        // [256][8]
  float* vag2b = bufB + 5120;        // [512][2]

  // ---- weight transpose+cast + va projections ----
  auto tc = [&](const float* W, unsigned short* Wt, int K, int F) {
    transpose_cast_k<<<dim3(K / 32, F / 32), 256, 0, stream>>>(W, Wt, K, F);
  };
  tc(W1a, Wt1a, 1024, 512); tc(W1b, Wt1b, 512, 256);
  tc(W2a, Wt2a, 1024, 512); tc(W2b, Wt2b, 512, 256);
  tc(W3a, Wt3a, 256, 128);  tc(W3b, Wt3b, 128, 256);
  tc(W4a, Wt4a, 256, 128);  tc(W4b, Wt4b, 128, 256);
  tc(Wg1a, Wtg1a, 256, 512); tc(Wg1b, Wtg1b, 512, 256);
  tc(Wg2a, Wtg2a, 256, 512); tc(Wg2b, Wtg2b, 512, 256);
  va_proj_k<4, 128><<<cdiv(256 * 8, 256), 256, 0, stream>>>(Wg1a, as1a, ad1a, vag1a, 256);
  va_proj_k<1, 256><<<cdiv(512 * 2, 256), 256, 0, stream>>>(Wg1b, as1b, ad1b, vag1b, 512);
  va_proj_k<4, 128><<<cdiv(256 * 8, 256), 256, 0, stream>>>(Wg2a, as2a, ad2a, vag2a, 256);
  va_proj_k<1, 256><<<cdiv(512 * 2, 256), 256, 0, stream>>>(Wg2b, as2b, ad2b, vag2b, 512);
  cast_bf16_k<<<cdiv(N * 1024 / 4, 256), 256, 0, stream>>>(x, xb, N * 1024 / 4);

  // ---- CSR builds ----
  auto build = [&](const int* ei, int* rowptr, int* col, float* dinv) {
    zero_int_k<<<cdiv(N, 256), 256, 0, stream>>>(degI, N);
    hist_k<<<cdiv(E, 256), 256, 0, stream>>>(ei + E, degI, E);
    scan_k<<<1, 1024, 0, stream>>>(degI, rowptr, cursor, N);
    if (dinv) dinv_k<<<cdiv(N, 256), 256, 0, stream>>>(degI, dinv, N);
    place_k<<<cdiv(E, 256), 256, 0, stream>>>(ei, ei + E, cursor, col, E);
  };
  build(sadj, rowptrS, colS, dinvS);
  build(fadj, rowptrF, colF, dinvF);
  build(asadj, rowptrA1, colA1, nullptr);
  build(afadj, rowptrA2, colA2, nullptr);

  auto gemmB = [&](const unsigned short* Ab, const unsigned short* Wt, int K, int F) {
    gemm_bf16_k<<<dim3(F / 128, cdiv(N, 128)), 256, 0, stream>>>(Ab, Wt, hb, N, K, F);
  };
  auto gcn0 = [&](const unsigned short* inb, const unsigned short* Wt, const float* b,
                  const int* rowptr, const int* col, const float* dinv, float* outf,
                  int K, int F) {
    gemmB(inb, Wt, K, F);
    if (F == 512) gcn_gather_k<0, 2><<<N, 256, 0, stream>>>(hb, rowptr, col, dinv, b, outf, nullptr, F);
    else          gcn_gather_k<0, 1><<<N, 256, 0, stream>>>(hb, rowptr, col, dinv, b, outf, nullptr, F);
  };
  auto gcn1 = [&](const unsigned short* inb, const unsigned short* Wt, const float* b,
                  const int* rowptr, const int* col, const float* dinv, int K, int F) {
    gemmB(inb, Wt, K, F);
    if (F == 512) gcn_gather_k<1, 2><<<N, 256, 0, stream>>>(hb, rowptr, col, dinv, b, nullptr, ab, F);
    else          gcn_gather_k<1, 1><<<N, 256, 0, stream>>>(hb, rowptr, col, dinv, b, nullptr, ab, F);
  };
  auto gcn2 = [&](const unsigned short* inb, const unsigned short* Wt, const float* b,
                  const int* rowptr, const int* col, const float* dinv, float* outf,
                  int K, int F) {
    gemmB(inb, Wt, K, F);
    if (F == 512) gcn_gather_k<2, 2><<<N, 256, 0, stream>>>(hb, rowptr, col, dinv, b, outf, ab, F);
    else          gcn_gather_k<2, 1><<<N, 256, 0, stream>>>(hb, rowptr, col, dinv, b, outf, ab, F);
  };
  auto gatA = [&](const unsigned short* Wt, const float* va, const float* b,
                  const int* rowptr, const int* col) {
    gemmB(ab, Wt, 256, 512);
    attn_dot_k<256, 4><<<cdiv(N, 4), 256, 0, stream>>>(ab, va, asrcB, adstB, N);
    gat_fused_k<4, 128, 0><<<N, 256, 0, stream>>>(hb, asrcB, adstB, rowptr, col, b, ab);
  };
  auto gatB = [&](const unsigned short* Wt, const float* va, const float* b,
                  const int* rowptr, const int* col) {
    gemmB(ab, Wt, 512, 256);
    attn_dot_k<512, 1><<<cdiv(N, 4), 256, 0, stream>>>(ab, va, asrcB, adstB, N);
    gat_fused_k<1, 256, 1><<<N, 256, 0, stream>>>(hb, asrcB, adstB, rowptr, col, b, ab);
  };

  // ---- path 1: x --GCN1--> E1 --GAT1--> emb2 --GCN3--> E3 ----
  gcn1(xb, Wt1a, b1a, rowptrS, colS, dinvS, 1024, 512);
  gcn2(ab, Wt1b, b1b, rowptrS, colS, dinvS, E1buf, 512, 256);
  gatA(Wtg1a, vag1a, bg1a, rowptrA1, colA1);
  gatB(Wtg1b, vag1b, bg1b, rowptrA1, colA1);
  gcn1(ab, Wt3a, b3a, rowptrS, colS, dinvS, 256, 128);
  gcn0(ab, Wt3b, b3b, rowptrS, colS, dinvS, E3buf, 128, 256);

  // ---- path 2: x --GCN2--> E4 --GAT2--> emb5 --GCN4--> E6 ----
  gcn1(xb, Wt2a, b2a, rowptrF, colF, dinvF, 1024, 512);
  gcn2(ab, Wt2b, b2b, rowptrF, colF, dinvF, E4buf, 512, 256);
  gatA(Wtg2a, vag2a, bg2a, rowptrA2, colA2);
  gatB(Wtg2b, vag2b, bg2b, rowptrA2, colA2);
  gcn1(ab, Wt4a, b4a, rowptrF, colF, dinvF, 256, 128);
  gcn0(ab, Wt4b, b4b, rowptrF, colF, dinvF, E6buf, 128, 256);

  // ---- fusion + MLP + log_softmax ----
  final2_k<<<cdiv(N, NPB), 256, 0, stream>>>(E1buf, E3buf, E4buf, E6buf,
                                             aw1, ab1, aw2, mw1, mb1, mw2, mb2,
                                             (float*)d_out, N);
}

// Round 8
// 1337.931 us; speedup vs baseline: 8.4057x; 1.1396x over previous
//
#include <hip/hip_runtime.h>
#include <cstddef>
#include <cstdint>
#include <cmath>

// ---------------------------------------------------------------------------
// HiGLDP forward, round 8: bf16 E-buffers + bf16 final; batched setup kernels
// (1 transpose-cast job kernel, 4-wide CSR build, merged va_proj).
// ---------------------------------------------------------------------------

static inline int cdiv(int a, int b) { return (a + b - 1) / b; }

typedef __attribute__((ext_vector_type(8))) unsigned short ush8;
typedef __attribute__((ext_vector_type(4))) unsigned short ush4;
typedef __attribute__((ext_vector_type(2))) unsigned short ush2;
typedef __attribute__((ext_vector_type(8))) short bf16x8;
typedef __attribute__((ext_vector_type(4))) float f32x4;

__device__ __forceinline__ unsigned short f2bf(float f) {
  unsigned u = __float_as_uint(f);
  unsigned r = 0x7fffu + ((u >> 16) & 1u);
  return (unsigned short)((u + r) >> 16);
}
__device__ __forceinline__ float bf2f(unsigned short u) {
  return __uint_as_float((unsigned)u << 16);
}

// ---------------- batched CSR build ----------------
__global__ void zero_int_k(int* __restrict__ p, int n) {
  int i = blockIdx.x * 256 + threadIdx.x;
  if (i < n) p[i] = 0;
}
__global__ void hist4_k(const int* __restrict__ e0, const int* __restrict__ e1,
                        const int* __restrict__ e2, const int* __restrict__ e3,
                        int* __restrict__ deg4, int E, int N) {
  int i = blockIdx.x * 256 + threadIdx.x;
  if (i >= 4 * E) return;
  const int* p; int e, off;
  if (i < E)          { p = e0; e = i;         off = 0; }
  else if (i < 2 * E) { p = e1; e = i - E;     off = N; }
  else if (i < 3 * E) { p = e2; e = i - 2 * E; off = 2 * N; }
  else                { p = e3; e = i - 3 * E; off = 3 * N; }
  atomicAdd(&deg4[off + p[E + e]], 1);
}
// 4 blocks: block b scans deg4[b*N..] -> rowptr4[b*(N+1)..], cursor4[b*N..]
__global__ __launch_bounds__(1024) void scan4_k(const int* __restrict__ deg4,
                                                int* __restrict__ rowptr4,
                                                int* __restrict__ cursor4, int N) {
  __shared__ int part[1024];
  const int b = blockIdx.x;
  const int* deg = deg4 + (size_t)b * N;
  int* rowptr = rowptr4 + (size_t)b * (N + 1);
  int* cursor = cursor4 + (size_t)b * N;
  const int t = threadIdx.x;
  const int CH = (N + 1023) / 1024;
  const int base = t * CH;
  int loc = 0;
  for (int i = 0; i < CH; ++i)
    if (base + i < N) loc += deg[base + i];
  part[t] = loc;
  __syncthreads();
  for (int off = 1; off < 1024; off <<= 1) {
    int v = (t >= off) ? part[t - off] : 0;
    __syncthreads();
    part[t] += v;
    __syncthreads();
  }
  int run = (t > 0) ? part[t - 1] : 0;
  for (int i = 0; i < CH; ++i)
    if (base + i < N) {
      rowptr[base + i] = run;
      cursor[base + i] = run;
      run += deg[base + i];
    }
  if (t == 1023) rowptr[N] = part[1023];
}
__global__ void place4_k(const int* __restrict__ e0, const int* __restrict__ e1,
                         const int* __restrict__ e2, const int* __restrict__ e3,
                         int* __restrict__ cursor4, int* __restrict__ col4,
                         int E, int N) {
  int i = blockIdx.x * 256 + threadIdx.x;
  if (i >= 4 * E) return;
  const int* p; int e, w;
  if (i < E)          { p = e0; e = i;         w = 0; }
  else if (i < 2 * E) { p = e1; e = i - E;     w = 1; }
  else if (i < 3 * E) { p = e2; e = i - 2 * E; w = 2; }
  else                { p = e3; e = i - 3 * E; w = 3; }
  int pos = atomicAdd(&cursor4[(size_t)w * N + p[E + e]], 1);
  col4[(size_t)w * E + pos] = p[e];
}
__global__ void dinv2_k(const int* __restrict__ deg4, float* __restrict__ dinvS,
                        float* __restrict__ dinvF, int N) {
  int i = blockIdx.x * 256 + threadIdx.x;
  if (i < N) dinvS[i] = rsqrtf((float)deg4[i] + 1.f);
  else if (i < 2 * N) dinvF[i - N] = rsqrtf((float)deg4[i] + 1.f);
}

// ---------------- casts ----------------
__global__ void cast_bf16_k(const float* __restrict__ in, unsigned short* __restrict__ out,
                            int n4) {
  int i = blockIdx.x * 256 + threadIdx.x;
  if (i >= n4) return;
  float4 v = reinterpret_cast<const float4*>(in)[i];
  ush4 o;
  o.x = f2bf(v.x); o.y = f2bf(v.y); o.z = f2bf(v.z); o.w = f2bf(v.w);
  reinterpret_cast<ush4*>(out)[i] = o;
}

// batched Wt[f][k] = bf16(W[k][f]) over 12 matrices
struct TcJobs {
  const float* src[12];
  unsigned short* dst[12];
  int K[12];
  int F[12];
  int start[13];
};
__global__ __launch_bounds__(256) void tc_batch_k(TcJobs j) {
  __shared__ float t[32][33];
  int flat = blockIdx.x;
  int job = 0;
  while (flat >= j.start[job + 1]) ++job;
  int local = flat - j.start[job];
  const float* W = j.src[job];
  unsigned short* Wt = j.dst[job];
  int K = j.K[job], F = j.F[job];
  int tilesX = K >> 5;
  int bk = (local % tilesX) * 32, bf = (local / tilesX) * 32;
  int tx = threadIdx.x & 31, ty = threadIdx.x >> 5;
  for (int i = ty; i < 32; i += 8) t[i][tx] = W[(size_t)(bk + i) * F + bf + tx];
  __syncthreads();
  for (int i = ty; i < 32; i += 8)
    Wt[(size_t)(bf + i) * K + bk + tx] = f2bf(t[tx][i]);
}

// merged va projections: va[k][o] = sum_c W[k,h*C+c]*a[h][c]
__device__ __forceinline__ void va_one(const float* __restrict__ W,
                                       const float* __restrict__ a_s,
                                       const float* __restrict__ a_d,
                                       float* __restrict__ va,
                                       int H, int C, int idx) {
  int k = idx / (2 * H), o = idx - k * 2 * H;
  int hh = (o >= H) ? (o - H) : o;
  const float* a = (o >= H) ? a_d : a_s;
  float s = 0.f;
  for (int c = 0; c < C; ++c) s += W[(size_t)k * (H * C) + hh * C + c] * a[hh * C + c];
  va[k * 2 * H + o] = s;
}
__global__ void va4_k(const float* W0, const float* s0, const float* d0, float* v0,
                      const float* W1, const float* s1, const float* d1, float* v1,
                      const float* W2, const float* s2, const float* d2, float* v2,
                      const float* W3, const float* s3, const float* d3, float* v3) {
  int i = blockIdx.x * 256 + threadIdx.x;  // [0, 6144)
  if (i < 2048)      va_one(W0, s0, d0, v0, 4, 128, i);
  else if (i < 3072) va_one(W1, s1, d1, v1, 1, 256, i - 2048);
  else if (i < 5120) va_one(W2, s2, d2, v2, 4, 128, i - 3072);
  else if (i < 6144) va_one(W3, s3, d3, v3, 1, 256, i - 5120);
}

// ---------------- bf16 MFMA GEMM: Cb[M,F] = bf16(A[M,K] @ Wt[F,K]^T) --------
#define LDT 40
__global__ __launch_bounds__(256) void gemm_bf16_k(
    const unsigned short* __restrict__ A,
    const unsigned short* __restrict__ Bt,
    unsigned short* __restrict__ Cb, int M, int K, int F) {
  __shared__ unsigned short Asl[128 * LDT];
  __shared__ unsigned short Bsl[128 * LDT];
  const int tid = threadIdx.x;
  const int wid = tid >> 6, lane = tid & 63;
  const int wr = (wid >> 1) * 64, wc = (wid & 1) * 64;
  const int bm = blockIdx.y * 128, bn = blockIdx.x * 128;
  const int l15 = lane & 15, lk = lane >> 4;
  f32x4 acc[4][4] = {};
  for (int k0 = 0; k0 < K; k0 += 32) {
    __syncthreads();
#pragma unroll
    for (int i = 0; i < 2; ++i) {
      int c = tid + i * 256;
      int r = c >> 2;
      int off = (c & 3) << 3;
      int gr = bm + r;
      ush8 av = {};
      if (gr < M) av = *reinterpret_cast<const ush8*>(A + (size_t)gr * K + k0 + off);
      *reinterpret_cast<ush8*>(&Asl[r * LDT + off]) = av;
      ush8 bv = *reinterpret_cast<const ush8*>(Bt + (size_t)(bn + r) * K + k0 + off);
      *reinterpret_cast<ush8*>(&Bsl[r * LDT + off]) = bv;
    }
    __syncthreads();
    bf16x8 af[4], bfv[4];
#pragma unroll
    for (int mi = 0; mi < 4; ++mi)
      af[mi] = *reinterpret_cast<const bf16x8*>(&Asl[(wr + mi * 16 + l15) * LDT + (lk << 3)]);
#pragma unroll
    for (int ni = 0; ni < 4; ++ni)
      bfv[ni] = *reinterpret_cast<const bf16x8*>(&Bsl[(wc + ni * 16 + l15) * LDT + (lk << 3)]);
#pragma unroll
    for (int mi = 0; mi < 4; ++mi)
#pragma unroll
      for (int ni = 0; ni < 4; ++ni)
        acc[mi][ni] = __builtin_amdgcn_mfma_f32_16x16x32_bf16(af[mi], bfv[ni], acc[mi][ni], 0, 0, 0);
  }
#pragma unroll
  for (int mi = 0; mi < 4; ++mi) {
    int gr0 = bm + wr + mi * 16 + (lk << 2);
#pragma unroll
    for (int ni = 0; ni < 4; ++ni) {
      int gc = bn + wc + ni * 16 + l15;
#pragma unroll
      for (int r4 = 0; r4 < 4; ++r4) {
        int gr = gr0 + r4;
        if (gr < M) Cb[(size_t)gr * F + gc] = f2bf(acc[mi][ni][r4]);
      }
    }
  }
}

// ---------------- GCN gather: WA -> write ab, WE -> write E(bf16) ----------
template <int WA, int WE, int VPT>
__global__ __launch_bounds__(256) void gcn_gather_k(
    const unsigned short* __restrict__ h, const int* __restrict__ rowptr,
    const int* __restrict__ col, const float* __restrict__ dinv,
    const float* __restrict__ bias, unsigned short* __restrict__ outa,
    unsigned short* __restrict__ oute, int F) {
  const int d = blockIdx.x;
  const int tid = threadIdx.x;
  const int f = tid * VPT;
  if (VPT == 1 && f >= F) return;
  const int beg = rowptr[d], end = rowptr[d + 1];
  const float di = dinv[d];
  float a0, a1 = 0.f;
  {
    float w = di * di;
    if (VPT == 2) {
      ush2 v = *reinterpret_cast<const ush2*>(h + (size_t)d * F + f);
      a0 = bf2f(v.x) * w; a1 = bf2f(v.y) * w;
    } else {
      a0 = bf2f(h[(size_t)d * F + f]) * w;
    }
  }
  for (int p = beg; p < end; ++p) {
    int s = col[p];
    float w = dinv[s] * di;
    if (VPT == 2) {
      ush2 v = *reinterpret_cast<const ush2*>(h + (size_t)s * F + f);
      a0 += bf2f(v.x) * w; a1 += bf2f(v.y) * w;
    } else {
      a0 += bf2f(h[(size_t)s * F + f]) * w;
    }
  }
  if (VPT == 2) {
    ush2 o2;
    o2.x = f2bf(fmaxf(a0 + bias[f], 0.f));
    o2.y = f2bf(fmaxf(a1 + bias[f + 1], 0.f));
    if (WA) *reinterpret_cast<ush2*>(outa + (size_t)d * F + f) = o2;
    if (WE) *reinterpret_cast<ush2*>(oute + (size_t)d * F + f) = o2;
  } else {
    unsigned short o = f2bf(fmaxf(a0 + bias[f], 0.f));
    if (WA) outa[(size_t)d * F + f] = o;
    if (WE) oute[(size_t)d * F + f] = o;
  }
}

// ---------------- GAT logits: [asrc|adst] = in(bf16) @ va ----------
template <int K, int H>
__global__ __launch_bounds__(256) void attn_dot_k(
    const unsigned short* __restrict__ in, const float* __restrict__ va,
    float* __restrict__ asrc, float* __restrict__ adst, int N) {
  constexpr int EPL = K / 64;
  const int n = blockIdx.x * 4 + (threadIdx.x >> 6);
  const int lane = threadIdx.x & 63;
  if (n >= N) return;
  float acc[2 * H] = {};
  const unsigned short* row = in + (size_t)n * K + lane * EPL;
  unsigned short vj[EPL];
  if (EPL == 4) {
    ush4 t = *reinterpret_cast<const ush4*>(row);
    vj[0] = t.x; vj[1] = t.y; vj[2] = t.z; vj[3] = t.w;
  } else {
    ush8 t = *reinterpret_cast<const ush8*>(row);
#pragma unroll
    for (int j = 0; j < EPL; ++j) vj[j] = t[j];
  }
#pragma unroll
  for (int j = 0; j < EPL; ++j) {
    float xv = bf2f(vj[j]);
    const float* vp = va + (size_t)(lane * EPL + j) * 2 * H;
#pragma unroll
    for (int o = 0; o < 2 * H; ++o) acc[o] += xv * vp[o];
  }
#pragma unroll
  for (int off = 32; off >= 1; off >>= 1)
#pragma unroll
    for (int o = 0; o < 2 * H; ++o) acc[o] += __shfl_xor(acc[o], off);
  if (lane == 0) {
#pragma unroll
    for (int hh = 0; hh < H; ++hh) {
      asrc[n * H + hh] = acc[hh];
      adst[n * H + hh] = acc[H + hh];
    }
  }
}

// ---------------- GAT fused softmax + aggregation ----------------
template <int H, int C, int EPI>
__global__ __launch_bounds__(256) void gat_fused_k(
    const unsigned short* __restrict__ h, const float* __restrict__ asrc,
    const float* __restrict__ adst, const int* __restrict__ rowptr,
    const int* __restrict__ col, const float* __restrict__ bias,
    unsigned short* __restrict__ out) {
  constexpr int F = H * C;
  const int d = blockIdx.x;
  const int tid = threadIdx.x;
  const int lane = tid & 63, wv = tid >> 6;
  const int beg = rowptr[d], end = rowptr[d + 1];
  __shared__ float sred[2][4][H > 4 ? H : 4];

  float ad[H], vself[H];
#pragma unroll
  for (int k = 0; k < H; ++k) {
    ad[k] = adst[d * H + k];
    float v = asrc[d * H + k] + ad[k];
    vself[k] = v > 0.f ? v : 0.2f * v;
  }
  float mx[H];
#pragma unroll
  for (int k = 0; k < H; ++k) mx[k] = vself[k];
  for (int p = beg + tid; p < end; p += 256) {
    int s = col[p];
#pragma unroll
    for (int k = 0; k < H; ++k) {
      float v = asrc[s * H + k] + ad[k];
      v = v > 0.f ? v : 0.2f * v;
      mx[k] = fmaxf(mx[k], v);
    }
  }
#pragma unroll
  for (int off = 32; off >= 1; off >>= 1)
#pragma unroll
    for (int k = 0; k < H; ++k) mx[k] = fmaxf(mx[k], __shfl_xor(mx[k], off));
  if (lane == 0)
#pragma unroll
    for (int k = 0; k < H; ++k) sred[0][wv][k] = mx[k];
  __syncthreads();
  float m[H];
#pragma unroll
  for (int k = 0; k < H; ++k)
    m[k] = fmaxf(fmaxf(sred[0][0][k], sred[0][1][k]),
                 fmaxf(sred[0][2][k], sred[0][3][k]));
  float dn[H];
#pragma unroll
  for (int k = 0; k < H; ++k) dn[k] = 0.f;
  for (int p = beg + tid; p < end; p += 256) {
    int s = col[p];
#pragma unroll
    for (int k = 0; k < H; ++k) {
      float v = asrc[s * H + k] + ad[k];
      v = v > 0.f ? v : 0.2f * v;
      dn[k] += __expf(v - m[k]);
    }
  }
#pragma unroll
  for (int off = 32; off >= 1; off >>= 1)
#pragma unroll
    for (int k = 0; k < H; ++k) dn[k] += __shfl_xor(dn[k], off);
  if (lane == 0)
#pragma unroll
    for (int k = 0; k < H; ++k) sred[1][wv][k] = dn[k];
  __syncthreads();
  float invD[H];
#pragma unroll
  for (int k = 0; k < H; ++k) {
    float t = sred[1][0][k] + sred[1][1][k] + sred[1][2][k] + sred[1][3][k];
    invD[k] = 1.f / (t + __expf(vself[k] - m[k]) + 1e-16f);
  }
  if (EPI == 0) {
    const int f0 = 2 * tid;
    const int k0 = f0 / C;
    float aself = __expf(vself[k0] - m[k0]) * invD[k0];
    ush2 hv = *reinterpret_cast<const ush2*>(h + (size_t)d * F + f0);
    float acc0 = aself * bf2f(hv.x), acc1 = aself * bf2f(hv.y);
    for (int p = beg; p < end; ++p) {
      int s = col[p];
      float v = asrc[s * H + k0] + ad[k0];
      v = v > 0.f ? v : 0.2f * v;
      float a = __expf(v - m[k0]) * invD[k0];
      ush2 sv = *reinterpret_cast<const ush2*>(h + (size_t)s * F + f0);
      acc0 += a * bf2f(sv.x);
      acc1 += a * bf2f(sv.y);
    }
    float v0 = acc0 + bias[f0];
    float v1 = acc1 + bias[f0 + 1];
    v0 = v0 > 0.f ? v0 : (__expf(v0) - 1.f);
    v1 = v1 > 0.f ? v1 : (__expf(v1) - 1.f);
    ush2 o2; o2.x = f2bf(v0); o2.y = f2bf(v1);
    *reinterpret_cast<ush2*>(out + (size_t)d * F + f0) = o2;
  } else {
    float aself = __expf(vself[0] - m[0]) * invD[0];
    float acc0 = aself * bf2f(h[(size_t)d * F + tid]);
    for (int p = beg; p < end; ++p) {
      int s = col[p];
      float v = asrc[s] + ad[0];
      v = v > 0.f ? v : 0.2f * v;
      float a = __expf(v - m[0]) * invD[0];
      acc0 += a * bf2f(h[(size_t)s * F + tid]);
    }
    float v = acc0 + bias[tid];
    float r = v;
#pragma unroll
    for (int off = 32; off >= 1; off >>= 1) r = fmaxf(r, __shfl_xor(r, off));
    __syncthreads();
    if (lane == 0) sred[0][wv][0] = r;
    __syncthreads();
    float m2 = fmaxf(fmaxf(sred[0][0][0], sred[0][1][0]),
                     fmaxf(sred[0][2][0], sred[0][3][0]));
    float e = __expf(v - m2);
    float se = e;
#pragma unroll
    for (int off = 32; off >= 1; off >>= 1) se += __shfl_xor(se, off);
    if (lane == 0) sred[1][wv][0] = se;
    __syncthreads();
    float tot = sred[1][0][0] + sred[1][1][0] + sred[1][2][0] + sred[1][3][0];
    float y = v - m2 - logf(tot);
    out[(size_t)d * F + tid] = f2bf(fmaxf(y, 0.f));
  }
}

// ---------------- final fusion + MLP + log_softmax (bf16 z, 8 nodes/block) --
#define NPB 8
__global__ __launch_bounds__(256) void final3_k(
    const unsigned short* __restrict__ E1, const unsigned short* __restrict__ E3,
    const unsigned short* __restrict__ E4, const unsigned short* __restrict__ E6,
    const float* __restrict__ aw1, const float* __restrict__ ab1,
    const float* __restrict__ aw2, const float* __restrict__ mw1,
    const float* __restrict__ mb1, const float* __restrict__ mw2,
    const float* __restrict__ mb2, float* __restrict__ out, int N) {
  __shared__ unsigned short zsh[NPB][2][512];  // 16 KB, bf16
  __shared__ float psh[NPB][256];              // 8 KB partials
  __shared__ float wsh[NPB * 2][17];
  __shared__ float warr[NPB][2];
  __shared__ float bsh[NPB][2];
  __shared__ float hsh[NPB][64];
  __shared__ float o7sh[NPB][8];
  const int t = threadIdx.x;
  const int n0 = blockIdx.x * NPB;
  // ---- load z: wave seg loads its source row (256 bf16 = 512B = 64x ush4) --
  {
    int seg = t >> 6, idx = t & 63;
    const unsigned short* sp = (seg == 0) ? E1 : (seg == 1) ? E3 : (seg == 2) ? E4 : E6;
    int r = seg >> 1, half = seg & 1;
    for (int nd = 0; nd < NPB; ++nd) {
      if (n0 + nd < N) {
        ush4 v = reinterpret_cast<const ush4*>(sp)[(size_t)(n0 + nd) * 64 + idx];
        reinterpret_cast<ush4*>(&zsh[nd][r][half * 256])[idx] = v;
      }
    }
  }
  __syncthreads();
  // ---- aw1: 16 rows x 16 cols, ush2 paired reads ----
  {
    int row = t >> 4, j = t & 15;
    int nd = row >> 1, r = row & 1;
    const ush2* zp = reinterpret_cast<const ush2*>(zsh[nd][r]);
    float a0 = ab1[j], a1 = 0.f;
    for (int c2 = 0; c2 < 256; ++c2) {
      ush2 v = zp[c2];
      a0 += bf2f(v.x) * aw1[(2 * c2) * 16 + j];
      a1 += bf2f(v.y) * aw1[(2 * c2 + 1) * 16 + j];
    }
    wsh[row][j] = tanhf(a0 + a1) * aw2[j];
  }
  __syncthreads();
  if (t < 16) {
    float s = 0.f;
    for (int j = 0; j < 16; ++j) s += wsh[t][j];
    warr[t >> 1][t & 1] = s;
  }
  __syncthreads();
  if (t < NPB) {
    float w0 = warr[t][0], w1 = warr[t][1];
    float mxv = fmaxf(w0, w1);
    float e0 = __expf(w0 - mxv), e1 = __expf(w1 - mxv);
    float inv = 1.f / (e0 + e1);
    bsh[t][0] = e0 * inv; bsh[t][1] = e1 * inv;
  }
  __syncthreads();
  // ---- emb = b0*z0 + b1*z1 (bf16, overwrite zsh[nd][0]) ----
  {
    int nd = t >> 5, l = t & 31;
    float b0 = bsh[nd][0], b1 = bsh[nd][1];
    ush2* z0 = reinterpret_cast<ush2*>(zsh[nd][0]);
    const ush2* z1 = reinterpret_cast<const ush2*>(zsh[nd][1]);
    for (int i = 0; i < 8; ++i) {
      int c2 = l + 32 * i;
      ush2 a = z0[c2], b = z1[c2];
      ush2 o;
      o.x = f2bf(b0 * bf2f(a.x) + b1 * bf2f(b.x));
      o.y = f2bf(b0 * bf2f(a.y) + b1 * bf2f(b.y));
      z0[c2] = o;
    }
  }
  __syncthreads();
  // ---- mw1: 64 outs x 4 K-chunks, 8-node ILP ----
  {
    int o = t & 63, ch = t >> 6;
    float accv[NPB];
#pragma unroll
    for (int nd = 0; nd < NPB; ++nd) accv[nd] = 0.f;
    for (int c2 = ch * 64; c2 < ch * 64 + 64; ++c2) {
      float w0 = mw1[(2 * c2) * 64 + o];
      float w1 = mw1[(2 * c2 + 1) * 64 + o];
#pragma unroll
      for (int nd = 0; nd < NPB; ++nd) {
        ush2 v = reinterpret_cast<const ush2*>(zsh[nd][0])[c2];
        accv[nd] += bf2f(v.x) * w0 + bf2f(v.y) * w1;
      }
    }
#pragma unroll
    for (int nd = 0; nd < NPB; ++nd) psh[nd][ch * 64 + o] = accv[nd];
  }
  __syncthreads();
  {
    int nd = t >> 5, oo = t & 31;
#pragma unroll
    for (int i = 0; i < 2; ++i) {
      int o = oo + i * 32;
      float s = mb1[o] + psh[nd][o] + psh[nd][64 + o] +
                psh[nd][128 + o] + psh[nd][192 + o];
      hsh[nd][o] = tanhf(s);
    }
  }
  __syncthreads();
  if (t < NPB * 7) {
    int nd = t / 7, jo = t - nd * 7;
    float a = mb2[jo];
    for (int j = 0; j < 64; ++j) a += hsh[nd][j] * mw2[j * 7 + jo];
    o7sh[nd][jo] = a;
  }
  __syncthreads();
  if (t < NPB && n0 + t < N) {
    float m = o7sh[t][0];
    for (int k = 1; k < 7; ++k) m = fmaxf(m, o7sh[t][k]);
    float s = 0.f;
    for (int k = 0; k < 7; ++k) s += expf(o7sh[t][k] - m);
    float ls = logf(s);
    for (int k = 0; k < 7; ++k) out[(size_t)(n0 + t) * 7 + k] = o7sh[t][k] - m - ls;
  }
}

// ---------------------------------------------------------------------------
extern "C" void kernel_launch(void* const* d_in, const int* in_sizes, int n_in,
                              void* d_out, int out_size, void* d_ws, size_t ws_size,
                              hipStream_t stream) {
  (void)n_in; (void)out_size; (void)ws_size;
  const float* x     = (const float*)d_in[0];
  const int*   sadj  = (const int*)d_in[1];
  const int*   fadj  = (const int*)d_in[2];
  const int*   asadj = (const int*)d_in[3];
  const int*   afadj = (const int*)d_in[4];
  const float* W1a = (const float*)d_in[5];  const float* b1a = (const float*)d_in[6];
  const float* W1b = (const float*)d_in[7];  const float* b1b = (const float*)d_in[8];
  const float* W2a = (const float*)d_in[9];  const float* b2a = (const float*)d_in[10];
  const float* W2b = (const float*)d_in[11]; const float* b2b = (const float*)d_in[12];
  const float* W3a = (const float*)d_in[13]; const float* b3a = (const float*)d_in[14];
  const float* W3b = (const float*)d_in[15]; const float* b3b = (const float*)d_in[16];
  const float* W4a = (const float*)d_in[17]; const float* b4a = (const float*)d_in[18];
  const float* W4b = (const float*)d_in[19]; const float* b4b = (const float*)d_in[20];
  const float* Wg1a = (const float*)d_in[21]; const float* as1a = (const float*)d_in[22];
  const float* ad1a = (const float*)d_in[23]; const float* bg1a = (const float*)d_in[24];
  const float* Wg1b = (const float*)d_in[25]; const float* as1b = (const float*)d_in[26];
  const float* ad1b = (const float*)d_in[27]; const float* bg1b = (const float*)d_in[28];
  const float* Wg2a = (const float*)d_in[29]; const float* as2a = (const float*)d_in[30];
  const float* ad2a = (const float*)d_in[31]; const float* bg2a = (const float*)d_in[32];
  const float* Wg2b = (const float*)d_in[33]; const float* as2b = (const float*)d_in[34];
  const float* ad2b = (const float*)d_in[35]; const float* bg2b = (const float*)d_in[36];
  const float* aw1 = (const float*)d_in[37]; const float* ab1 = (const float*)d_in[38];
  const float* aw2 = (const float*)d_in[39];
  const float* mw1 = (const float*)d_in[40]; const float* mb1 = (const float*)d_in[41];
  const float* mw2 = (const float*)d_in[42]; const float* mb2 = (const float*)d_in[43];

  const int N = in_sizes[0] / 1024;   // 20000
  const int E = in_sizes[1] / 2;      // 160000

  // ---- workspace layout ----
  float* ws = (float*)d_ws;
  float* bufA  = ws;                          // N*512 floats; hb aliases it
  float* vaT   = bufA + (size_t)N * 512;      // 8192 floats of va tables
  float* dinvS = vaT + 8192;                  // N
  float* dinvF = dinvS + N;                   // N
  float* asrcB = dinvF + N;                   // N*4
  float* adstB = asrcB + (size_t)N * 4;       // N*4
  int* ib = (int*)(adstB + (size_t)N * 4);
  int* rowptr4 = ib;            ib += 4 * (N + 1);
  int* col4    = ib;            ib += 4 * E;
  int* deg4    = ib;            ib += 4 * N;
  int* cursor4 = ib;            ib += 4 * N;
  unsigned short* ub = (unsigned short*)(ib + ((size_t)(-(intptr_t)ib) & 3));
  unsigned short* xb = ub;            ub += (size_t)N * 1024;
  unsigned short* ab = ub;            ub += (size_t)N * 512;
  unsigned short* E1bb = ub;          ub += (size_t)N * 256;
  unsigned short* E3bb = ub;          ub += (size_t)N * 256;
  unsigned short* E4bb = ub;          ub += (size_t)N * 256;
  unsigned short* E6bb = ub;          ub += (size_t)N * 256;
  unsigned short* Wt1a = ub;  ub += 1024 * 512;
  unsigned short* Wt1b = ub;  ub += 512 * 256;
  unsigned short* Wt2a = ub;  ub += 1024 * 512;
  unsigned short* Wt2b = ub;  ub += 512 * 256;
  unsigned short* Wt3a = ub;  ub += 256 * 128;
  unsigned short* Wt3b = ub;  ub += 128 * 256;
  unsigned short* Wt4a = ub;  ub += 256 * 128;
  unsigned short* Wt4b = ub;  ub += 128 * 256;
  unsigned short* Wtg1a = ub; ub += 256 * 512;
  unsigned short* Wtg1b = ub; ub += 512 * 256;
  unsigned short* Wtg2a = ub; ub += 256 * 512;
  unsigned short* Wtg2b = ub; ub += 512 * 256;
  unsigned short* hb = (unsigned short*)bufA;
  float* vag1a = vaT;               // [256][8]
  float* vag1b = vaT + 2048;        // [512][2]
  float* vag2a = vaT + 3072;        // [256][8]
  float* vag2b = vaT + 5120;        // [512][2]
  int* rowptrS = rowptr4;
  int* rowptrF = rowptr4 + (N + 1);
  int* rowptrA1 = rowptr4 + 2 * (N + 1);
  int* rowptrA2 = rowptr4 + 3 * (N + 1);
  int* colS = col4;
  int* colF = col4 + E;
  int* colA1 = col4 + 2 * E;
  int* colA2 = col4 + 3 * E;

  // ---- batched setup: transpose-casts, va projections, x cast, CSR ----
  {
    TcJobs j;
    const float* srcs[12] = {W1a, W1b, W2a, W2b, W3a, W3b, W4a, W4b, Wg1a, Wg1b, Wg2a, Wg2b};
    unsigned short* dsts[12] = {Wt1a, Wt1b, Wt2a, Wt2b, Wt3a, Wt3b, Wt4a, Wt4b,
                                Wtg1a, Wtg1b, Wtg2a, Wtg2b};
    int Ks[12] = {1024, 512, 1024, 512, 256, 128, 256, 128, 256, 512, 256, 512};
    int Fs[12] = {512, 256, 512, 256, 128, 256, 128, 256, 512, 256, 512, 256};
    int acc = 0;
    for (int i = 0; i < 12; ++i) {
      j.src[i] = srcs[i]; j.dst[i] = dsts[i]; j.K[i] = Ks[i]; j.F[i] = Fs[i];
      j.start[i] = acc;
      acc += (Ks[i] / 32) * (Fs[i] / 32);
    }
    j.start[12] = acc;
    tc_batch_k<<<acc, 256, 0, stream>>>(j);
  }
  va4_k<<<24, 256, 0, stream>>>(Wg1a, as1a, ad1a, vag1a, Wg1b, as1b, ad1b, vag1b,
                                Wg2a, as2a, ad2a, vag2a, Wg2b, as2b, ad2b, vag2b);
  cast_bf16_k<<<cdiv(N * 1024 / 4, 256), 256, 0, stream>>>(x, xb, N * 1024 / 4);
  zero_int_k<<<cdiv(4 * N, 256), 256, 0, stream>>>(deg4, 4 * N);
  hist4_k<<<cdiv(4 * E, 256), 256, 0, stream>>>(sadj, fadj, asadj, afadj, deg4, E, N);
  scan4_k<<<4, 1024, 0, stream>>>(deg4, rowptr4, cursor4, N);
  dinv2_k<<<cdiv(2 * N, 256), 256, 0, stream>>>(deg4, dinvS, dinvF, N);
  place4_k<<<cdiv(4 * E, 256), 256, 0, stream>>>(sadj, fadj, asadj, afadj, cursor4, col4, E, N);

  auto gemmB = [&](const unsigned short* Ab, const unsigned short* Wt, int K, int F) {
    gemm_bf16_k<<<dim3(F / 128, cdiv(N, 128)), 256, 0, stream>>>(Ab, Wt, hb, N, K, F);
  };
  auto gcnA = [&](const unsigned short* inb, const unsigned short* Wt, const float* b,
                  const int* rowptr, const int* col, const float* dinv, int K, int F) {
    gemmB(inb, Wt, K, F);
    if (F == 512) gcn_gather_k<1, 0, 2><<<N, 256, 0, stream>>>(hb, rowptr, col, dinv, b, ab, nullptr, F);
    else          gcn_gather_k<1, 0, 1><<<N, 256, 0, stream>>>(hb, rowptr, col, dinv, b, ab, nullptr, F);
  };
  auto gcnAE = [&](const unsigned short* inb, const unsigned short* Wt, const float* b,
                   const int* rowptr, const int* col, const float* dinv,
                   unsigned short* Eb, int K, int F) {
    gemmB(inb, Wt, K, F);
    gcn_gather_k<1, 1, 1><<<N, 256, 0, stream>>>(hb, rowptr, col, dinv, b, ab, Eb, F);
  };
  auto gcnE = [&](const unsigned short* inb, const unsigned short* Wt, const float* b,
                  const int* rowptr, const int* col, const float* dinv,
                  unsigned short* Eb, int K, int F) {
    gemmB(inb, Wt, K, F);
    gcn_gather_k<0, 1, 1><<<N, 256, 0, stream>>>(hb, rowptr, col, dinv, b, nullptr, Eb, F);
  };
  auto gatA = [&](const unsigned short* Wt, const float* va, const float* b,
                  const int* rowptr, const int* col) {
    gemmB(ab, Wt, 256, 512);
    attn_dot_k<256, 4><<<cdiv(N, 4), 256, 0, stream>>>(ab, va, asrcB, adstB, N);
    gat_fused_k<4, 128, 0><<<N, 256, 0, stream>>>(hb, asrcB, adstB, rowptr, col, b, ab);
  };
  auto gatB = [&](const unsigned short* Wt, const float* va, const float* b,
                  const int* rowptr, const int* col) {
    gemmB(ab, Wt, 512, 256);
    attn_dot_k<512, 1><<<cdiv(N, 4), 256, 0, stream>>>(ab, va, asrcB, adstB, N);
    gat_fused_k<1, 256, 1><<<N, 256, 0, stream>>>(hb, asrcB, adstB, rowptr, col, b, ab);
  };

  // ---- path 1: x --GCN1--> E1 --GAT1--> emb2 --GCN3--> E3 ----
  gcnA(xb, Wt1a, b1a, rowptrS, colS, dinvS, 1024, 512);
  gcnAE(ab, Wt1b, b1b, rowptrS, colS, dinvS, E1bb, 512, 256);
  gatA(Wtg1a, vag1a, bg1a, rowptrA1, colA1);
  gatB(Wtg1b, vag1b, bg1b, rowptrA1, colA1);
  gcnA(ab, Wt3a, b3a, rowptrS, colS, dinvS, 256, 128);
  gcnE(ab, Wt3b, b3b, rowptrS, colS, dinvS, E3bb, 128, 256);

  // ---- path 2: x --GCN2--> E4 --GAT2--> emb5 --GCN4--> E6 ----
  gcnA(xb, Wt2a, b2a, rowptrF, colF, dinvF, 1024, 512);
  gcnAE(ab, Wt2b, b2b, rowptrF, colF, dinvF, E4bb, 512, 256);
  gatA(Wtg2a, vag2a, bg2a, rowptrA2, colA2);
  gatB(Wtg2b, vag2b, bg2b, rowptrA2, colA2);
  gcnA(ab, Wt4a, b4a, rowptrF, colF, dinvF, 256, 128);
  gcnE(ab, Wt4b, b4b, rowptrF, colF, dinvF, E6bb, 128, 256);

  // ---- fusion + MLP + log_softmax ----
  final3_k<<<cdiv(N, NPB), 256, 0, stream>>>(E1bb, E3bb, E4bb, E6bb,
                                             aw1, ab1, aw2, mw1, mb1, mw2, mb2,
                                             (float*)d_out, N);
}

// Round 9
// 1137.780 us; speedup vs baseline: 9.8844x; 1.1759x over previous
//
#include <hip/hip_runtime.h>
#include <cstddef>
#include <cstdint>
#include <cmath>

// ---------------------------------------------------------------------------
// HiGLDP forward, round 9: wave-per-node gather/GAT kernels (16B/lane loads,
// shuffle reductions, no LDS/barriers); bf16 everywhere; batched setup.
// ---------------------------------------------------------------------------

static inline int cdiv(int a, int b) { return (a + b - 1) / b; }

typedef __attribute__((ext_vector_type(8))) unsigned short ush8;
typedef __attribute__((ext_vector_type(4))) unsigned short ush4;
typedef __attribute__((ext_vector_type(2))) unsigned short ush2;
typedef __attribute__((ext_vector_type(8))) short bf16x8;
typedef __attribute__((ext_vector_type(4))) float f32x4;

__device__ __forceinline__ unsigned short f2bf(float f) {
  unsigned u = __float_as_uint(f);
  unsigned r = 0x7fffu + ((u >> 16) & 1u);
  return (unsigned short)((u + r) >> 16);
}
__device__ __forceinline__ float bf2f(unsigned short u) {
  return __uint_as_float((unsigned)u << 16);
}

// ---------------- batched CSR build ----------------
__global__ void zero_int_k(int* __restrict__ p, int n) {
  int i = blockIdx.x * 256 + threadIdx.x;
  if (i < n) p[i] = 0;
}
__global__ void hist4_k(const int* __restrict__ e0, const int* __restrict__ e1,
                        const int* __restrict__ e2, const int* __restrict__ e3,
                        int* __restrict__ deg4, int E, int N) {
  int i = blockIdx.x * 256 + threadIdx.x;
  if (i >= 4 * E) return;
  const int* p; int e, off;
  if (i < E)          { p = e0; e = i;         off = 0; }
  else if (i < 2 * E) { p = e1; e = i - E;     off = N; }
  else if (i < 3 * E) { p = e2; e = i - 2 * E; off = 2 * N; }
  else                { p = e3; e = i - 3 * E; off = 3 * N; }
  atomicAdd(&deg4[off + p[E + e]], 1);
}
__global__ __launch_bounds__(1024) void scan4_k(const int* __restrict__ deg4,
                                                int* __restrict__ rowptr4,
                                                int* __restrict__ cursor4, int N) {
  __shared__ int part[1024];
  const int b = blockIdx.x;
  const int* deg = deg4 + (size_t)b * N;
  int* rowptr = rowptr4 + (size_t)b * (N + 1);
  int* cursor = cursor4 + (size_t)b * N;
  const int t = threadIdx.x;
  const int CH = (N + 1023) / 1024;
  const int base = t * CH;
  int loc = 0;
  for (int i = 0; i < CH; ++i)
    if (base + i < N) loc += deg[base + i];
  part[t] = loc;
  __syncthreads();
  for (int off = 1; off < 1024; off <<= 1) {
    int v = (t >= off) ? part[t - off] : 0;
    __syncthreads();
    part[t] += v;
    __syncthreads();
  }
  int run = (t > 0) ? part[t - 1] : 0;
  for (int i = 0; i < CH; ++i)
    if (base + i < N) {
      rowptr[base + i] = run;
      cursor[base + i] = run;
      run += deg[base + i];
    }
  if (t == 1023) rowptr[N] = part[1023];
}
__global__ void place4_k(const int* __restrict__ e0, const int* __restrict__ e1,
                         const int* __restrict__ e2, const int* __restrict__ e3,
                         int* __restrict__ cursor4, int* __restrict__ col4,
                         int E, int N) {
  int i = blockIdx.x * 256 + threadIdx.x;
  if (i >= 4 * E) return;
  const int* p; int e, w;
  if (i < E)          { p = e0; e = i;         w = 0; }
  else if (i < 2 * E) { p = e1; e = i - E;     w = 1; }
  else if (i < 3 * E) { p = e2; e = i - 2 * E; w = 2; }
  else                { p = e3; e = i - 3 * E; w = 3; }
  int pos = atomicAdd(&cursor4[(size_t)w * N + p[E + e]], 1);
  col4[(size_t)w * E + pos] = p[e];
}
__global__ void dinv2_k(const int* __restrict__ deg4, float* __restrict__ dinvS,
                        float* __restrict__ dinvF, int N) {
  int i = blockIdx.x * 256 + threadIdx.x;
  if (i < N) dinvS[i] = rsqrtf((float)deg4[i] + 1.f);
  else if (i < 2 * N) dinvF[i - N] = rsqrtf((float)deg4[i] + 1.f);
}

// ---------------- casts ----------------
__global__ void cast_bf16_k(const float* __restrict__ in, unsigned short* __restrict__ out,
                            int n4) {
  int i = blockIdx.x * 256 + threadIdx.x;
  if (i >= n4) return;
  float4 v = reinterpret_cast<const float4*>(in)[i];
  ush4 o;
  o.x = f2bf(v.x); o.y = f2bf(v.y); o.z = f2bf(v.z); o.w = f2bf(v.w);
  reinterpret_cast<ush4*>(out)[i] = o;
}

struct TcJobs {
  const float* src[12];
  unsigned short* dst[12];
  int K[12];
  int F[12];
  int start[13];
};
__global__ __launch_bounds__(256) void tc_batch_k(TcJobs j) {
  __shared__ float t[32][33];
  int flat = blockIdx.x;
  int job = 0;
  while (flat >= j.start[job + 1]) ++job;
  int local = flat - j.start[job];
  const float* W = j.src[job];
  unsigned short* Wt = j.dst[job];
  int K = j.K[job], F = j.F[job];
  int tilesX = K >> 5;
  int bk = (local % tilesX) * 32, bf = (local / tilesX) * 32;
  int tx = threadIdx.x & 31, ty = threadIdx.x >> 5;
  for (int i = ty; i < 32; i += 8) t[i][tx] = W[(size_t)(bk + i) * F + bf + tx];
  __syncthreads();
  for (int i = ty; i < 32; i += 8)
    Wt[(size_t)(bf + i) * K + bk + tx] = f2bf(t[tx][i]);
}

__device__ __forceinline__ void va_one(const float* __restrict__ W,
                                       const float* __restrict__ a_s,
                                       const float* __restrict__ a_d,
                                       float* __restrict__ va,
                                       int H, int C, int idx) {
  int k = idx / (2 * H), o = idx - k * 2 * H;
  int hh = (o >= H) ? (o - H) : o;
  const float* a = (o >= H) ? a_d : a_s;
  float s = 0.f;
  for (int c = 0; c < C; ++c) s += W[(size_t)k * (H * C) + hh * C + c] * a[hh * C + c];
  va[k * 2 * H + o] = s;
}
__global__ void va4_k(const float* W0, const float* s0, const float* d0, float* v0,
                      const float* W1, const float* s1, const float* d1, float* v1,
                      const float* W2, const float* s2, const float* d2, float* v2,
                      const float* W3, const float* s3, const float* d3, float* v3) {
  int i = blockIdx.x * 256 + threadIdx.x;
  if (i < 2048)      va_one(W0, s0, d0, v0, 4, 128, i);
  else if (i < 3072) va_one(W1, s1, d1, v1, 1, 256, i - 2048);
  else if (i < 5120) va_one(W2, s2, d2, v2, 4, 128, i - 3072);
  else if (i < 6144) va_one(W3, s3, d3, v3, 1, 256, i - 5120);
}

// ---------------- bf16 MFMA GEMM: Cb[M,F] = bf16(A[M,K] @ Wt[F,K]^T) --------
#define LDT 40
__global__ __launch_bounds__(256) void gemm_bf16_k(
    const unsigned short* __restrict__ A,
    const unsigned short* __restrict__ Bt,
    unsigned short* __restrict__ Cb, int M, int K, int F) {
  __shared__ unsigned short Asl[128 * LDT];
  __shared__ unsigned short Bsl[128 * LDT];
  const int tid = threadIdx.x;
  const int wid = tid >> 6, lane = tid & 63;
  const int wr = (wid >> 1) * 64, wc = (wid & 1) * 64;
  const int bm = blockIdx.y * 128, bn = blockIdx.x * 128;
  const int l15 = lane & 15, lk = lane >> 4;
  f32x4 acc[4][4] = {};
  for (int k0 = 0; k0 < K; k0 += 32) {
    __syncthreads();
#pragma unroll
    for (int i = 0; i < 2; ++i) {
      int c = tid + i * 256;
      int r = c >> 2;
      int off = (c & 3) << 3;
      int gr = bm + r;
      ush8 av = {};
      if (gr < M) av = *reinterpret_cast<const ush8*>(A + (size_t)gr * K + k0 + off);
      *reinterpret_cast<ush8*>(&Asl[r * LDT + off]) = av;
      ush8 bv = *reinterpret_cast<const ush8*>(Bt + (size_t)(bn + r) * K + k0 + off);
      *reinterpret_cast<ush8*>(&Bsl[r * LDT + off]) = bv;
    }
    __syncthreads();
    bf16x8 af[4], bfv[4];
#pragma unroll
    for (int mi = 0; mi < 4; ++mi)
      af[mi] = *reinterpret_cast<const bf16x8*>(&Asl[(wr + mi * 16 + l15) * LDT + (lk << 3)]);
#pragma unroll
    for (int ni = 0; ni < 4; ++ni)
      bfv[ni] = *reinterpret_cast<const bf16x8*>(&Bsl[(wc + ni * 16 + l15) * LDT + (lk << 3)]);
#pragma unroll
    for (int mi = 0; mi < 4; ++mi)
#pragma unroll
      for (int ni = 0; ni < 4; ++ni)
        acc[mi][ni] = __builtin_amdgcn_mfma_f32_16x16x32_bf16(af[mi], bfv[ni], acc[mi][ni], 0, 0, 0);
  }
#pragma unroll
  for (int mi = 0; mi < 4; ++mi) {
    int gr0 = bm + wr + mi * 16 + (lk << 2);
#pragma unroll
    for (int ni = 0; ni < 4; ++ni) {
      int gc = bn + wc + ni * 16 + l15;
#pragma unroll
      for (int r4 = 0; r4 < 4; ++r4) {
        int gr = gr0 + r4;
        if (gr < M) Cb[(size_t)gr * F + gc] = f2bf(acc[mi][ni][r4]);
      }
    }
  }
}

// ---------------- vector bf16 row helpers ----------------
template <int EPL>
__device__ __forceinline__ void load_row(const unsigned short* __restrict__ p,
                                         float* __restrict__ v) {
  if (EPL == 8) {
    ush8 t = *reinterpret_cast<const ush8*>(p);
#pragma unroll
    for (int i = 0; i < 8; ++i) v[i] = bf2f(t[i]);
  } else if (EPL == 4) {
    ush4 t = *reinterpret_cast<const ush4*>(p);
    v[0] = bf2f(t.x); v[1] = bf2f(t.y); v[2] = bf2f(t.z); v[3] = bf2f(t.w);
  } else {
    ush2 t = *reinterpret_cast<const ush2*>(p);
    v[0] = bf2f(t.x); v[1] = bf2f(t.y);
  }
}
template <int EPL>
__device__ __forceinline__ void store_row(unsigned short* __restrict__ p,
                                          const float* __restrict__ v) {
  if (EPL == 8) {
    ush8 t;
#pragma unroll
    for (int i = 0; i < 8; ++i) t[i] = f2bf(v[i]);
    *reinterpret_cast<ush8*>(p) = t;
  } else if (EPL == 4) {
    ush4 t;
    t.x = f2bf(v[0]); t.y = f2bf(v[1]); t.z = f2bf(v[2]); t.w = f2bf(v[3]);
    *reinterpret_cast<ush4*>(p) = t;
  } else {
    ush2 t;
    t.x = f2bf(v[0]); t.y = f2bf(v[1]);
    *reinterpret_cast<ush2*>(p) = t;
  }
}

// ---------------- GCN gather: wave per node ----------------
// F = EPL*64. WA -> write ab, WE -> write E buffer.
template <int WA, int WE, int EPL>
__global__ __launch_bounds__(256) void gcn_gather_w_k(
    const unsigned short* __restrict__ h, const int* __restrict__ rowptr,
    const int* __restrict__ col, const float* __restrict__ dinv,
    const float* __restrict__ bias, unsigned short* __restrict__ outa,
    unsigned short* __restrict__ oute, int N) {
  constexpr int F = EPL * 64;
  const int node = blockIdx.x * 4 + (threadIdx.x >> 6);
  const int lane = threadIdx.x & 63;
  if (node >= N) return;
  const int beg = rowptr[node], end = rowptr[node + 1];
  const float di = dinv[node];
  const int f0 = lane * EPL;
  float acc[EPL], row[EPL];
  load_row<EPL>(h + (size_t)node * F + f0, row);
  {
    float w = di * di;
#pragma unroll
    for (int i = 0; i < EPL; ++i) acc[i] = row[i] * w;
  }
  for (int p = beg; p < end; ++p) {
    int s = col[p];
    float w = dinv[s] * di;
    load_row<EPL>(h + (size_t)s * F + f0, row);
#pragma unroll
    for (int i = 0; i < EPL; ++i) acc[i] += row[i] * w;
  }
#pragma unroll
  for (int i = 0; i < EPL; ++i) acc[i] = fmaxf(acc[i] + bias[f0 + i], 0.f);
  if (WA) store_row<EPL>(outa + (size_t)node * F + f0, acc);
  if (WE) store_row<EPL>(oute + (size_t)node * F + f0, acc);
}

// ---------------- GAT logits: [asrc|adst] = in(bf16) @ va ----------
template <int K, int H>
__global__ __launch_bounds__(256) void attn_dot_k(
    const unsigned short* __restrict__ in, const float* __restrict__ va,
    float* __restrict__ asrc, float* __restrict__ adst, int N) {
  constexpr int EPL = K / 64;
  const int n = blockIdx.x * 4 + (threadIdx.x >> 6);
  const int lane = threadIdx.x & 63;
  if (n >= N) return;
  float acc[2 * H] = {};
  float xv[EPL];
  load_row<EPL>(in + (size_t)n * K + lane * EPL, xv);
#pragma unroll
  for (int j = 0; j < EPL; ++j) {
    const float* vp = va + (size_t)(lane * EPL + j) * 2 * H;
#pragma unroll
    for (int o = 0; o < 2 * H; ++o) acc[o] += xv[j] * vp[o];
  }
#pragma unroll
  for (int off = 32; off >= 1; off >>= 1)
#pragma unroll
    for (int o = 0; o < 2 * H; ++o) acc[o] += __shfl_xor(acc[o], off);
  if (lane == 0) {
#pragma unroll
    for (int hh = 0; hh < H; ++hh) {
      asrc[n * H + hh] = acc[hh];
      adst[n * H + hh] = acc[H + hh];
    }
  }
}

// ---------------- GAT fused: wave per node, shuffle reductions --------------
template <int H, int C, int EPI>
__global__ __launch_bounds__(256) void gat_fused_w_k(
    const unsigned short* __restrict__ h, const float* __restrict__ asrc,
    const float* __restrict__ adst, const int* __restrict__ rowptr,
    const int* __restrict__ col, const float* __restrict__ bias,
    unsigned short* __restrict__ out, int N) {
  constexpr int F = H * C;
  constexpr int EPL = F / 64;
  const int node = blockIdx.x * 4 + (threadIdx.x >> 6);
  const int lane = threadIdx.x & 63;
  if (node >= N) return;
  const int beg = rowptr[node], end = rowptr[node + 1];

  float ad[H], vself[H];
#pragma unroll
  for (int k = 0; k < H; ++k) {
    ad[k] = adst[node * H + k];
    float v = asrc[node * H + k] + ad[k];
    vself[k] = v > 0.f ? v : 0.2f * v;
  }
  // ---- pass 1: max over edges (lanes stride edges) ----
  float m[H];
#pragma unroll
  for (int k = 0; k < H; ++k) m[k] = vself[k];
  for (int p = beg + lane; p < end; p += 64) {
    int s = col[p];
#pragma unroll
    for (int k = 0; k < H; ++k) {
      float v = asrc[s * H + k] + ad[k];
      v = v > 0.f ? v : 0.2f * v;
      m[k] = fmaxf(m[k], v);
    }
  }
#pragma unroll
  for (int off = 32; off >= 1; off >>= 1)
#pragma unroll
    for (int k = 0; k < H; ++k) m[k] = fmaxf(m[k], __shfl_xor(m[k], off));
  // ---- pass 2: denom ----
  float dn[H] = {};
  for (int p = beg + lane; p < end; p += 64) {
    int s = col[p];
#pragma unroll
    for (int k = 0; k < H; ++k) {
      float v = asrc[s * H + k] + ad[k];
      v = v > 0.f ? v : 0.2f * v;
      dn[k] += __expf(v - m[k]);
    }
  }
#pragma unroll
  for (int off = 32; off >= 1; off >>= 1)
#pragma unroll
    for (int k = 0; k < H; ++k) dn[k] += __shfl_xor(dn[k], off);
  float invD[H];
#pragma unroll
  for (int k = 0; k < H; ++k)
    invD[k] = 1.f / (dn[k] + __expf(vself[k] - m[k]) + 1e-16f);
  // ---- pass 3: weighted feature gather (serial edges, vector rows) ----
  const int f0 = lane * EPL;
  const int k0 = f0 / C;  // constant per lane (EPL divides C)
  float acc[EPL], row[EPL];
  load_row<EPL>(h + (size_t)node * F + f0, row);
  {
    float aself = __expf(vself[k0] - m[k0]) * invD[k0];
#pragma unroll
    for (int i = 0; i < EPL; ++i) acc[i] = aself * row[i];
  }
  for (int p = beg; p < end; ++p) {
    int s = col[p];
    float v = asrc[s * H + k0] + ad[k0];
    v = v > 0.f ? v : 0.2f * v;
    float a = __expf(v - m[k0]) * invD[k0];
    load_row<EPL>(h + (size_t)s * F + f0, row);
#pragma unroll
    for (int i = 0; i < EPL; ++i) acc[i] += a * row[i];
  }
  // ---- epilogue ----
  if (EPI == 0) {
#pragma unroll
    for (int i = 0; i < EPL; ++i) {
      float v = acc[i] + bias[f0 + i];
      acc[i] = v > 0.f ? v : (__expf(v) - 1.f);
    }
    store_row<EPL>(out + (size_t)node * F + f0, acc);
  } else {
    // H==1: log_softmax over the F=256 row (wave-internal) then relu
#pragma unroll
    for (int i = 0; i < EPL; ++i) acc[i] += bias[f0 + i];
    float r = acc[0];
#pragma unroll
    for (int i = 1; i < EPL; ++i) r = fmaxf(r, acc[i]);
#pragma unroll
    for (int off = 32; off >= 1; off >>= 1) r = fmaxf(r, __shfl_xor(r, off));
    float se = 0.f;
#pragma unroll
    for (int i = 0; i < EPL; ++i) se += __expf(acc[i] - r);
#pragma unroll
    for (int off = 32; off >= 1; off >>= 1) se += __shfl_xor(se, off);
    float ls = logf(se);
#pragma unroll
    for (int i = 0; i < EPL; ++i) acc[i] = fmaxf(acc[i] - r - ls, 0.f);
    store_row<EPL>(out + (size_t)node * F + f0, acc);
  }
}

// ---------------- final fusion + MLP + log_softmax (bf16 z, 8 nodes/block) --
#define NPB 8
__global__ __launch_bounds__(256) void final3_k(
    const unsigned short* __restrict__ E1, const unsigned short* __restrict__ E3,
    const unsigned short* __restrict__ E4, const unsigned short* __restrict__ E6,
    const float* __restrict__ aw1, const float* __restrict__ ab1,
    const float* __restrict__ aw2, const float* __restrict__ mw1,
    const float* __restrict__ mb1, const float* __restrict__ mw2,
    const float* __restrict__ mb2, float* __restrict__ out, int N) {
  __shared__ unsigned short zsh[NPB][2][512];
  __shared__ float psh[NPB][256];
  __shared__ float wsh[NPB * 2][17];
  __shared__ float warr[NPB][2];
  __shared__ float bsh[NPB][2];
  __shared__ float hsh[NPB][64];
  __shared__ float o7sh[NPB][8];
  const int t = threadIdx.x;
  const int n0 = blockIdx.x * NPB;
  {
    int seg = t >> 6, idx = t & 63;
    const unsigned short* sp = (seg == 0) ? E1 : (seg == 1) ? E3 : (seg == 2) ? E4 : E6;
    int r = seg >> 1, half = seg & 1;
    for (int nd = 0; nd < NPB; ++nd) {
      if (n0 + nd < N) {
        ush4 v = reinterpret_cast<const ush4*>(sp)[(size_t)(n0 + nd) * 64 + idx];
        reinterpret_cast<ush4*>(&zsh[nd][r][half * 256])[idx] = v;
      }
    }
  }
  __syncthreads();
  {
    int row = t >> 4, j = t & 15;
    int nd = row >> 1, r = row & 1;
    const ush2* zp = reinterpret_cast<const ush2*>(zsh[nd][r]);
    float a0 = ab1[j], a1 = 0.f;
    for (int c2 = 0; c2 < 256; ++c2) {
      ush2 v = zp[c2];
      a0 += bf2f(v.x) * aw1[(2 * c2) * 16 + j];
      a1 += bf2f(v.y) * aw1[(2 * c2 + 1) * 16 + j];
    }
    wsh[row][j] = tanhf(a0 + a1) * aw2[j];
  }
  __syncthreads();
  if (t < 16) {
    float s = 0.f;
    for (int j = 0; j < 16; ++j) s += wsh[t][j];
    warr[t >> 1][t & 1] = s;
  }
  __syncthreads();
  if (t < NPB) {
    float w0 = warr[t][0], w1 = warr[t][1];
    float mxv = fmaxf(w0, w1);
    float e0 = __expf(w0 - mxv), e1 = __expf(w1 - mxv);
    float inv = 1.f / (e0 + e1);
    bsh[t][0] = e0 * inv; bsh[t][1] = e1 * inv;
  }
  __syncthreads();
  {
    int nd = t >> 5, l = t & 31;
    float b0 = bsh[nd][0], b1 = bsh[nd][1];
    ush2* z0 = reinterpret_cast<ush2*>(zsh[nd][0]);
    const ush2* z1 = reinterpret_cast<const ush2*>(zsh[nd][1]);
    for (int i = 0; i < 8; ++i) {
      int c2 = l + 32 * i;
      ush2 a = z0[c2], b = z1[c2];
      ush2 o;
      o.x = f2bf(b0 * bf2f(a.x) + b1 * bf2f(b.x));
      o.y = f2bf(b0 * bf2f(a.y) + b1 * bf2f(b.y));
      z0[c2] = o;
    }
  }
  __syncthreads();
  {
    int o = t & 63, ch = t >> 6;
    float accv[NPB];
#pragma unroll
    for (int nd = 0; nd < NPB; ++nd) accv[nd] = 0.f;
    for (int c2 = ch * 64; c2 < ch * 64 + 64; ++c2) {
      float w0 = mw1[(2 * c2) * 64 + o];
      float w1 = mw1[(2 * c2 + 1) * 64 + o];
#pragma unroll
      for (int nd = 0; nd < NPB; ++nd) {
        ush2 v = reinterpret_cast<const ush2*>(zsh[nd][0])[c2];
        accv[nd] += bf2f(v.x) * w0 + bf2f(v.y) * w1;
      }
    }
#pragma unroll
    for (int nd = 0; nd < NPB; ++nd) psh[nd][ch * 64 + o] = accv[nd];
  }
  __syncthreads();
  {
    int nd = t >> 5, oo = t & 31;
#pragma unroll
    for (int i = 0; i < 2; ++i) {
      int o = oo + i * 32;
      float s = mb1[o] + psh[nd][o] + psh[nd][64 + o] +
                psh[nd][128 + o] + psh[nd][192 + o];
      hsh[nd][o] = tanhf(s);
    }
  }
  __syncthreads();
  if (t < NPB * 7) {
    int nd = t / 7, jo = t - nd * 7;
    float a = mb2[jo];
    for (int j = 0; j < 64; ++j) a += hsh[nd][j] * mw2[j * 7 + jo];
    o7sh[nd][jo] = a;
  }
  __syncthreads();
  if (t < NPB && n0 + t < N) {
    float m = o7sh[t][0];
    for (int k = 1; k < 7; ++k) m = fmaxf(m, o7sh[t][k]);
    float s = 0.f;
    for (int k = 0; k < 7; ++k) s += expf(o7sh[t][k] - m);
    float ls = logf(s);
    for (int k = 0; k < 7; ++k) out[(size_t)(n0 + t) * 7 + k] = o7sh[t][k] - m - ls;
  }
}

// ---------------------------------------------------------------------------
extern "C" void kernel_launch(void* const* d_in, const int* in_sizes, int n_in,
                              void* d_out, int out_size, void* d_ws, size_t ws_size,
                              hipStream_t stream) {
  (void)n_in; (void)out_size; (void)ws_size;
  const float* x     = (const float*)d_in[0];
  const int*   sadj  = (const int*)d_in[1];
  const int*   fadj  = (const int*)d_in[2];
  const int*   asadj = (const int*)d_in[3];
  const int*   afadj = (const int*)d_in[4];
  const float* W1a = (const float*)d_in[5];  const float* b1a = (const float*)d_in[6];
  const float* W1b = (const float*)d_in[7];  const float* b1b = (const float*)d_in[8];
  const float* W2a = (const float*)d_in[9];  const float* b2a = (const float*)d_in[10];
  const float* W2b = (const float*)d_in[11]; const float* b2b = (const float*)d_in[12];
  const float* W3a = (const float*)d_in[13]; const float* b3a = (const float*)d_in[14];
  const float* W3b = (const float*)d_in[15]; const float* b3b = (const float*)d_in[16];
  const float* W4a = (const float*)d_in[17]; const float* b4a = (const float*)d_in[18];
  const float* W4b = (const float*)d_in[19]; const float* b4b = (const float*)d_in[20];
  const float* Wg1a = (const float*)d_in[21]; const float* as1a = (const float*)d_in[22];
  const float* ad1a = (const float*)d_in[23]; const float* bg1a = (const float*)d_in[24];
  const float* Wg1b = (const float*)d_in[25]; const float* as1b = (const float*)d_in[26];
  const float* ad1b = (const float*)d_in[27]; const float* bg1b = (const float*)d_in[28];
  const float* Wg2a = (const float*)d_in[29]; const float* as2a = (const float*)d_in[30];
  const float* ad2a = (const float*)d_in[31]; const float* bg2a = (const float*)d_in[32];
  const float* Wg2b = (const float*)d_in[33]; const float* as2b = (const float*)d_in[34];
  const float* ad2b = (const float*)d_in[35]; const float* bg2b = (const float*)d_in[36];
  const float* aw1 = (const float*)d_in[37]; const float* ab1 = (const float*)d_in[38];
  const float* aw2 = (const float*)d_in[39];
  const float* mw1 = (const float*)d_in[40]; const float* mb1 = (const float*)d_in[41];
  const float* mw2 = (const float*)d_in[42]; const float* mb2 = (const float*)d_in[43];

  const int N = in_sizes[0] / 1024;   // 20000
  const int E = in_sizes[1] / 2;      // 160000

  // ---- workspace layout ----
  float* ws = (float*)d_ws;
  float* bufA  = ws;                          // N*512 floats; hb aliases it
  float* vaT   = bufA + (size_t)N * 512;      // 8192 floats
  float* dinvS = vaT + 8192;                  // N
  float* dinvF = dinvS + N;                   // N
  float* asrcB = dinvF + N;                   // N*4
  float* adstB = asrcB + (size_t)N * 4;       // N*4
  int* ib = (int*)(adstB + (size_t)N * 4);
  int* rowptr4 = ib;            ib += 4 * (N + 1);
  int* col4    = ib;            ib += 4 * E;
  int* deg4    = ib;            ib += 4 * N;
  int* cursor4 = ib;            ib += 4 * N;
  unsigned short* ub = (unsigned short*)(ib + ((size_t)(-(intptr_t)ib) & 3));
  unsigned short* xb = ub;            ub += (size_t)N * 1024;
  unsigned short* ab = ub;            ub += (size_t)N * 512;
  unsigned short* E1bb = ub;          ub += (size_t)N * 256;
  unsigned short* E3bb = ub;          ub += (size_t)N * 256;
  unsigned short* E4bb = ub;          ub += (size_t)N * 256;
  unsigned short* E6bb = ub;          ub += (size_t)N * 256;
  unsigned short* Wt1a = ub;  ub += 1024 * 512;
  unsigned short* Wt1b = ub;  ub += 512 * 256;
  unsigned short* Wt2a = ub;  ub += 1024 * 512;
  unsigned short* Wt2b = ub;  ub += 512 * 256;
  unsigned short* Wt3a = ub;  ub += 256 * 128;
  unsigned short* Wt3b = ub;  ub += 128 * 256;
  unsigned short* Wt4a = ub;  ub += 256 * 128;
  unsigned short* Wt4b = ub;  ub += 128 * 256;
  unsigned short* Wtg1a = ub; ub += 256 * 512;
  unsigned short* Wtg1b = ub; ub += 512 * 256;
  unsigned short* Wtg2a = ub; ub += 256 * 512;
  unsigned short* Wtg2b = ub; ub += 512 * 256;
  unsigned short* hb = (unsigned short*)bufA;
  float* vag1a = vaT;
  float* vag1b = vaT + 2048;
  float* vag2a = vaT + 3072;
  float* vag2b = vaT + 5120;
  int* rowptrS = rowptr4;
  int* rowptrF = rowptr4 + (N + 1);
  int* rowptrA1 = rowptr4 + 2 * (N + 1);
  int* rowptrA2 = rowptr4 + 3 * (N + 1);
  int* colS = col4;
  int* colF = col4 + E;
  int* colA1 = col4 + 2 * E;
  int* colA2 = col4 + 3 * E;

  // ---- batched setup ----
  {
    TcJobs j;
    const float* srcs[12] = {W1a, W1b, W2a, W2b, W3a, W3b, W4a, W4b, Wg1a, Wg1b, Wg2a, Wg2b};
    unsigned short* dsts[12] = {Wt1a, Wt1b, Wt2a, Wt2b, Wt3a, Wt3b, Wt4a, Wt4b,
                                Wtg1a, Wtg1b, Wtg2a, Wtg2b};
    int Ks[12] = {1024, 512, 1024, 512, 256, 128, 256, 128, 256, 512, 256, 512};
    int Fs[12] = {512, 256, 512, 256, 128, 256, 128, 256, 512, 256, 512, 256};
    int acc = 0;
    for (int i = 0; i < 12; ++i) {
      j.src[i] = srcs[i]; j.dst[i] = dsts[i]; j.K[i] = Ks[i]; j.F[i] = Fs[i];
      j.start[i] = acc;
      acc += (Ks[i] / 32) * (Fs[i] / 32);
    }
    j.start[12] = acc;
    tc_batch_k<<<acc, 256, 0, stream>>>(j);
  }
  va4_k<<<24, 256, 0, stream>>>(Wg1a, as1a, ad1a, vag1a, Wg1b, as1b, ad1b, vag1b,
                                Wg2a, as2a, ad2a, vag2a, Wg2b, as2b, ad2b, vag2b);
  cast_bf16_k<<<cdiv(N * 1024 / 4, 256), 256, 0, stream>>>(x, xb, N * 1024 / 4);
  zero_int_k<<<cdiv(4 * N, 256), 256, 0, stream>>>(deg4, 4 * N);
  hist4_k<<<cdiv(4 * E, 256), 256, 0, stream>>>(sadj, fadj, asadj, afadj, deg4, E, N);
  scan4_k<<<4, 1024, 0, stream>>>(deg4, rowptr4, cursor4, N);
  dinv2_k<<<cdiv(2 * N, 256), 256, 0, stream>>>(deg4, dinvS, dinvF, N);
  place4_k<<<cdiv(4 * E, 256), 256, 0, stream>>>(sadj, fadj, asadj, afadj, cursor4, col4, E, N);

  const int GW = cdiv(N, 4);  // wave-per-node grids
  auto gemmB = [&](const unsigned short* Ab, const unsigned short* Wt, int K, int F) {
    gemm_bf16_k<<<dim3(F / 128, cdiv(N, 128)), 256, 0, stream>>>(Ab, Wt, hb, N, K, F);
  };
  auto gcnA = [&](const unsigned short* inb, const unsigned short* Wt, const float* b,
                  const int* rowptr, const int* col, const float* dinv, int K, int F) {
    gemmB(inb, Wt, K, F);
    if (F == 512) gcn_gather_w_k<1, 0, 8><<<GW, 256, 0, stream>>>(hb, rowptr, col, dinv, b, ab, nullptr, N);
    else          gcn_gather_w_k<1, 0, 2><<<GW, 256, 0, stream>>>(hb, rowptr, col, dinv, b, ab, nullptr, N);
  };
  auto gcnAE = [&](const unsigned short* inb, const unsigned short* Wt, const float* b,
                   const int* rowptr, const int* col, const float* dinv,
                   unsigned short* Eb, int K, int F) {
    gemmB(inb, Wt, K, F);
    gcn_gather_w_k<1, 1, 4><<<GW, 256, 0, stream>>>(hb, rowptr, col, dinv, b, ab, Eb, N);
  };
  auto gcnE = [&](const unsigned short* inb, const unsigned short* Wt, const float* b,
                  const int* rowptr, const int* col, const float* dinv,
                  unsigned short* Eb, int K, int F) {
    gemmB(inb, Wt, K, F);
    gcn_gather_w_k<0, 1, 4><<<GW, 256, 0, stream>>>(hb, rowptr, col, dinv, b, nullptr, Eb, N);
  };
  auto gatA = [&](const unsigned short* Wt, const float* va, const float* b,
                  const int* rowptr, const int* col) {
    gemmB(ab, Wt, 256, 512);
    attn_dot_k<256, 4><<<GW, 256, 0, stream>>>(ab, va, asrcB, adstB, N);
    gat_fused_w_k<4, 128, 0><<<GW, 256, 0, stream>>>(hb, asrcB, adstB, rowptr, col, b, ab, N);
  };
  auto gatB = [&](const unsigned short* Wt, const float* va, const float* b,
                  const int* rowptr, const int* col) {
    gemmB(ab, Wt, 512, 256);
    attn_dot_k<512, 1><<<GW, 256, 0, stream>>>(ab, va, asrcB, adstB, N);
    gat_fused_w_k<1, 256, 1><<<GW, 256, 0, stream>>>(hb, asrcB, adstB, rowptr, col, b, ab, N);
  };

  // ---- path 1: x --GCN1--> E1 --GAT1--> emb2 --GCN3--> E3 ----
  gcnA(xb, Wt1a, b1a, rowptrS, colS, dinvS, 1024, 512);
  gcnAE(ab, Wt1b, b1b, rowptrS, colS, dinvS, E1bb, 512, 256);
  gatA(Wtg1a, vag1a, bg1a, rowptrA1, colA1);
  gatB(Wtg1b, vag1b, bg1b, rowptrA1, colA1);
  gcnA(ab, Wt3a, b3a, rowptrS, colS, dinvS, 256, 128);
  gcnE(ab, Wt3b, b3b, rowptrS, colS, dinvS, E3bb, 128, 256);

  // ---- path 2: x --GCN2--> E4 --GAT2--> emb5 --GCN4--> E6 ----
  gcnA(xb, Wt2a, b2a, rowptrF, colF, dinvF, 1024, 512);
  gcnAE(ab, Wt2b, b2b, rowptrF, colF, dinvF, E4bb, 512, 256);
  gatA(Wtg2a, vag2a, bg2a, rowptrA2, colA2);
  gatB(Wtg2b, vag2b, bg2b, rowptrA2, colA2);
  gcnA(ab, Wt4a, b4a, rowptrF, colF, dinvF, 256, 128);
  gcnE(ab, Wt4b, b4b, rowptrF, colF, dinvF, E6bb, 128, 256);

  // ---- fusion + MLP + log_softmax ----
  final3_k<<<cdiv(N, NPB), 256, 0, stream>>>(E1bb, E3bb, E4bb, E6bb,
                                             aw1, ab1, aw2, mw1, mb1, mw2, mb2,
                                             (float*)d_out, N);
}

// Round 12
// 1055.344 us; speedup vs baseline: 10.6565x; 1.0781x over previous
//
#include <hip/hip_runtime.h>
#include <cstddef>
#include <cstdint>
#include <cmath>

// ---------------------------------------------------------------------------
// HiGLDP forward, round 10b (resubmit): dual-path batched dispatches.
// ---------------------------------------------------------------------------

static inline int cdiv(int a, int b) { return (a + b - 1) / b; }

typedef __attribute__((ext_vector_type(8))) unsigned short ush8;
typedef __attribute__((ext_vector_type(4))) unsigned short ush4;
typedef __attribute__((ext_vector_type(2))) unsigned short ush2;
typedef __attribute__((ext_vector_type(8))) short bf16x8;
typedef __attribute__((ext_vector_type(4))) float f32x4;

__device__ __forceinline__ unsigned short f2bf(float f) {
  unsigned u = __float_as_uint(f);
  unsigned r = 0x7fffu + ((u >> 16) & 1u);
  return (unsigned short)((u + r) >> 16);
}
__device__ __forceinline__ float bf2f(unsigned short u) {
  return __uint_as_float((unsigned)u << 16);
}

// pointer-pair structs for dual-path batching
struct P2c { const unsigned short* p[2]; };
struct P2m { unsigned short* p[2]; };
struct F2c { const float* p[2]; };
struct F2m { float* p[2]; };
struct I2c { const int* p[2]; };

// ---------------- batched CSR build ----------------
__global__ void zero_int_k(int* __restrict__ p, int n) {
  int i = blockIdx.x * 256 + threadIdx.x;
  if (i < n) p[i] = 0;
}
__global__ void hist4_k(const int* __restrict__ e0, const int* __restrict__ e1,
                        const int* __restrict__ e2, const int* __restrict__ e3,
                        int* __restrict__ deg4, int E, int N) {
  int i = blockIdx.x * 256 + threadIdx.x;
  if (i >= 4 * E) return;
  const int* p; int e, off;
  if (i < E)          { p = e0; e = i;         off = 0; }
  else if (i < 2 * E) { p = e1; e = i - E;     off = N; }
  else if (i < 3 * E) { p = e2; e = i - 2 * E; off = 2 * N; }
  else                { p = e3; e = i - 3 * E; off = 3 * N; }
  atomicAdd(&deg4[off + p[E + e]], 1);
}
__global__ __launch_bounds__(1024) void scan4_k(const int* __restrict__ deg4,
                                                int* __restrict__ rowptr4,
                                                int* __restrict__ cursor4, int N) {
  __shared__ int part[1024];
  const int b = blockIdx.x;
  const int* deg = deg4 + (size_t)b * N;
  int* rowptr = rowptr4 + (size_t)b * (N + 1);
  int* cursor = cursor4 + (size_t)b * N;
  const int t = threadIdx.x;
  const int CH = (N + 1023) / 1024;
  const int base = t * CH;
  int loc = 0;
  for (int i = 0; i < CH; ++i)
    if (base + i < N) loc += deg[base + i];
  part[t] = loc;
  __syncthreads();
  for (int off = 1; off < 1024; off <<= 1) {
    int v = (t >= off) ? part[t - off] : 0;
    __syncthreads();
    part[t] += v;
    __syncthreads();
  }
  int run = (t > 0) ? part[t - 1] : 0;
  for (int i = 0; i < CH; ++i)
    if (base + i < N) {
      rowptr[base + i] = run;
      cursor[base + i] = run;
      run += deg[base + i];
    }
  if (t == 1023) rowptr[N] = part[1023];
}
__global__ void place4_k(const int* __restrict__ e0, const int* __restrict__ e1,
                         const int* __restrict__ e2, const int* __restrict__ e3,
                         int* __restrict__ cursor4, int* __restrict__ col4,
                         int E, int N) {
  int i = blockIdx.x * 256 + threadIdx.x;
  if (i >= 4 * E) return;
  const int* p; int e, w;
  if (i < E)          { p = e0; e = i;         w = 0; }
  else if (i < 2 * E) { p = e1; e = i - E;     w = 1; }
  else if (i < 3 * E) { p = e2; e = i - 2 * E; w = 2; }
  else                { p = e3; e = i - 3 * E; w = 3; }
  int pos = atomicAdd(&cursor4[(size_t)w * N + p[E + e]], 1);
  col4[(size_t)w * E + pos] = p[e];
}
__global__ void dinv2_k(const int* __restrict__ deg4, float* __restrict__ dinvS,
                        float* __restrict__ dinvF, int N) {
  int i = blockIdx.x * 256 + threadIdx.x;
  if (i < N) dinvS[i] = rsqrtf((float)deg4[i] + 1.f);
  else if (i < 2 * N) dinvF[i - N] = rsqrtf((float)deg4[i] + 1.f);
}

// ---------------- casts ----------------
__global__ void cast_bf16_k(const float* __restrict__ in, unsigned short* __restrict__ out,
                            int n4) {
  int i = blockIdx.x * 256 + threadIdx.x;
  if (i >= n4) return;
  float4 v = reinterpret_cast<const float4*>(in)[i];
  ush4 o;
  o.x = f2bf(v.x); o.y = f2bf(v.y); o.z = f2bf(v.z); o.w = f2bf(v.w);
  reinterpret_cast<ush4*>(out)[i] = o;
}

struct TcJobs {
  const float* src[12];
  unsigned short* dst[12];
  int K[12];
  int F[12];
  int start[13];
};
__global__ __launch_bounds__(256) void tc_batch_k(TcJobs j) {
  __shared__ float t[32][33];
  int flat = blockIdx.x;
  int job = 0;
  while (flat >= j.start[job + 1]) ++job;
  int local = flat - j.start[job];
  const float* W = j.src[job];
  unsigned short* Wt = j.dst[job];
  int K = j.K[job], F = j.F[job];
  int tilesX = K >> 5;
  int bk = (local % tilesX) * 32, bf = (local / tilesX) * 32;
  int tx = threadIdx.x & 31, ty = threadIdx.x >> 5;
  for (int i = ty; i < 32; i += 8) t[i][tx] = W[(size_t)(bk + i) * F + bf + tx];
  __syncthreads();
  for (int i = ty; i < 32; i += 8)
    Wt[(size_t)(bf + i) * K + bk + tx] = f2bf(t[tx][i]);
}

__device__ __forceinline__ void va_one(const float* __restrict__ W,
                                       const float* __restrict__ a_s,
                                       const float* __restrict__ a_d,
                                       float* __restrict__ va,
                                       int H, int C, int idx) {
  int k = idx / (2 * H), o = idx - k * 2 * H;
  int hh = (o >= H) ? (o - H) : o;
  const float* a = (o >= H) ? a_d : a_s;
  float s = 0.f;
  for (int c = 0; c < C; ++c) s += W[(size_t)k * (H * C) + hh * C + c] * a[hh * C + c];
  va[k * 2 * H + o] = s;
}
__global__ void va4_k(const float* W0, const float* s0, const float* d0, float* v0,
                      const float* W1, const float* s1, const float* d1, float* v1,
                      const float* W2, const float* s2, const float* d2, float* v2,
                      const float* W3, const float* s3, const float* d3, float* v3) {
  int i = blockIdx.x * 256 + threadIdx.x;
  if (i < 2048)      va_one(W0, s0, d0, v0, 4, 128, i);
  else if (i < 3072) va_one(W1, s1, d1, v1, 1, 256, i - 2048);
  else if (i < 5120) va_one(W2, s2, d2, v2, 4, 128, i - 3072);
  else if (i < 6144) va_one(W3, s3, d3, v3, 1, 256, i - 5120);
}

// ---------------- bf16 MFMA GEMM, dual-path via blockIdx.z ----------------
#define LDT 40
__global__ __launch_bounds__(256) void gemm_bf16_k(
    P2c A, P2c Bt, P2m Cb, int M, int K, int F) {
  __shared__ unsigned short Asl[128 * LDT];
  __shared__ unsigned short Bsl[128 * LDT];
  const int z = blockIdx.z;
  const unsigned short* __restrict__ Ap = A.p[z];
  const unsigned short* __restrict__ Bp = Bt.p[z];
  unsigned short* __restrict__ Cp = Cb.p[z];
  const int tid = threadIdx.x;
  const int wid = tid >> 6, lane = tid & 63;
  const int wr = (wid >> 1) * 64, wc = (wid & 1) * 64;
  const int bm = blockIdx.y * 128, bn = blockIdx.x * 128;
  const int l15 = lane & 15, lk = lane >> 4;
  f32x4 acc[4][4] = {};
  for (int k0 = 0; k0 < K; k0 += 32) {
    __syncthreads();
#pragma unroll
    for (int i = 0; i < 2; ++i) {
      int c = tid + i * 256;
      int r = c >> 2;
      int off = (c & 3) << 3;
      int gr = bm + r;
      ush8 av = {};
      if (gr < M) av = *reinterpret_cast<const ush8*>(Ap + (size_t)gr * K + k0 + off);
      *reinterpret_cast<ush8*>(&Asl[r * LDT + off]) = av;
      ush8 bv = *reinterpret_cast<const ush8*>(Bp + (size_t)(bn + r) * K + k0 + off);
      *reinterpret_cast<ush8*>(&Bsl[r * LDT + off]) = bv;
    }
    __syncthreads();
    bf16x8 af[4], bfv[4];
#pragma unroll
    for (int mi = 0; mi < 4; ++mi)
      af[mi] = *reinterpret_cast<const bf16x8*>(&Asl[(wr + mi * 16 + l15) * LDT + (lk << 3)]);
#pragma unroll
    for (int ni = 0; ni < 4; ++ni)
      bfv[ni] = *reinterpret_cast<const bf16x8*>(&Bsl[(wc + ni * 16 + l15) * LDT + (lk << 3)]);
#pragma unroll
    for (int mi = 0; mi < 4; ++mi)
#pragma unroll
      for (int ni = 0; ni < 4; ++ni)
        acc[mi][ni] = __builtin_amdgcn_mfma_f32_16x16x32_bf16(af[mi], bfv[ni], acc[mi][ni], 0, 0, 0);
  }
#pragma unroll
  for (int mi = 0; mi < 4; ++mi) {
    int gr0 = bm + wr + mi * 16 + (lk << 2);
#pragma unroll
    for (int ni = 0; ni < 4; ++ni) {
      int gc = bn + wc + ni * 16 + l15;
#pragma unroll
      for (int r4 = 0; r4 < 4; ++r4) {
        int gr = gr0 + r4;
        if (gr < M) Cp[(size_t)gr * F + gc] = f2bf(acc[mi][ni][r4]);
      }
    }
  }
}

// ---------------- vector bf16 row helpers ----------------
template <int EPL>
__device__ __forceinline__ void load_row(const unsigned short* __restrict__ p,
                                         float* __restrict__ v) {
  if (EPL == 8) {
    ush8 t = *reinterpret_cast<const ush8*>(p);
#pragma unroll
    for (int i = 0; i < 8; ++i) v[i] = bf2f(t[i]);
  } else if (EPL == 4) {
    ush4 t = *reinterpret_cast<const ush4*>(p);
    v[0] = bf2f(t.x); v[1] = bf2f(t.y); v[2] = bf2f(t.z); v[3] = bf2f(t.w);
  } else {
    ush2 t = *reinterpret_cast<const ush2*>(p);
    v[0] = bf2f(t.x); v[1] = bf2f(t.y);
  }
}
template <int EPL>
__device__ __forceinline__ void store_row(unsigned short* __restrict__ p,
                                          const float* __restrict__ v) {
  if (EPL == 8) {
    ush8 t;
#pragma unroll
    for (int i = 0; i < 8; ++i) t[i] = f2bf(v[i]);
    *reinterpret_cast<ush8*>(p) = t;
  } else if (EPL == 4) {
    ush4 t;
    t.x = f2bf(v[0]); t.y = f2bf(v[1]); t.z = f2bf(v[2]); t.w = f2bf(v[3]);
    *reinterpret_cast<ush4*>(p) = t;
  } else {
    ush2 t;
    t.x = f2bf(v[0]); t.y = f2bf(v[1]);
    *reinterpret_cast<ush2*>(p) = t;
  }
}

// ---------------- GCN gather: wave per node, dual-path over 2N -------------
template <int WA, int WE, int EPL>
__global__ __launch_bounds__(256) void gcn_gather_w_k(
    P2c h, I2c rowptr, I2c col, F2c dinv, F2c bias, P2m outa, P2m oute, int N) {
  constexpr int F = EPL * 64;
  const int gid = blockIdx.x * 4 + (threadIdx.x >> 6);
  const int lane = threadIdx.x & 63;
  if (gid >= 2 * N) return;
  const int pa = gid >= N;
  const int node = gid - pa * N;
  const unsigned short* __restrict__ hp = h.p[pa];
  const int* __restrict__ rp = rowptr.p[pa];
  const int* __restrict__ cp = col.p[pa];
  const float* __restrict__ dv = dinv.p[pa];
  const float* __restrict__ bp = bias.p[pa];
  const int beg = rp[node], end = rp[node + 1];
  const float di = dv[node];
  const int f0 = lane * EPL;
  float acc[EPL], row[EPL];
  load_row<EPL>(hp + (size_t)node * F + f0, row);
  {
    float w = di * di;
#pragma unroll
    for (int i = 0; i < EPL; ++i) acc[i] = row[i] * w;
  }
  for (int p = beg; p < end; ++p) {
    int s = cp[p];
    float w = dv[s] * di;
    load_row<EPL>(hp + (size_t)s * F + f0, row);
#pragma unroll
    for (int i = 0; i < EPL; ++i) acc[i] += row[i] * w;
  }
#pragma unroll
  for (int i = 0; i < EPL; ++i) acc[i] = fmaxf(acc[i] + bp[f0 + i], 0.f);
  if (WA) store_row<EPL>(outa.p[pa] + (size_t)node * F + f0, acc);
  if (WE) store_row<EPL>(oute.p[pa] + (size_t)node * F + f0, acc);
}

// ---------------- GAT logits, dual-path ----------------
template <int K, int H>
__global__ __launch_bounds__(256) void attn_dot_k(
    P2c in, F2c va, F2m asrc, F2m adst, int N) {
  constexpr int EPL = K / 64;
  const int gid = blockIdx.x * 4 + (threadIdx.x >> 6);
  const int lane = threadIdx.x & 63;
  if (gid >= 2 * N) return;
  const int pa = gid >= N;
  const int n = gid - pa * N;
  float acc[2 * H] = {};
  float xv[EPL];
  load_row<EPL>(in.p[pa] + (size_t)n * K + lane * EPL, xv);
  const float* __restrict__ vap = va.p[pa];
#pragma unroll
  for (int j = 0; j < EPL; ++j) {
    const float* vp = vap + (size_t)(lane * EPL + j) * 2 * H;
#pragma unroll
    for (int o = 0; o < 2 * H; ++o) acc[o] += xv[j] * vp[o];
  }
#pragma unroll
  for (int off = 32; off >= 1; off >>= 1)
#pragma unroll
    for (int o = 0; o < 2 * H; ++o) acc[o] += __shfl_xor(acc[o], off);
  if (lane == 0) {
#pragma unroll
    for (int hh = 0; hh < H; ++hh) {
      asrc.p[pa][n * H + hh] = acc[hh];
      adst.p[pa][n * H + hh] = acc[H + hh];
    }
  }
}

// ---------------- GAT fused, dual-path, wave per node ----------------
template <int H, int C, int EPI>
__global__ __launch_bounds__(256) void gat_fused_w_k(
    P2c h, F2c asrc, F2c adst, I2c rowptr, I2c col, F2c bias, P2m out, int N) {
  constexpr int F = H * C;
  constexpr int EPL = F / 64;
  const int gid = blockIdx.x * 4 + (threadIdx.x >> 6);
  const int lane = threadIdx.x & 63;
  if (gid >= 2 * N) return;
  const int pa = gid >= N;
  const int node = gid - pa * N;
  const unsigned short* __restrict__ hp = h.p[pa];
  const float* __restrict__ asp = asrc.p[pa];
  const float* __restrict__ adp = adst.p[pa];
  const int* __restrict__ rp = rowptr.p[pa];
  const int* __restrict__ cp = col.p[pa];
  const float* __restrict__ bp = bias.p[pa];
  const int beg = rp[node], end = rp[node + 1];

  float ad[H], vself[H];
#pragma unroll
  for (int k = 0; k < H; ++k) {
    ad[k] = adp[node * H + k];
    float v = asp[node * H + k] + ad[k];
    vself[k] = v > 0.f ? v : 0.2f * v;
  }
  float m[H];
#pragma unroll
  for (int k = 0; k < H; ++k) m[k] = vself[k];
  for (int p = beg + lane; p < end; p += 64) {
    int s = cp[p];
#pragma unroll
    for (int k = 0; k < H; ++k) {
      float v = asp[s * H + k] + ad[k];
      v = v > 0.f ? v : 0.2f * v;
      m[k] = fmaxf(m[k], v);
    }
  }
#pragma unroll
  for (int off = 32; off >= 1; off >>= 1)
#pragma unroll
    for (int k = 0; k < H; ++k) m[k] = fmaxf(m[k], __shfl_xor(m[k], off));
  float dn[H] = {};
  for (int p = beg + lane; p < end; p += 64) {
    int s = cp[p];
#pragma unroll
    for (int k = 0; k < H; ++k) {
      float v = asp[s * H + k] + ad[k];
      v = v > 0.f ? v : 0.2f * v;
      dn[k] += __expf(v - m[k]);
    }
  }
#pragma unroll
  for (int off = 32; off >= 1; off >>= 1)
#pragma unroll
    for (int k = 0; k < H; ++k) dn[k] += __shfl_xor(dn[k], off);
  float invD[H];
#pragma unroll
  for (int k = 0; k < H; ++k)
    invD[k] = 1.f / (dn[k] + __expf(vself[k] - m[k]) + 1e-16f);
  const int f0 = lane * EPL;
  const int k0 = f0 / C;
  float acc[EPL], row[EPL];
  load_row<EPL>(hp + (size_t)node * F + f0, row);
  {
    float aself = __expf(vself[k0] - m[k0]) * invD[k0];
#pragma unroll
    for (int i = 0; i < EPL; ++i) acc[i] = aself * row[i];
  }
  for (int p = beg; p < end; ++p) {
    int s = cp[p];
    float v = asp[s * H + k0] + ad[k0];
    v = v > 0.f ? v : 0.2f * v;
    float a = __expf(v - m[k0]) * invD[k0];
    load_row<EPL>(hp + (size_t)s * F + f0, row);
#pragma unroll
    for (int i = 0; i < EPL; ++i) acc[i] += a * row[i];
  }
  if (EPI == 0) {
#pragma unroll
    for (int i = 0; i < EPL; ++i) {
      float v = acc[i] + bp[f0 + i];
      acc[i] = v > 0.f ? v : (__expf(v) - 1.f);
    }
    store_row<EPL>(out.p[pa] + (size_t)node * F + f0, acc);
  } else {
#pragma unroll
    for (int i = 0; i < EPL; ++i) acc[i] += bp[f0 + i];
    float r = acc[0];
#pragma unroll
    for (int i = 1; i < EPL; ++i) r = fmaxf(r, acc[i]);
#pragma unroll
    for (int off = 32; off >= 1; off >>= 1) r = fmaxf(r, __shfl_xor(r, off));
    float se = 0.f;
#pragma unroll
    for (int i = 0; i < EPL; ++i) se += __expf(acc[i] - r);
#pragma unroll
    for (int off = 32; off >= 1; off >>= 1) se += __shfl_xor(se, off);
    float ls = logf(se);
#pragma unroll
    for (int i = 0; i < EPL; ++i) acc[i] = fmaxf(acc[i] - r - ls, 0.f);
    store_row<EPL>(out.p[pa] + (size_t)node * F + f0, acc);
  }
}

// ---------------- final fusion + MLP + log_softmax (bf16 z, 8 nodes/block) --
#define NPB 8
__global__ __launch_bounds__(256) void final3_k(
    const unsigned short* __restrict__ E1, const unsigned short* __restrict__ E3,
    const unsigned short* __restrict__ E4, const unsigned short* __restrict__ E6,
    const float* __restrict__ aw1, const float* __restrict__ ab1,
    const float* __restrict__ aw2, const float* __restrict__ mw1,
    const float* __restrict__ mb1, const float* __restrict__ mw2,
    const float* __restrict__ mb2, float* __restrict__ out, int N) {
  __shared__ unsigned short zsh[NPB][2][512];
  __shared__ float psh[NPB][256];
  __shared__ float wsh[NPB * 2][17];
  __shared__ float warr[NPB][2];
  __shared__ float bsh[NPB][2];
  __shared__ float hsh[NPB][64];
  __shared__ float o7sh[NPB][8];
  const int t = threadIdx.x;
  const int n0 = blockIdx.x * NPB;
  {
    int seg = t >> 6, idx = t & 63;
    const unsigned short* sp = (seg == 0) ? E1 : (seg == 1) ? E3 : (seg == 2) ? E4 : E6;
    int r = seg >> 1, half = seg & 1;
    for (int nd = 0; nd < NPB; ++nd) {
      if (n0 + nd < N) {
        ush4 v = reinterpret_cast<const ush4*>(sp)[(size_t)(n0 + nd) * 64 + idx];
        reinterpret_cast<ush4*>(&zsh[nd][r][half * 256])[idx] = v;
      }
    }
  }
  __syncthreads();
  {
    int row = t >> 4, j = t & 15;
    int nd = row >> 1, r = row & 1;
    const ush2* zp = reinterpret_cast<const ush2*>(zsh[nd][r]);
    float a0 = ab1[j], a1 = 0.f;
    for (int c2 = 0; c2 < 256; ++c2) {
      ush2 v = zp[c2];
      a0 += bf2f(v.x) * aw1[(2 * c2) * 16 + j];
      a1 += bf2f(v.y) * aw1[(2 * c2 + 1) * 16 + j];
    }
    wsh[row][j] = tanhf(a0 + a1) * aw2[j];
  }
  __syncthreads();
  if (t < 16) {
    float s = 0.f;
    for (int j = 0; j < 16; ++j) s += wsh[t][j];
    warr[t >> 1][t & 1] = s;
  }
  __syncthreads();
  if (t < NPB) {
    float w0 = warr[t][0], w1 = warr[t][1];
    float mxv = fmaxf(w0, w1);
    float e0 = __expf(w0 - mxv), e1 = __expf(w1 - mxv);
    float inv = 1.f / (e0 + e1);
    bsh[t][0] = e0 * inv; bsh[t][1] = e1 * inv;
  }
  __syncthreads();
  {
    int nd = t >> 5, l = t & 31;
    float b0 = bsh[nd][0], b1 = bsh[nd][1];
    ush2* z0 = reinterpret_cast<ush2*>(zsh[nd][0]);
    const ush2* z1 = reinterpret_cast<const ush2*>(zsh[nd][1]);
    for (int i = 0; i < 8; ++i) {
      int c2 = l + 32 * i;
      ush2 a = z0[c2], b = z1[c2];
      ush2 o;
      o.x = f2bf(b0 * bf2f(a.x) + b1 * bf2f(b.x));
      o.y = f2bf(b0 * bf2f(a.y) + b1 * bf2f(b.y));
      z0[c2] = o;
    }
  }
  __syncthreads();
  {
    int o = t & 63, ch = t >> 6;
    float accv[NPB];
#pragma unroll
    for (int nd = 0; nd < NPB; ++nd) accv[nd] = 0.f;
    for (int c2 = ch * 64; c2 < ch * 64 + 64; ++c2) {
      float w0 = mw1[(2 * c2) * 64 + o];
      float w1 = mw1[(2 * c2 + 1) * 64 + o];
#pragma unroll
      for (int nd = 0; nd < NPB; ++nd) {
        ush2 v = reinterpret_cast<const ush2*>(zsh[nd][0])[c2];
        accv[nd] += bf2f(v.x) * w0 + bf2f(v.y) * w1;
      }
    }
#pragma unroll
    for (int nd = 0; nd < NPB; ++nd) psh[nd][ch * 64 + o] = accv[nd];
  }
  __syncthreads();
  {
    int nd = t >> 5, oo = t & 31;
#pragma unroll
    for (int i = 0; i < 2; ++i) {
      int o = oo + i * 32;
      float s = mb1[o] + psh[nd][o] + psh[nd][64 + o] +
                psh[nd][128 + o] + psh[nd][192 + o];
      hsh[nd][o] = tanhf(s);
    }
  }
  __syncthreads();
  if (t < NPB * 7) {
    int nd = t / 7, jo = t - nd * 7;
    float a = mb2[jo];
    for (int j = 0; j < 64; ++j) a += hsh[nd][j] * mw2[j * 7 + jo];
    o7sh[nd][jo] = a;
  }
  __syncthreads();
  if (t < NPB && n0 + t < N) {
    float m = o7sh[t][0];
    for (int k = 1; k < 7; ++k) m = fmaxf(m, o7sh[t][k]);
    float s = 0.f;
    for (int k = 0; k < 7; ++k) s += expf(o7sh[t][k] - m);
    float ls = logf(s);
    for (int k = 0; k < 7; ++k) out[(size_t)(n0 + t) * 7 + k] = o7sh[t][k] - m - ls;
  }
}

// ---------------------------------------------------------------------------
extern "C" void kernel_launch(void* const* d_in, const int* in_sizes, int n_in,
                              void* d_out, int out_size, void* d_ws, size_t ws_size,
                              hipStream_t stream) {
  (void)n_in; (void)out_size; (void)ws_size;
  const float* x     = (const float*)d_in[0];
  const int*   sadj  = (const int*)d_in[1];
  const int*   fadj  = (const int*)d_in[2];
  const int*   asadj = (const int*)d_in[3];
  const int*   afadj = (const int*)d_in[4];
  const float* W1a = (const float*)d_in[5];  const float* b1a = (const float*)d_in[6];
  const float* W1b = (const float*)d_in[7];  const float* b1b = (const float*)d_in[8];
  const float* W2a = (const float*)d_in[9];  const float* b2a = (const float*)d_in[10];
  const float* W2b = (const float*)d_in[11]; const float* b2b = (const float*)d_in[12];
  const float* W3a = (const float*)d_in[13]; const float* b3a = (const float*)d_in[14];
  const float* W3b = (const float*)d_in[15]; const float* b3b = (const float*)d_in[16];
  const float* W4a = (const float*)d_in[17]; const float* b4a = (const float*)d_in[18];
  const float* W4b = (const float*)d_in[19]; const float* b4b = (const float*)d_in[20];
  const float* Wg1a = (const float*)d_in[21]; const float* as1a = (const float*)d_in[22];
  const float* ad1a = (const float*)d_in[23]; const float* bg1a = (const float*)d_in[24];
  const float* Wg1b = (const float*)d_in[25]; const float* as1b = (const float*)d_in[26];
  const float* ad1b = (const float*)d_in[27]; const float* bg1b = (const float*)d_in[28];
  const float* Wg2a = (const float*)d_in[29]; const float* as2a = (const float*)d_in[30];
  const float* ad2a = (const float*)d_in[31]; const float* bg2a = (const float*)d_in[32];
  const float* Wg2b = (const float*)d_in[33]; const float* as2b = (const float*)d_in[34];
  const float* ad2b = (const float*)d_in[35]; const float* bg2b = (const float*)d_in[36];
  const float* aw1 = (const float*)d_in[37]; const float* ab1 = (const float*)d_in[38];
  const float* aw2 = (const float*)d_in[39];
  const float* mw1 = (const float*)d_in[40]; const float* mb1 = (const float*)d_in[41];
  const float* mw2 = (const float*)d_in[42]; const float* mb2 = (const float*)d_in[43];

  const int N = in_sizes[0] / 1024;   // 20000
  const int E = in_sizes[1] / 2;      // 160000

  // ---- workspace layout ----
  float* ws = (float*)d_ws;
  float* bufA  = ws;                          // N*512 floats; hb1/hb2 alias it
  float* vaT   = bufA + (size_t)N * 512;      // 8192 floats
  float* dinvS = vaT + 8192;                  // N
  float* dinvF = dinvS + N;                   // N
  float* asrc1 = dinvF + N;                   // N*4
  float* adst1 = asrc1 + (size_t)N * 4;       // N*4
  float* asrc2 = adst1 + (size_t)N * 4;       // N*4
  float* adst2 = asrc2 + (size_t)N * 4;       // N*4
  int* ib = (int*)(adst2 + (size_t)N * 4);
  int* rowptr4 = ib;            ib += 4 * (N + 1);
  int* col4    = ib;            ib += 4 * E;
  int* deg4    = ib;            ib += 4 * N;
  int* cursor4 = ib;            ib += 4 * N;
  unsigned short* ub = (unsigned short*)(ib + ((size_t)(-(intptr_t)ib) & 3));
  unsigned short* xb = ub;            ub += (size_t)N * 1024;
  unsigned short* actb1 = ub;         ub += (size_t)N * 512;
  unsigned short* actb2 = ub;         ub += (size_t)N * 512;
  unsigned short* E1bb = ub;          ub += (size_t)N * 256;
  unsigned short* E3bb = ub;          ub += (size_t)N * 256;
  unsigned short* E4bb = ub;          ub += (size_t)N * 256;
  unsigned short* E6bb = ub;          ub += (size_t)N * 256;
  unsigned short* Wt1a = ub;  ub += 1024 * 512;
  unsigned short* Wt1b = ub;  ub += 512 * 256;
  unsigned short* Wt2a = ub;  ub += 1024 * 512;
  unsigned short* Wt2b = ub;  ub += 512 * 256;
  unsigned short* Wt3a = ub;  ub += 256 * 128;
  unsigned short* Wt3b = ub;  ub += 128 * 256;
  unsigned short* Wt4a = ub;  ub += 256 * 128;
  unsigned short* Wt4b = ub;  ub += 128 * 256;
  unsigned short* Wtg1a = ub; ub += 256 * 512;
  unsigned short* Wtg1b = ub; ub += 512 * 256;
  unsigned short* Wtg2a = ub; ub += 256 * 512;
  unsigned short* Wtg2b = ub; ub += 512 * 256;
  unsigned short* hb1 = (unsigned short*)bufA;          // N*512 bf16
  unsigned short* hb2 = hb1 + (size_t)N * 512;          // N*512 bf16
  float* vag1a = vaT;
  float* vag1b = vaT + 2048;
  float* vag2a = vaT + 3072;
  float* vag2b = vaT + 5120;
  int* rowptrS = rowptr4;
  int* rowptrF = rowptr4 + (N + 1);
  int* rowptrA1 = rowptr4 + 2 * (N + 1);
  int* rowptrA2 = rowptr4 + 3 * (N + 1);
  int* colS = col4;
  int* colF = col4 + E;
  int* colA1 = col4 + 2 * E;
  int* colA2 = col4 + 3 * E;

  // ---- batched setup ----
  {
    TcJobs j;
    const float* srcs[12] = {W1a, W1b, W2a, W2b, W3a, W3b, W4a, W4b, Wg1a, Wg1b, Wg2a, Wg2b};
    unsigned short* dsts[12] = {Wt1a, Wt1b, Wt2a, Wt2b, Wt3a, Wt3b, Wt4a, Wt4b,
                                Wtg1a, Wtg1b, Wtg2a, Wtg2b};
    int Ks[12] = {1024, 512, 1024, 512, 256, 128, 256, 128, 256, 512, 256, 512};
    int Fs[12] = {512, 256, 512, 256, 128, 256, 128, 256, 512, 256, 512, 256};
    int acc = 0;
    for (int i = 0; i < 12; ++i) {
      j.src[i] = srcs[i]; j.dst[i] = dsts[i]; j.K[i] = Ks[i]; j.F[i] = Fs[i];
      j.start[i] = acc;
      acc += (Ks[i] / 32) * (Fs[i] / 32);
    }
    j.start[12] = acc;
    tc_batch_k<<<acc, 256, 0, stream>>>(j);
  }
  va4_k<<<24, 256, 0, stream>>>(Wg1a, as1a, ad1a, vag1a, Wg1b, as1b, ad1b, vag1b,
                                Wg2a, as2a, ad2a, vag2a, Wg2b, as2b, ad2b, vag2b);
  cast_bf16_k<<<cdiv(N * 1024 / 4, 256), 256, 0, stream>>>(x, xb, N * 1024 / 4);
  zero_int_k<<<cdiv(4 * N, 256), 256, 0, stream>>>(deg4, 4 * N);
  hist4_k<<<cdiv(4 * E, 256), 256, 0, stream>>>(sadj, fadj, asadj, afadj, deg4, E, N);
  scan4_k<<<4, 1024, 0, stream>>>(deg4, rowptr4, cursor4, N);
  dinv2_k<<<cdiv(2 * N, 256), 256, 0, stream>>>(deg4, dinvS, dinvF, N);
  place4_k<<<cdiv(4 * E, 256), 256, 0, stream>>>(sadj, fadj, asadj, afadj, cursor4, col4, E, N);

  // ---- dual-path batched pipeline ----
  const int GW2 = cdiv(2 * N, 4);
  P2c Hh = {{hb1, hb2}};
  P2m Hm = {{hb1, hb2}};
  P2c Aa = {{actb1, actb2}};
  P2m Am = {{actb1, actb2}};
  I2c RG = {{rowptrS, rowptrF}}, CG = {{colS, colF}};
  I2c RA = {{rowptrA1, rowptrA2}}, CA = {{colA1, colA2}};
  F2c DV = {{dinvS, dinvF}};
  F2c AS = {{asrc1, asrc2}}, AD = {{adst1, adst2}};
  F2m ASm = {{asrc1, asrc2}}, ADm = {{adst1, adst2}};

  auto gemm2 = [&](P2c A, P2c Bt, int K, int F) {
    gemm_bf16_k<<<dim3(F / 128, cdiv(N, 128), 2), 256, 0, stream>>>(A, Bt, Hm, N, K, F);
  };

  // stage 1: x @ W1a / W2a  (1024->512)
  gemm2({{xb, xb}}, {{Wt1a, Wt2a}}, 1024, 512);
  gcn_gather_w_k<1, 0, 8><<<GW2, 256, 0, stream>>>(Hh, RG, CG, DV, {{b1a, b2a}}, Am, {{nullptr, nullptr}}, N);
  // stage 2: 512->256, write act + E1/E4
  gemm2(Aa, {{Wt1b, Wt2b}}, 512, 256);
  gcn_gather_w_k<1, 1, 4><<<GW2, 256, 0, stream>>>(Hh, RG, CG, DV, {{b1b, b2b}}, Am, {{E1bb, E4bb}}, N);
  // stage 3: GAT layer 1 (256->512, 4 heads)
  gemm2(Aa, {{Wtg1a, Wtg2a}}, 256, 512);
  attn_dot_k<256, 4><<<GW2, 256, 0, stream>>>(Aa, {{vag1a, vag2a}}, ASm, ADm, N);
  gat_fused_w_k<4, 128, 0><<<GW2, 256, 0, stream>>>(Hh, AS, AD, RA, CA, {{bg1a, bg2a}}, Am, N);
  // stage 4: GAT layer 2 (512->256, 1 head, log_softmax+relu)
  gemm2(Aa, {{Wtg1b, Wtg2b}}, 512, 256);
  attn_dot_k<512, 1><<<GW2, 256, 0, stream>>>(Aa, {{vag1b, vag2b}}, ASm, ADm, N);
  gat_fused_w_k<1, 256, 1><<<GW2, 256, 0, stream>>>(Hh, AS, AD, RA, CA, {{bg1b, bg2b}}, Am, N);
  // stage 5: 256->128
  gemm2(Aa, {{Wt3a, Wt4a}}, 256, 128);
  gcn_gather_w_k<1, 0, 2><<<GW2, 256, 0, stream>>>(Hh, RG, CG, DV, {{b3a, b4a}}, Am, {{nullptr, nullptr}}, N);
  // stage 6: 128->256, write E3/E6
  gemm2(Aa, {{Wt3b, Wt4b}}, 128, 256);
  gcn_gather_w_k<0, 1, 4><<<GW2, 256, 0, stream>>>(Hh, RG, CG, DV, {{b3b, b4b}}, Am, {{E3bb, E6bb}}, N);

  // ---- fusion + MLP + log_softmax ----
  final3_k<<<cdiv(N, NPB), 256, 0, stream>>>(E1bb, E3bb, E4bb, E6bb,
                                             aw1, ab1, aw2, mw1, mb1, mw2, mb2,
                                             (float*)d_out, N);
}

// Round 13
// 1027.099 us; speedup vs baseline: 10.9495x; 1.0275x over previous
//
#include <hip/hip_runtime.h>
#include <cstddef>
#include <cstdint>
#include <cmath>

// ---------------------------------------------------------------------------
// HiGLDP forward, round 13: + XCD-aware bijective block swizzle on the GEMM
// (same-A-panel blocks co-located per XCD L2). Rest identical to round 10b.
// ---------------------------------------------------------------------------

static inline int cdiv(int a, int b) { return (a + b - 1) / b; }

typedef __attribute__((ext_vector_type(8))) unsigned short ush8;
typedef __attribute__((ext_vector_type(4))) unsigned short ush4;
typedef __attribute__((ext_vector_type(2))) unsigned short ush2;
typedef __attribute__((ext_vector_type(8))) short bf16x8;
typedef __attribute__((ext_vector_type(4))) float f32x4;

__device__ __forceinline__ unsigned short f2bf(float f) {
  unsigned u = __float_as_uint(f);
  unsigned r = 0x7fffu + ((u >> 16) & 1u);
  return (unsigned short)((u + r) >> 16);
}
__device__ __forceinline__ float bf2f(unsigned short u) {
  return __uint_as_float((unsigned)u << 16);
}

// pointer-pair structs for dual-path batching
struct P2c { const unsigned short* p[2]; };
struct P2m { unsigned short* p[2]; };
struct F2c { const float* p[2]; };
struct F2m { float* p[2]; };
struct I2c { const int* p[2]; };

// ---------------- batched CSR build ----------------
__global__ void zero_int_k(int* __restrict__ p, int n) {
  int i = blockIdx.x * 256 + threadIdx.x;
  if (i < n) p[i] = 0;
}
__global__ void hist4_k(const int* __restrict__ e0, const int* __restrict__ e1,
                        const int* __restrict__ e2, const int* __restrict__ e3,
                        int* __restrict__ deg4, int E, int N) {
  int i = blockIdx.x * 256 + threadIdx.x;
  if (i >= 4 * E) return;
  const int* p; int e, off;
  if (i < E)          { p = e0; e = i;         off = 0; }
  else if (i < 2 * E) { p = e1; e = i - E;     off = N; }
  else if (i < 3 * E) { p = e2; e = i - 2 * E; off = 2 * N; }
  else                { p = e3; e = i - 3 * E; off = 3 * N; }
  atomicAdd(&deg4[off + p[E + e]], 1);
}
__global__ __launch_bounds__(1024) void scan4_k(const int* __restrict__ deg4,
                                                int* __restrict__ rowptr4,
                                                int* __restrict__ cursor4, int N) {
  __shared__ int part[1024];
  const int b = blockIdx.x;
  const int* deg = deg4 + (size_t)b * N;
  int* rowptr = rowptr4 + (size_t)b * (N + 1);
  int* cursor = cursor4 + (size_t)b * N;
  const int t = threadIdx.x;
  const int CH = (N + 1023) / 1024;
  const int base = t * CH;
  int loc = 0;
  for (int i = 0; i < CH; ++i)
    if (base + i < N) loc += deg[base + i];
  part[t] = loc;
  __syncthreads();
  for (int off = 1; off < 1024; off <<= 1) {
    int v = (t >= off) ? part[t - off] : 0;
    __syncthreads();
    part[t] += v;
    __syncthreads();
  }
  int run = (t > 0) ? part[t - 1] : 0;
  for (int i = 0; i < CH; ++i)
    if (base + i < N) {
      rowptr[base + i] = run;
      cursor[base + i] = run;
      run += deg[base + i];
    }
  if (t == 1023) rowptr[N] = part[1023];
}
__global__ void place4_k(const int* __restrict__ e0, const int* __restrict__ e1,
                         const int* __restrict__ e2, const int* __restrict__ e3,
                         int* __restrict__ cursor4, int* __restrict__ col4,
                         int E, int N) {
  int i = blockIdx.x * 256 + threadIdx.x;
  if (i >= 4 * E) return;
  const int* p; int e, w;
  if (i < E)          { p = e0; e = i;         w = 0; }
  else if (i < 2 * E) { p = e1; e = i - E;     w = 1; }
  else if (i < 3 * E) { p = e2; e = i - 2 * E; w = 2; }
  else                { p = e3; e = i - 3 * E; w = 3; }
  int pos = atomicAdd(&cursor4[(size_t)w * N + p[E + e]], 1);
  col4[(size_t)w * E + pos] = p[e];
}
__global__ void dinv2_k(const int* __restrict__ deg4, float* __restrict__ dinvS,
                        float* __restrict__ dinvF, int N) {
  int i = blockIdx.x * 256 + threadIdx.x;
  if (i < N) dinvS[i] = rsqrtf((float)deg4[i] + 1.f);
  else if (i < 2 * N) dinvF[i - N] = rsqrtf((float)deg4[i] + 1.f);
}

// ---------------- casts ----------------
__global__ void cast_bf16_k(const float* __restrict__ in, unsigned short* __restrict__ out,
                            int n4) {
  int i = blockIdx.x * 256 + threadIdx.x;
  if (i >= n4) return;
  float4 v = reinterpret_cast<const float4*>(in)[i];
  ush4 o;
  o.x = f2bf(v.x); o.y = f2bf(v.y); o.z = f2bf(v.z); o.w = f2bf(v.w);
  reinterpret_cast<ush4*>(out)[i] = o;
}

struct TcJobs {
  const float* src[12];
  unsigned short* dst[12];
  int K[12];
  int F[12];
  int start[13];
};
__global__ __launch_bounds__(256) void tc_batch_k(TcJobs j) {
  __shared__ float t[32][33];
  int flat = blockIdx.x;
  int job = 0;
  while (flat >= j.start[job + 1]) ++job;
  int local = flat - j.start[job];
  const float* W = j.src[job];
  unsigned short* Wt = j.dst[job];
  int K = j.K[job], F = j.F[job];
  int tilesX = K >> 5;
  int bk = (local % tilesX) * 32, bf = (local / tilesX) * 32;
  int tx = threadIdx.x & 31, ty = threadIdx.x >> 5;
  for (int i = ty; i < 32; i += 8) t[i][tx] = W[(size_t)(bk + i) * F + bf + tx];
  __syncthreads();
  for (int i = ty; i < 32; i += 8)
    Wt[(size_t)(bf + i) * K + bk + tx] = f2bf(t[tx][i]);
}

__device__ __forceinline__ void va_one(const float* __restrict__ W,
                                       const float* __restrict__ a_s,
                                       const float* __restrict__ a_d,
                                       float* __restrict__ va,
                                       int H, int C, int idx) {
  int k = idx / (2 * H), o = idx - k * 2 * H;
  int hh = (o >= H) ? (o - H) : o;
  const float* a = (o >= H) ? a_d : a_s;
  float s = 0.f;
  for (int c = 0; c < C; ++c) s += W[(size_t)k * (H * C) + hh * C + c] * a[hh * C + c];
  va[k * 2 * H + o] = s;
}
__global__ void va4_k(const float* W0, const float* s0, const float* d0, float* v0,
                      const float* W1, const float* s1, const float* d1, float* v1,
                      const float* W2, const float* s2, const float* d2, float* v2,
                      const float* W3, const float* s3, const float* d3, float* v3) {
  int i = blockIdx.x * 256 + threadIdx.x;
  if (i < 2048)      va_one(W0, s0, d0, v0, 4, 128, i);
  else if (i < 3072) va_one(W1, s1, d1, v1, 1, 256, i - 2048);
  else if (i < 5120) va_one(W2, s2, d2, v2, 4, 128, i - 3072);
  else if (i < 6144) va_one(W3, s3, d3, v3, 1, 256, i - 5120);
}

// ---------------- bf16 MFMA GEMM, dual-path + XCD swizzle ----------------
#define LDT 40
#define NXCD 8
__global__ __launch_bounds__(256) void gemm_bf16_k(
    P2c A, P2c Bt, P2m Cb, int M, int K, int F, int gx, int gy) {
  __shared__ unsigned short Asl[128 * LDT];
  __shared__ unsigned short Bsl[128 * LDT];
  // ---- XCD-aware bijective swizzle (m204): contiguous logical chunk / XCD.
  // HW round-robins consecutive orig ids across XCDs; remap so each XCD's
  // blocks form a contiguous run of (x-fastest) tiles -> same-A-panel blocks
  // (consecutive x at fixed y) share one XCD's L2.
  const int nwg = gx * gy * 2;
  const int orig = blockIdx.x + gx * (blockIdx.y + gy * blockIdx.z);
  const int xcd = orig & (NXCD - 1);
  const int q = nwg >> 3, r = nwg & (NXCD - 1);
  const int swz = (xcd < r ? xcd * (q + 1) : r * (q + 1) + (xcd - r) * q) + (orig >> 3);
  const int z = swz / (gx * gy);
  const int rem = swz - z * (gx * gy);
  const int bn = (rem % gx) * 128;
  const int bm = (rem / gx) * 128;
  const unsigned short* __restrict__ Ap = A.p[z];
  const unsigned short* __restrict__ Bp = Bt.p[z];
  unsigned short* __restrict__ Cp = Cb.p[z];
  const int tid = threadIdx.x;
  const int wid = tid >> 6, lane = tid & 63;
  const int wr = (wid >> 1) * 64, wc = (wid & 1) * 64;
  const int l15 = lane & 15, lk = lane >> 4;
  f32x4 acc[4][4] = {};
  for (int k0 = 0; k0 < K; k0 += 32) {
    __syncthreads();
#pragma unroll
    for (int i = 0; i < 2; ++i) {
      int c = tid + i * 256;
      int rr = c >> 2;
      int off = (c & 3) << 3;
      int gr = bm + rr;
      ush8 av = {};
      if (gr < M) av = *reinterpret_cast<const ush8*>(Ap + (size_t)gr * K + k0 + off);
      *reinterpret_cast<ush8*>(&Asl[rr * LDT + off]) = av;
      ush8 bv = *reinterpret_cast<const ush8*>(Bp + (size_t)(bn + rr) * K + k0 + off);
      *reinterpret_cast<ush8*>(&Bsl[rr * LDT + off]) = bv;
    }
    __syncthreads();
    bf16x8 af[4], bfv[4];
#pragma unroll
    for (int mi = 0; mi < 4; ++mi)
      af[mi] = *reinterpret_cast<const bf16x8*>(&Asl[(wr + mi * 16 + l15) * LDT + (lk << 3)]);
#pragma unroll
    for (int ni = 0; ni < 4; ++ni)
      bfv[ni] = *reinterpret_cast<const bf16x8*>(&Bsl[(wc + ni * 16 + l15) * LDT + (lk << 3)]);
#pragma unroll
    for (int mi = 0; mi < 4; ++mi)
#pragma unroll
      for (int ni = 0; ni < 4; ++ni)
        acc[mi][ni] = __builtin_amdgcn_mfma_f32_16x16x32_bf16(af[mi], bfv[ni], acc[mi][ni], 0, 0, 0);
  }
#pragma unroll
  for (int mi = 0; mi < 4; ++mi) {
    int gr0 = bm + wr + mi * 16 + (lk << 2);
#pragma unroll
    for (int ni = 0; ni < 4; ++ni) {
      int gc = bn + wc + ni * 16 + l15;
#pragma unroll
      for (int r4 = 0; r4 < 4; ++r4) {
        int gr = gr0 + r4;
        if (gr < M) Cp[(size_t)gr * F + gc] = f2bf(acc[mi][ni][r4]);
      }
    }
  }
}

// ---------------- vector bf16 row helpers ----------------
template <int EPL>
__device__ __forceinline__ void load_row(const unsigned short* __restrict__ p,
                                         float* __restrict__ v) {
  if (EPL == 8) {
    ush8 t = *reinterpret_cast<const ush8*>(p);
#pragma unroll
    for (int i = 0; i < 8; ++i) v[i] = bf2f(t[i]);
  } else if (EPL == 4) {
    ush4 t = *reinterpret_cast<const ush4*>(p);
    v[0] = bf2f(t.x); v[1] = bf2f(t.y); v[2] = bf2f(t.z); v[3] = bf2f(t.w);
  } else {
    ush2 t = *reinterpret_cast<const ush2*>(p);
    v[0] = bf2f(t.x); v[1] = bf2f(t.y);
  }
}
template <int EPL>
__device__ __forceinline__ void store_row(unsigned short* __restrict__ p,
                                          const float* __restrict__ v) {
  if (EPL == 8) {
    ush8 t;
#pragma unroll
    for (int i = 0; i < 8; ++i) t[i] = f2bf(v[i]);
    *reinterpret_cast<ush8*>(p) = t;
  } else if (EPL == 4) {
    ush4 t;
    t.x = f2bf(v[0]); t.y = f2bf(v[1]); t.z = f2bf(v[2]); t.w = f2bf(v[3]);
    *reinterpret_cast<ush4*>(p) = t;
  } else {
    ush2 t;
    t.x = f2bf(v[0]); t.y = f2bf(v[1]);
    *reinterpret_cast<ush2*>(p) = t;
  }
}

// ---------------- GCN gather: wave per node, dual-path over 2N -------------
template <int WA, int WE, int EPL>
__global__ __launch_bounds__(256) void gcn_gather_w_k(
    P2c h, I2c rowptr, I2c col, F2c dinv, F2c bias, P2m outa, P2m oute, int N) {
  constexpr int F = EPL * 64;
  const int gid = blockIdx.x * 4 + (threadIdx.x >> 6);
  const int lane = threadIdx.x & 63;
  if (gid >= 2 * N) return;
  const int pa = gid >= N;
  const int node = gid - pa * N;
  const unsigned short* __restrict__ hp = h.p[pa];
  const int* __restrict__ rp = rowptr.p[pa];
  const int* __restrict__ cp = col.p[pa];
  const float* __restrict__ dv = dinv.p[pa];
  const float* __restrict__ bp = bias.p[pa];
  const int beg = rp[node], end = rp[node + 1];
  const float di = dv[node];
  const int f0 = lane * EPL;
  float acc[EPL], row[EPL];
  load_row<EPL>(hp + (size_t)node * F + f0, row);
  {
    float w = di * di;
#pragma unroll
    for (int i = 0; i < EPL; ++i) acc[i] = row[i] * w;
  }
  for (int p = beg; p < end; ++p) {
    int s = cp[p];
    float w = dv[s] * di;
    load_row<EPL>(hp + (size_t)s * F + f0, row);
#pragma unroll
    for (int i = 0; i < EPL; ++i) acc[i] += row[i] * w;
  }
#pragma unroll
  for (int i = 0; i < EPL; ++i) acc[i] = fmaxf(acc[i] + bp[f0 + i], 0.f);
  if (WA) store_row<EPL>(outa.p[pa] + (size_t)node * F + f0, acc);
  if (WE) store_row<EPL>(oute.p[pa] + (size_t)node * F + f0, acc);
}

// ---------------- GAT logits, dual-path ----------------
template <int K, int H>
__global__ __launch_bounds__(256) void attn_dot_k(
    P2c in, F2c va, F2m asrc, F2m adst, int N) {
  constexpr int EPL = K / 64;
  const int gid = blockIdx.x * 4 + (threadIdx.x >> 6);
  const int lane = threadIdx.x & 63;
  if (gid >= 2 * N) return;
  const int pa = gid >= N;
  const int n = gid - pa * N;
  float acc[2 * H] = {};
  float xv[EPL];
  load_row<EPL>(in.p[pa] + (size_t)n * K + lane * EPL, xv);
  const float* __restrict__ vap = va.p[pa];
#pragma unroll
  for (int j = 0; j < EPL; ++j) {
    const float* vp = vap + (size_t)(lane * EPL + j) * 2 * H;
#pragma unroll
    for (int o = 0; o < 2 * H; ++o) acc[o] += xv[j] * vp[o];
  }
#pragma unroll
  for (int off = 32; off >= 1; off >>= 1)
#pragma unroll
    for (int o = 0; o < 2 * H; ++o) acc[o] += __shfl_xor(acc[o], off);
  if (lane == 0) {
#pragma unroll
    for (int hh = 0; hh < H; ++hh) {
      asrc.p[pa][n * H + hh] = acc[hh];
      adst.p[pa][n * H + hh] = acc[H + hh];
    }
  }
}

// ---------------- GAT fused, dual-path, wave per node ----------------
template <int H, int C, int EPI>
__global__ __launch_bounds__(256) void gat_fused_w_k(
    P2c h, F2c asrc, F2c adst, I2c rowptr, I2c col, F2c bias, P2m out, int N) {
  constexpr int F = H * C;
  constexpr int EPL = F / 64;
  const int gid = blockIdx.x * 4 + (threadIdx.x >> 6);
  const int lane = threadIdx.x & 63;
  if (gid >= 2 * N) return;
  const int pa = gid >= N;
  const int node = gid - pa * N;
  const unsigned short* __restrict__ hp = h.p[pa];
  const float* __restrict__ asp = asrc.p[pa];
  const float* __restrict__ adp = adst.p[pa];
  const int* __restrict__ rp = rowptr.p[pa];
  const int* __restrict__ cp = col.p[pa];
  const float* __restrict__ bp = bias.p[pa];
  const int beg = rp[node], end = rp[node + 1];

  float ad[H], vself[H];
#pragma unroll
  for (int k = 0; k < H; ++k) {
    ad[k] = adp[node * H + k];
    float v = asp[node * H + k] + ad[k];
    vself[k] = v > 0.f ? v : 0.2f * v;
  }
  float m[H];
#pragma unroll
  for (int k = 0; k < H; ++k) m[k] = vself[k];
  for (int p = beg + lane; p < end; p += 64) {
    int s = cp[p];
#pragma unroll
    for (int k = 0; k < H; ++k) {
      float v = asp[s * H + k] + ad[k];
      v = v > 0.f ? v : 0.2f * v;
      m[k] = fmaxf(m[k], v);
    }
  }
#pragma unroll
  for (int off = 32; off >= 1; off >>= 1)
#pragma unroll
    for (int k = 0; k < H; ++k) m[k] = fmaxf(m[k], __shfl_xor(m[k], off));
  float dn[H] = {};
  for (int p = beg + lane; p < end; p += 64) {
    int s = cp[p];
#pragma unroll
    for (int k = 0; k < H; ++k) {
      float v = asp[s * H + k] + ad[k];
      v = v > 0.f ? v : 0.2f * v;
      dn[k] += __expf(v - m[k]);
    }
  }
#pragma unroll
  for (int off = 32; off >= 1; off >>= 1)
#pragma unroll
    for (int k = 0; k < H; ++k) dn[k] += __shfl_xor(dn[k], off);
  float invD[H];
#pragma unroll
  for (int k = 0; k < H; ++k)
    invD[k] = 1.f / (dn[k] + __expf(vself[k] - m[k]) + 1e-16f);
  const int f0 = lane * EPL;
  const int k0 = f0 / C;
  float acc[EPL], row[EPL];
  load_row<EPL>(hp + (size_t)node * F + f0, row);
  {
    float aself = __expf(vself[k0] - m[k0]) * invD[k0];
#pragma unroll
    for (int i = 0; i < EPL; ++i) acc[i] = aself * row[i];
  }
  for (int p = beg; p < end; ++p) {
    int s = cp[p];
    float v = asp[s * H + k0] + ad[k0];
    v = v > 0.f ? v : 0.2f * v;
    float a = __expf(v - m[k0]) * invD[k0];
    load_row<EPL>(hp + (size_t)s * F + f0, row);
#pragma unroll
    for (int i = 0; i < EPL; ++i) acc[i] += a * row[i];
  }
  if (EPI == 0) {
#pragma unroll
    for (int i = 0; i < EPL; ++i) {
      float v = acc[i] + bp[f0 + i];
      acc[i] = v > 0.f ? v : (__expf(v) - 1.f);
    }
    store_row<EPL>(out.p[pa] + (size_t)node * F + f0, acc);
  } else {
#pragma unroll
    for (int i = 0; i < EPL; ++i) acc[i] += bp[f0 + i];
    float r = acc[0];
#pragma unroll
    for (int i = 1; i < EPL; ++i) r = fmaxf(r, acc[i]);
#pragma unroll
    for (int off = 32; off >= 1; off >>= 1) r = fmaxf(r, __shfl_xor(r, off));
    float se = 0.f;
#pragma unroll
    for (int i = 0; i < EPL; ++i) se += __expf(acc[i] - r);
#pragma unroll
    for (int off = 32; off >= 1; off >>= 1) se += __shfl_xor(se, off);
    float ls = logf(se);
#pragma unroll
    for (int i = 0; i < EPL; ++i) acc[i] = fmaxf(acc[i] - r - ls, 0.f);
    store_row<EPL>(out.p[pa] + (size_t)node * F + f0, acc);
  }
}

// ---------------- final fusion + MLP + log_softmax (bf16 z, 8 nodes/block) --
#define NPB 8
__global__ __launch_bounds__(256) void final3_k(
    const unsigned short* __restrict__ E1, const unsigned short* __restrict__ E3,
    const unsigned short* __restrict__ E4, const unsigned short* __restrict__ E6,
    const float* __restrict__ aw1, const float* __restrict__ ab1,
    const float* __restrict__ aw2, const float* __restrict__ mw1,
    const float* __restrict__ mb1, const float* __restrict__ mw2,
    const float* __restrict__ mb2, float* __restrict__ out, int N) {
  __shared__ unsigned short zsh[NPB][2][512];
  __shared__ float psh[NPB][256];
  __shared__ float wsh[NPB * 2][17];
  __shared__ float warr[NPB][2];
  __shared__ float bsh[NPB][2];
  __shared__ float hsh[NPB][64];
  __shared__ float o7sh[NPB][8];
  const int t = threadIdx.x;
  const int n0 = blockIdx.x * NPB;
  {
    int seg = t >> 6, idx = t & 63;
    const unsigned short* sp = (seg == 0) ? E1 : (seg == 1) ? E3 : (seg == 2) ? E4 : E6;
    int r = seg >> 1, half = seg & 1;
    for (int nd = 0; nd < NPB; ++nd) {
      if (n0 + nd < N) {
        ush4 v = reinterpret_cast<const ush4*>(sp)[(size_t)(n0 + nd) * 64 + idx];
        reinterpret_cast<ush4*>(&zsh[nd][r][half * 256])[idx] = v;
      }
    }
  }
  __syncthreads();
  {
    int row = t >> 4, j = t & 15;
    int nd = row >> 1, r = row & 1;
    const ush2* zp = reinterpret_cast<const ush2*>(zsh[nd][r]);
    float a0 = ab1[j], a1 = 0.f;
    for (int c2 = 0; c2 < 256; ++c2) {
      ush2 v = zp[c2];
      a0 += bf2f(v.x) * aw1[(2 * c2) * 16 + j];
      a1 += bf2f(v.y) * aw1[(2 * c2 + 1) * 16 + j];
    }
    wsh[row][j] = tanhf(a0 + a1) * aw2[j];
  }
  __syncthreads();
  if (t < 16) {
    float s = 0.f;
    for (int j = 0; j < 16; ++j) s += wsh[t][j];
    warr[t >> 1][t & 1] = s;
  }
  __syncthreads();
  if (t < NPB) {
    float w0 = warr[t][0], w1 = warr[t][1];
    float mxv = fmaxf(w0, w1);
    float e0 = __expf(w0 - mxv), e1 = __expf(w1 - mxv);
    float inv = 1.f / (e0 + e1);
    bsh[t][0] = e0 * inv; bsh[t][1] = e1 * inv;
  }
  __syncthreads();
  {
    int nd = t >> 5, l = t & 31;
    float b0 = bsh[nd][0], b1 = bsh[nd][1];
    ush2* z0 = reinterpret_cast<ush2*>(zsh[nd][0]);
    const ush2* z1 = reinterpret_cast<const ush2*>(zsh[nd][1]);
    for (int i = 0; i < 8; ++i) {
      int c2 = l + 32 * i;
      ush2 a = z0[c2], b = z1[c2];
      ush2 o;
      o.x = f2bf(b0 * bf2f(a.x) + b1 * bf2f(b.x));
      o.y = f2bf(b0 * bf2f(a.y) + b1 * bf2f(b.y));
      z0[c2] = o;
    }
  }
  __syncthreads();
  {
    int o = t & 63, ch = t >> 6;
    float accv[NPB];
#pragma unroll
    for (int nd = 0; nd < NPB; ++nd) accv[nd] = 0.f;
    for (int c2 = ch * 64; c2 < ch * 64 + 64; ++c2) {
      float w0 = mw1[(2 * c2) * 64 + o];
      float w1 = mw1[(2 * c2 + 1) * 64 + o];
#pragma unroll
      for (int nd = 0; nd < NPB; ++nd) {
        ush2 v = reinterpret_cast<const ush2*>(zsh[nd][0])[c2];
        accv[nd] += bf2f(v.x) * w0 + bf2f(v.y) * w1;
      }
    }
#pragma unroll
    for (int nd = 0; nd < NPB; ++nd) psh[nd][ch * 64 + o] = accv[nd];
  }
  __syncthreads();
  {
    int nd = t >> 5, oo = t & 31;
#pragma unroll
    for (int i = 0; i < 2; ++i) {
      int o = oo + i * 32;
      float s = mb1[o] + psh[nd][o] + psh[nd][64 + o] +
                psh[nd][128 + o] + psh[nd][192 + o];
      hsh[nd][o] = tanhf(s);
    }
  }
  __syncthreads();
  if (t < NPB * 7) {
    int nd = t / 7, jo = t - nd * 7;
    float a = mb2[jo];
    for (int j = 0; j < 64; ++j) a += hsh[nd][j] * mw2[j * 7 + jo];
    o7sh[nd][jo] = a;
  }
  __syncthreads();
  if (t < NPB && n0 + t < N) {
    float m = o7sh[t][0];
    for (int k = 1; k < 7; ++k) m = fmaxf(m, o7sh[t][k]);
    float s = 0.f;
    for (int k = 0; k < 7; ++k) s += expf(o7sh[t][k] - m);
    float ls = logf(s);
    for (int k = 0; k < 7; ++k) out[(size_t)(n0 + t) * 7 + k] = o7sh[t][k] - m - ls;
  }
}

// ---------------------------------------------------------------------------
extern "C" void kernel_launch(void* const* d_in, const int* in_sizes, int n_in,
                              void* d_out, int out_size, void* d_ws, size_t ws_size,
                              hipStream_t stream) {
  (void)n_in; (void)out_size; (void)ws_size;
  const float* x     = (const float*)d_in[0];
  const int*   sadj  = (const int*)d_in[1];
  const int*   fadj  = (const int*)d_in[2];
  const int*   asadj = (const int*)d_in[3];
  const int*   afadj = (const int*)d_in[4];
  const float* W1a = (const float*)d_in[5];  const float* b1a = (const float*)d_in[6];
  const float* W1b = (const float*)d_in[7];  const float* b1b = (const float*)d_in[8];
  const float* W2a = (const float*)d_in[9];  const float* b2a = (const float*)d_in[10];
  const float* W2b = (const float*)d_in[11]; const float* b2b = (const float*)d_in[12];
  const float* W3a = (const float*)d_in[13]; const float* b3a = (const float*)d_in[14];
  const float* W3b = (const float*)d_in[15]; const float* b3b = (const float*)d_in[16];
  const float* W4a = (const float*)d_in[17]; const float* b4a = (const float*)d_in[18];
  const float* W4b = (const float*)d_in[19]; const float* b4b = (const float*)d_in[20];
  const float* Wg1a = (const float*)d_in[21]; const float* as1a = (const float*)d_in[22];
  const float* ad1a = (const float*)d_in[23]; const float* bg1a = (const float*)d_in[24];
  const float* Wg1b = (const float*)d_in[25]; const float* as1b = (const float*)d_in[26];
  const float* ad1b = (const float*)d_in[27]; const float* bg1b = (const float*)d_in[28];
  const float* Wg2a = (const float*)d_in[29]; const float* as2a = (const float*)d_in[30];
  const float* ad2a = (const float*)d_in[31]; const float* bg2a = (const float*)d_in[32];
  const float* Wg2b = (const float*)d_in[33]; const float* as2b = (const float*)d_in[34];
  const float* ad2b = (const float*)d_in[35]; const float* bg2b = (const float*)d_in[36];
  const float* aw1 = (const float*)d_in[37]; const float* ab1 = (const float*)d_in[38];
  const float* aw2 = (const float*)d_in[39];
  const float* mw1 = (const float*)d_in[40]; const float* mb1 = (const float*)d_in[41];
  const float* mw2 = (const float*)d_in[42]; const float* mb2 = (const float*)d_in[43];

  const int N = in_sizes[0] / 1024;   // 20000
  const int E = in_sizes[1] / 2;      // 160000

  // ---- workspace layout ----
  float* ws = (float*)d_ws;
  float* bufA  = ws;                          // N*512 floats; hb1/hb2 alias it
  float* vaT   = bufA + (size_t)N * 512;      // 8192 floats
  float* dinvS = vaT + 8192;                  // N
  float* dinvF = dinvS + N;                   // N
  float* asrc1 = dinvF + N;                   // N*4
  float* adst1 = asrc1 + (size_t)N * 4;       // N*4
  float* asrc2 = adst1 + (size_t)N * 4;       // N*4
  float* adst2 = asrc2 + (size_t)N * 4;       // N*4
  int* ib = (int*)(adst2 + (size_t)N * 4);
  int* rowptr4 = ib;            ib += 4 * (N + 1);
  int* col4    = ib;            ib += 4 * E;
  int* deg4    = ib;            ib += 4 * N;
  int* cursor4 = ib;            ib += 4 * N;
  unsigned short* ub = (unsigned short*)(ib + ((size_t)(-(intptr_t)ib) & 3));
  unsigned short* xb = ub;            ub += (size_t)N * 1024;
  unsigned short* actb1 = ub;         ub += (size_t)N * 512;
  unsigned short* actb2 = ub;         ub += (size_t)N * 512;
  unsigned short* E1bb = ub;          ub += (size_t)N * 256;
  unsigned short* E3bb = ub;          ub += (size_t)N * 256;
  unsigned short* E4bb = ub;          ub += (size_t)N * 256;
  unsigned short* E6bb = ub;          ub += (size_t)N * 256;
  unsigned short* Wt1a = ub;  ub += 1024 * 512;
  unsigned short* Wt1b = ub;  ub += 512 * 256;
  unsigned short* Wt2a = ub;  ub += 1024 * 512;
  unsigned short* Wt2b = ub;  ub += 512 * 256;
  unsigned short* Wt3a = ub;  ub += 256 * 128;
  unsigned short* Wt3b = ub;  ub += 128 * 256;
  unsigned short* Wt4a = ub;  ub += 256 * 128;
  unsigned short* Wt4b = ub;  ub += 128 * 256;
  unsigned short* Wtg1a = ub; ub += 256 * 512;
  unsigned short* Wtg1b = ub; ub += 512 * 256;
  unsigned short* Wtg2a = ub; ub += 256 * 512;
  unsigned short* Wtg2b = ub; ub += 512 * 256;
  unsigned short* hb1 = (unsigned short*)bufA;          // N*512 bf16
  unsigned short* hb2 = hb1 + (size_t)N * 512;          // N*512 bf16
  float* vag1a = vaT;
  float* vag1b = vaT + 2048;
  float* vag2a = vaT + 3072;
  float* vag2b = vaT + 5120;
  int* rowptrS = rowptr4;
  int* rowptrF = rowptr4 + (N + 1);
  int* rowptrA1 = rowptr4 + 2 * (N + 1);
  int* rowptrA2 = rowptr4 + 3 * (N + 1);
  int* colS = col4;
  int* colF = col4 + E;
  int* colA1 = col4 + 2 * E;
  int* colA2 = col4 + 3 * E;

  // ---- batched setup ----
  {
    TcJobs j;
    const float* srcs[12] = {W1a, W1b, W2a, W2b, W3a, W3b, W4a, W4b, Wg1a, Wg1b, Wg2a, Wg2b};
    unsigned short* dsts[12] = {Wt1a, Wt1b, Wt2a, Wt2b, Wt3a, Wt3b, Wt4a, Wt4b,
                                Wtg1a, Wtg1b, Wtg2a, Wtg2b};
    int Ks[12] = {1024, 512, 1024, 512, 256, 128, 256, 128, 256, 512, 256, 512};
    int Fs[12] = {512, 256, 512, 256, 128, 256, 128, 256, 512, 256, 512, 256};
    int acc = 0;
    for (int i = 0; i < 12; ++i) {
      j.src[i] = srcs[i]; j.dst[i] = dsts[i]; j.K[i] = Ks[i]; j.F[i] = Fs[i];
      j.start[i] = acc;
      acc += (Ks[i] / 32) * (Fs[i] / 32);
    }
    j.start[12] = acc;
    tc_batch_k<<<acc, 256, 0, stream>>>(j);
  }
  va4_k<<<24, 256, 0, stream>>>(Wg1a, as1a, ad1a, vag1a, Wg1b, as1b, ad1b, vag1b,
                                Wg2a, as2a, ad2a, vag2a, Wg2b, as2b, ad2b, vag2b);
  cast_bf16_k<<<cdiv(N * 1024 / 4, 256), 256, 0, stream>>>(x, xb, N * 1024 / 4);
  zero_int_k<<<cdiv(4 * N, 256), 256, 0, stream>>>(deg4, 4 * N);
  hist4_k<<<cdiv(4 * E, 256), 256, 0, stream>>>(sadj, fadj, asadj, afadj, deg4, E, N);
  scan4_k<<<4, 1024, 0, stream>>>(deg4, rowptr4, cursor4, N);
  dinv2_k<<<cdiv(2 * N, 256), 256, 0, stream>>>(deg4, dinvS, dinvF, N);
  place4_k<<<cdiv(4 * E, 256), 256, 0, stream>>>(sadj, fadj, asadj, afadj, cursor4, col4, E, N);

  // ---- dual-path batched pipeline ----
  const int GW2 = cdiv(2 * N, 4);
  P2c Hh = {{hb1, hb2}};
  P2m Hm = {{hb1, hb2}};
  P2c Aa = {{actb1, actb2}};
  P2m Am = {{actb1, actb2}};
  I2c RG = {{rowptrS, rowptrF}}, CG = {{colS, colF}};
  I2c RA = {{rowptrA1, rowptrA2}}, CA = {{colA1, colA2}};
  F2c DV = {{dinvS, dinvF}};
  F2c AS = {{asrc1, asrc2}}, AD = {{adst1, adst2}};
  F2m ASm = {{asrc1, asrc2}}, ADm = {{adst1, adst2}};

  auto gemm2 = [&](P2c A, P2c Bt, int K, int F) {
    int gx = F / 128, gy = cdiv(N, 128);
    gemm_bf16_k<<<dim3(gx, gy, 2), 256, 0, stream>>>(A, Bt, Hm, N, K, F, gx, gy);
  };

  // stage 1: x @ W1a / W2a  (1024->512)
  gemm2({{xb, xb}}, {{Wt1a, Wt2a}}, 1024, 512);
  gcn_gather_w_k<1, 0, 8><<<GW2, 256, 0, stream>>>(Hh, RG, CG, DV, {{b1a, b2a}}, Am, {{nullptr, nullptr}}, N);
  // stage 2: 512->256, write act + E1/E4
  gemm2(Aa, {{Wt1b, Wt2b}}, 512, 256);
  gcn_gather_w_k<1, 1, 4><<<GW2, 256, 0, stream>>>(Hh, RG, CG, DV, {{b1b, b2b}}, Am, {{E1bb, E4bb}}, N);
  // stage 3: GAT layer 1 (256->512, 4 heads)
  gemm2(Aa, {{Wtg1a, Wtg2a}}, 256, 512);
  attn_dot_k<256, 4><<<GW2, 256, 0, stream>>>(Aa, {{vag1a, vag2a}}, ASm, ADm, N);
  gat_fused_w_k<4, 128, 0><<<GW2, 256, 0, stream>>>(Hh, AS, AD, RA, CA, {{bg1a, bg2a}}, Am, N);
  // stage 4: GAT layer 2 (512->256, 1 head, log_softmax+relu)
  gemm2(Aa, {{Wtg1b, Wtg2b}}, 512, 256);
  attn_dot_k<512, 1><<<GW2, 256, 0, stream>>>(Aa, {{vag1b, vag2b}}, ASm, ADm, N);
  gat_fused_w_k<1, 256, 1><<<GW2, 256, 0, stream>>>(Hh, AS, AD, RA, CA, {{bg1b, bg2b}}, Am, N);
  // stage 5: 256->128
  gemm2(Aa, {{Wt3a, Wt4a}}, 256, 128);
  gcn_gather_w_k<1, 0, 2><<<GW2, 256, 0, stream>>>(Hh, RG, CG, DV, {{b3a, b4a}}, Am, {{nullptr, nullptr}}, N);
  // stage 6: 128->256, write E3/E6
  gemm2(Aa, {{Wt3b, Wt4b}}, 128, 256);
  gcn_gather_w_k<0, 1, 4><<<GW2, 256, 0, stream>>>(Hh, RG, CG, DV, {{b3b, b4b}}, Am, {{E3bb, E6bb}}, N);

  // ---- fusion + MLP + log_softmax ----
  final3_k<<<cdiv(N, NPB), 256, 0, stream>>>(E1bb, E3bb, E4bb, E6bb,
                                             aw1, ab1, aw2, mw1, mb1, mw2, mb2,
                                             (float*)d_out, N);
}